// Round 10
// baseline (159.653 us; speedup 1.0000x reference)
//
#include <hip/hip_runtime.h>
#include <cmath>

#define ROWS      16384
#define SEQLEN    8192
#define BATCH     2
#define NHEADS    24
#define HEADDIM   16
#define D_STATE   16
#define D_INNER   384
#define D_MODEL   192
#define D_IN_PROJ 808
#define CONV_DIM  400
#define NCHUNKS   32
#define CHUNK     256
#define EPS       1e-5f

typedef short bf16x8 __attribute__((ext_vector_type(8)));
typedef float f32x4  __attribute__((ext_vector_type(4)));
typedef unsigned short us4v __attribute__((ext_vector_type(4)));
typedef unsigned short us8v __attribute__((ext_vector_type(8)));

__device__ __forceinline__ float silu_f(float x) { return x / (1.0f + expf(-x)); }
__device__ __forceinline__ float softplus_f(float x) { return (x > 20.0f) ? x : log1pf(expf(x)); }
__device__ __forceinline__ unsigned short f2bf(float x) {
  unsigned u = __builtin_bit_cast(unsigned, x);
  u += 0x7fff + ((u >> 16) & 1);
  return (unsigned short)(u >> 16);
}
__device__ __forceinline__ float bf2f(unsigned short s) {
  unsigned u = (unsigned)s << 16;
  return __builtin_bit_cast(float, u);
}

// ---------------------------------------------------------------------------
// K0: fp32 -> bf16 conversion for W_in, W_out (weights only; ~0.5 MB)
// ---------------------------------------------------------------------------
__global__ __launch_bounds__(256)
void cvt2_kernel(const float* __restrict__ a, unsigned short* __restrict__ ao, long na,
                 const float* __restrict__ b, unsigned short* __restrict__ bo, long nb) {
  const long t0 = na >> 2, t1 = t0 + (nb >> 2);
  const long stride = (long)gridDim.x * blockDim.x;
  for (long i = (long)blockIdx.x * blockDim.x + threadIdx.x; i < t1; i += stride) {
    const float4* s; us4v* d; long j;
    if (i < t0) { s = (const float4*)a; d = (us4v*)ao; j = i; }
    else        { s = (const float4*)b; d = (us4v*)bo; j = i - t0; }
    float4 v = s[j];
    us4v o = { f2bf(v.x), f2bf(v.y), f2bf(v.z), f2bf(v.w) };
    d[j] = o;
  }
}

// ---------------------------------------------------------------------------
// MFMA bf16 GEMM: C[M,N] = A[M,K] * W[N,K]^T. A fp32 (converted in staging)
// or bf16; out bf16 or fp32. Double-buffered LDS.
// Operand-swapped MFMA (W as A-operand) -> lane holds 4 consecutive OUTPUT
// COLUMNS -> packed 8B/16B epilogue stores.
// ---------------------------------------------------------------------------
template<bool A_F32, bool OUT_BF16>
__launch_bounds__(256, 3)
__global__ void gemm_bf16(const void* __restrict__ Ap,
                          const unsigned short* __restrict__ W,
                          void* __restrict__ Cp, int M, int N, int K) {
  constexpr int BM = 128, BN = 128, BK = 32, LDK = 40;
  __shared__ unsigned short As[2][BM * LDK];
  __shared__ unsigned short Ws[2][BN * LDK];
  const int tid  = threadIdx.x;
  const int wid  = tid >> 6, lane = tid & 63;
  const int wr   = wid >> 1, wc = wid & 1;
  const int fr   = lane & 15, fq = lane >> 4;
  const long m0  = (long)blockIdx.y * BM;
  const int  n0  = blockIdx.x * BN;

  f32x4 acc[4][4] = {};

  auto stage = [&](int k0, int buf) {
    if (A_F32) {
      const float* A = (const float*)Ap;
#pragma unroll
      for (int p = 0; p < 2; ++p) {
        int flat = p * 2048 + tid * 8;
        int r = flat >> 5, c = flat & 31;
        const float4* src = (const float4*)(A + (m0 + r) * (long)K + k0 + c);
        float4 v0 = src[0], v1 = src[1];
        us8v o = { f2bf(v0.x), f2bf(v0.y), f2bf(v0.z), f2bf(v0.w),
                   f2bf(v1.x), f2bf(v1.y), f2bf(v1.z), f2bf(v1.w) };
        *(us8v*)&As[buf][r * LDK + c] = o;
      }
    } else {
      const unsigned short* A = (const unsigned short*)Ap;
#pragma unroll
      for (int p = 0; p < 2; ++p) {
        int flat = p * 2048 + tid * 8;
        int r = flat >> 5, c = flat & 31;
        us8v v = *(const us8v*)(A + (m0 + r) * (long)K + k0 + c);
        *(us8v*)&As[buf][r * LDK + c] = v;
      }
    }
#pragma unroll
    for (int p = 0; p < 2; ++p) {
      int flat = p * 2048 + tid * 8;
      int r = flat >> 5, c = flat & 31;
      int gn = n0 + r;
      us8v v = { 0, 0, 0, 0, 0, 0, 0, 0 };
      if (gn < N) v = *(const us8v*)(W + (long)gn * K + k0 + c);
      *(us8v*)&Ws[buf][r * LDK + c] = v;
    }
  };

  const int nk = K / BK;
  stage(0, 0);
  __syncthreads();
  for (int kt = 0; kt < nk; ++kt) {
    const int cur = kt & 1;
    if (kt + 1 < nk) stage((kt + 1) * BK, cur ^ 1);
    bf16x8 af[4], bfr[4];
#pragma unroll
    for (int m = 0; m < 4; ++m)
      af[m] = *(const bf16x8*)&As[cur][(wr * 64 + m * 16 + fr) * LDK + fq * 8];
#pragma unroll
    for (int n = 0; n < 4; ++n)
      bfr[n] = *(const bf16x8*)&Ws[cur][(wc * 64 + n * 16 + fr) * LDK + fq * 8];
    // swapped operands: D rows = W-rows (cols of C), D cols = A-rows (rows of C)
#pragma unroll
    for (int m = 0; m < 4; ++m)
#pragma unroll
      for (int n = 0; n < 4; ++n)
        acc[m][n] = __builtin_amdgcn_mfma_f32_16x16x32_bf16(bfr[n], af[m], acc[m][n], 0, 0, 0);
    __syncthreads();
  }

  // lane holds C[row=gm][cols gn..gn+3] -> packed stores
#pragma unroll
  for (int m = 0; m < 4; ++m) {
    const long gm = m0 + wr * 64 + m * 16 + fr;
#pragma unroll
    for (int n = 0; n < 4; ++n) {
      const int gn = n0 + wc * 64 + n * 16 + fq * 4;
      if (gn < N) {
        if (OUT_BF16) {
          us4v o = { f2bf(acc[m][n][0]), f2bf(acc[m][n][1]),
                     f2bf(acc[m][n][2]), f2bf(acc[m][n][3]) };
          *(us4v*)((unsigned short*)Cp + gm * N + gn) = o;
        } else {
          float4 o = make_float4(acc[m][n][0], acc[m][n][1], acc[m][n][2], acc[m][n][3]);
          *(float4*)((float*)Cp + gm * N + gn) = o;
        }
      }
    }
  }
}

// ---------------------------------------------------------------------------
// fp32 SIMT GEMM (tiny K1b only: N=16)
// ---------------------------------------------------------------------------
template<int BM, int BN, int BK, int TM, int TN>
__launch_bounds__((BM / TM) * (BN / TN))
__global__ void gemm_nt(const float* __restrict__ A, const float* __restrict__ W,
                        float* __restrict__ C, int M, int N, int K) {
  __shared__ float As[BK][BM + 4];
  __shared__ float Ws[BK][BN + 4];
  constexpr int NTX = BN / TN;
  constexpr int NT  = (BM / TM) * (BN / TN);
  const int tid = threadIdx.x;
  const int tx  = tid % NTX;
  const int ty  = tid / NTX;
  const long m0 = (long)blockIdx.y * BM;
  const long n0 = (long)blockIdx.x * BN;
  float acc[TM][TN] = {};

  for (int k0 = 0; k0 < K; k0 += BK) {
    for (int i = tid; i < BM * BK; i += NT) {
      int m = i / BK, kk = i % BK;
      long gm = m0 + m;
      As[kk][m] = (gm < M) ? A[gm * K + (k0 + kk)] : 0.0f;
    }
    for (int i = tid; i < BN * BK; i += NT) {
      int n = i / BK, kk = i % BK;
      long gn = n0 + n;
      Ws[kk][n] = (gn < N) ? W[gn * K + (k0 + kk)] : 0.0f;
    }
    __syncthreads();
#pragma unroll
    for (int kk = 0; kk < BK; ++kk) {
      float a[TM], w[TN];
#pragma unroll
      for (int i = 0; i < TM; ++i) a[i] = As[kk][ty * TM + i];
#pragma unroll
      for (int j = 0; j < TN; ++j) w[j] = Ws[kk][tx * TN + j];
#pragma unroll
      for (int i = 0; i < TM; ++i)
#pragma unroll
        for (int j = 0; j < TN; ++j)
          acc[i][j] += a[i] * w[j];
    }
    __syncthreads();
  }
#pragma unroll
  for (int i = 0; i < TM; ++i) {
    long gm = m0 + ty * TM + i;
    if (gm >= M) continue;
#pragma unroll
    for (int j = 0; j < TN; ++j) {
      long gn = n0 + tx * TN + j;
      if (gn < N) C[gm * N + gn] = acc[i][j];
    }
  }
}

// ---------------------------------------------------------------------------
// K2: per-row depthwise causal conv + silu + dt softplus.
// ---------------------------------------------------------------------------
__global__ __launch_bounds__(448)
void conv_dt_row(const unsigned short* __restrict__ zxbdt, const float* __restrict__ cproj,
                 const float* __restrict__ conv_w, const float* __restrict__ conv_b,
                 const float* __restrict__ conv_w_b, const float* __restrict__ conv_b_b,
                 const float* __restrict__ dt_bias,
                 unsigned short* __restrict__ xoT, unsigned short* __restrict__ Bo,
                 unsigned short* __restrict__ Co, float* __restrict__ dtoT) {
  const int row = blockIdx.x;
  const int b   = row / SEQLEN, t = row % SEQLEN;
  const int c   = threadIdx.x;

  if (c < CONV_DIM) {
    const float4 wv = *(const float4*)(conv_w + c * 4);
    const unsigned short* base = zxbdt + (size_t)row * D_IN_PROJ + D_INNER + c;
    const float x0 = (t >= 3) ? bf2f(base[-3 * D_IN_PROJ]) : 0.0f;
    const float x1 = (t >= 2) ? bf2f(base[-2 * D_IN_PROJ]) : 0.0f;
    const float x2 = (t >= 1) ? bf2f(base[-1 * D_IN_PROJ]) : 0.0f;
    const float x3 = bf2f(base[0]);
    float acc = conv_b[c] + wv.x * x0 + wv.y * x1 + wv.z * x2 + wv.w * x3;
    unsigned short y = f2bf(silu_f(acc));
    if (c < D_INNER) {
      const int h = c >> 4, i = c & 15;
      xoT[((size_t)(b * NHEADS + h) * SEQLEN + t) * HEADDIM + i] = y;
    } else {
      Bo[(size_t)row * D_STATE + (c - D_INNER)] = y;
    }
  } else if (c < CONV_DIM + D_STATE) {
    const int cc = c - CONV_DIM;
    const float4 wv = *(const float4*)(conv_w_b + cc * 4);
    const float* base = cproj + (size_t)row * D_STATE + cc;
    const float x0 = (t >= 3) ? base[-3 * D_STATE] : 0.0f;
    const float x1 = (t >= 2) ? base[-2 * D_STATE] : 0.0f;
    const float x2 = (t >= 1) ? base[-1 * D_STATE] : 0.0f;
    const float x3 = base[0];
    float acc = conv_b_b[cc] + wv.x * x0 + wv.y * x1 + wv.z * x2 + wv.w * x3;
    Co[(size_t)row * D_STATE + cc] = f2bf(silu_f(acc));
  } else if (c < CONV_DIM + D_STATE + NHEADS) {
    const int h = c - CONV_DIM - D_STATE;
    float v = bf2f(zxbdt[(size_t)row * D_IN_PROJ + (D_IN_PROJ - NHEADS) + h]) + dt_bias[h];
    dtoT[(size_t)(b * NHEADS + h) * SEQLEN + t] = softplus_f(v);
  }
}

// ---------------------------------------------------------------------------
// K3 (MFMA): per (h, chunk, b) block, 4 waves. Head-major in/out. 35KB LDS.
// ---------------------------------------------------------------------------
__global__ __launch_bounds__(256, 4)
void ssd_mfma_kernel(const unsigned short* __restrict__ xoT, const unsigned short* __restrict__ Bo,
                     const unsigned short* __restrict__ Co, const float* __restrict__ dtoT,
                     const float* __restrict__ A_log,
                     unsigned short* __restrict__ YdT, float* __restrict__ acum_g,
                     float* __restrict__ csum_g, float* __restrict__ stloc) {
  const int h    = blockIdx.x;
  const int cidx = blockIdx.y;
  const int b    = blockIdx.z;
  const int l    = threadIdx.x;
  const int t    = cidx * CHUNK + l;
  const size_t row  = (size_t)b * SEQLEN + t;
  const size_t hrow = (size_t)(b * NHEADS + h) * SEQLEN + t;
  const int wid = l >> 6, lane = l & 63;
  const int fr  = lane & 15, g = lane >> 4;

  __shared__ unsigned short Bs[256 * 24 + 32];
  __shared__ unsigned short xsT[16 * 264];
  __shared__ unsigned short BwT[16 * 264];
  __shared__ unsigned short Ps[4][16 * 40];
  __shared__ float sc[CHUNK];
  __shared__ float wsum[4];

  const float Ah  = -expf(A_log[h]);
  const float dtv = dtoT[hrow];

  float v = dtv * Ah;
#pragma unroll
  for (int off = 1; off < 64; off <<= 1) {
    float u = __shfl_up(v, off, 64);
    if (lane >= off) v += u;
  }
  if (lane == 63) wsum[wid] = v;

  us8v b0, b1;
  {
    const us8v z8 = { 0, 0, 0, 0, 0, 0, 0, 0 };
    const us8v* bp = (const us8v*)(Bo + row * D_STATE);
    b0 = bp[0]; b1 = bp[1];
    *(us8v*)&Bs[l * 24 + 0] = b0;
    *(us8v*)&Bs[l * 24 + 8] = b1;
    *(us8v*)&Bs[l * 24 + 16] = z8;
    if (l < 32) Bs[256 * 24 + l] = 0;
    const us8v* xp = (const us8v*)(xoT + hrow * HEADDIM);
    us8v x0 = xp[0], x1 = xp[1];
#pragma unroll
    for (int q = 0; q < 8; ++q) {
      xsT[q * 264 + l]       = f2bf(bf2f(x0[q]) * dtv);
      xsT[(q + 8) * 264 + l] = f2bf(bf2f(x1[q]) * dtv);
    }
  }
  __syncthreads();   // #1

  float pre = 0.f, ctot = 0.f;
#pragma unroll
  for (int w = 0; w < 4; ++w) {
    float s = wsum[w];
    if (w < wid) pre += s;
    ctot += s;
  }
  v += pre;
  sc[l] = v;
  acum_g[hrow] = v;
  if (l == CHUNK - 1) csum_g[(b * NHEADS + h) * NCHUNKS + cidx] = v;
  const float wdv = __expf(ctot - v);
#pragma unroll
  for (int q = 0; q < 8; ++q) {
    BwT[q * 264 + l]       = f2bf(bf2f(b0[q]) * wdv);
    BwT[(q + 8) * 264 + l] = f2bf(bf2f(b1[q]) * wdv);
  }
  __syncthreads();   // #2

  // chunk state: wave 0 computes all of K=256 (8 MFMAs), writes stloc direct
  if (wid == 0) {
    f32x4 accS = {};
#pragma unroll
    for (int k2 = 0; k2 < 8; ++k2) {
      bf16x8 af = *(const bf16x8*)&BwT[fr * 264 + 32 * k2 + 8 * g];
      bf16x8 bb = *(const bf16x8*)&xsT[fr * 264 + 32 * k2 + 8 * g];
      accS = __builtin_amdgcn_mfma_f32_16x16x32_bf16(af, bb, accS, 0, 0, 0);
    }
    *(f32x4*)&stloc[((size_t)(b * NCHUNKS + cidx) * NHEADS + h) * 256 + fr * 16 + 4 * g] = accS;
  }

  // Y_diag strips
  const int strips[4] = { wid, 7 - wid, 8 + wid, 15 - wid };
  const f32x4 zf = { 0.f, 0.f, 0.f, 0.f };
  const unsigned short* Cbase = Co + ((size_t)b * SEQLEN + (size_t)cidx * CHUNK) * D_STATE;
#pragma unroll
  for (int q = 0; q < 4; ++q) {
    const int lt = strips[q];
    f32x4 acc = zf;
    bf16x8 cf = { 0, 0, 0, 0, 0, 0, 0, 0 };
    if (g < 2) cf = *(const bf16x8*)(Cbase + (lt * 16 + fr) * D_STATE + 8 * g);
    const float acl = sc[lt * 16 + fr];
    const int   lg  = lt * 16 + fr;
    const int npair = (lt + 2) >> 1;
    for (int sp = 0; sp < npair; ++sp) {
#pragma unroll
      for (int ti = 0; ti < 2; ++ti) {
        const int st = 2 * sp + ti;
        if (st <= lt) {
          bf16x8 bfg = *(const bf16x8*)&Bs[(st * 16 + fr) * 24 + 8 * g];
          f32x4 G = __builtin_amdgcn_mfma_f32_16x16x32_bf16(bfg, cf, zf, 0, 0, 0);
          f32x4 se = *(const f32x4*)&sc[st * 16 + 4 * g];
          uint2 pk;
          {
            const int sbase = st * 16 + 4 * g;
            float w0 = (sbase + 0 <= lg) ? __expf(acl - se[0]) : 0.f;
            float w1 = (sbase + 1 <= lg) ? __expf(acl - se[1]) : 0.f;
            float w2 = (sbase + 2 <= lg) ? __expf(acl - se[2]) : 0.f;
            float w3 = (sbase + 3 <= lg) ? __expf(acl - se[3]) : 0.f;
            pk.x = (unsigned)f2bf(G[0] * w0) | ((unsigned)f2bf(G[1] * w1) << 16);
            pk.y = (unsigned)f2bf(G[2] * w2) | ((unsigned)f2bf(G[3] * w3) << 16);
          }
          *(uint2*)&Ps[wid][fr * 40 + 16 * ti + 4 * g] = pk;
        } else {
          uint2 zz; zz.x = 0u; zz.y = 0u;
          *(uint2*)&Ps[wid][fr * 40 + 16 * ti + 4 * g] = zz;
        }
      }
      const bf16x8 pf = *(const bf16x8*)&Ps[wid][fr * 40 + 8 * g];
      const bf16x8 xf = *(const bf16x8*)&xsT[fr * 264 + sp * 32 + 8 * g];
      acc = __builtin_amdgcn_mfma_f32_16x16x32_bf16(xf, pf, acc, 0, 0, 0);
    }
    us4v o = { f2bf(acc[0]), f2bf(acc[1]), f2bf(acc[2]), f2bf(acc[3]) };
    *(us4v*)(YdT + ((size_t)(b * NHEADS + h) * SEQLEN + (size_t)cidx * CHUNK + lt * 16 + fr) * HEADDIM
             + 4 * g) = o;
  }
}

// ---------------------------------------------------------------------------
// K4: sequential inter-chunk state recurrence ([p][n] layout)
// ---------------------------------------------------------------------------
__global__ __launch_bounds__(256)
void chunk_scan_kernel(const float* __restrict__ stloc, const float* __restrict__ csum_g,
                       float* __restrict__ stpre) {
  const int b  = blockIdx.x / NHEADS;
  const int h  = blockIdx.x % NHEADS;
  const int pn = threadIdx.x;
  float S = 0.0f;
  for (int c = 0; c < NCHUNKS; ++c) {
    const size_t idx = ((size_t)(b * NCHUNKS + c) * NHEADS + h) * 256 + pn;
    stpre[idx] = S;
    S = __expf(csum_g[(b * NHEADS + h) * NCHUNKS + c]) * S + stloc[idx];
  }
}

// ---------------------------------------------------------------------------
// K5 (tiled): Y_off + D*x, silu(z) gate, RMSNorm -> row-major bf16 yn.
// ---------------------------------------------------------------------------
#define TT 16
__global__ __launch_bounds__(384)
void yoff_norm_tiled(const unsigned short* __restrict__ YdT, const unsigned short* __restrict__ xoT,
                     const unsigned short* __restrict__ Co, const float* __restrict__ acum_g,
                     const float* __restrict__ stpre, const float* __restrict__ Dvec,
                     const unsigned short* __restrict__ zxbdt, const float* __restrict__ norm_w,
                     unsigned short* __restrict__ yn) {
  const int r0   = blockIdx.x * TT;
  const int b    = r0 / SEQLEN;
  const int t0   = r0 % SEQLEN;
  const int cidx = t0 / CHUNK;
  const int d    = threadIdx.x;
  const int h    = d >> 4, p = d & 15;
  const int wv   = d >> 6;

  __shared__ unsigned short Yt[NHEADS * TT * 16];
  __shared__ unsigned short Xt[NHEADS * TT * 16];
  __shared__ float At[NHEADS * TT];
  __shared__ float Ct[TT * 16];
  __shared__ float red[TT][6];

  {
    us8v* Yt8 = (us8v*)Yt;
    us8v* Xt8 = (us8v*)Xt;
#pragma unroll
    for (int rep = 0; rep < 2; ++rep) {
      int j = d + rep * 384;
      int hh = j >> 5, q = j & 31;
      const size_t src = ((size_t)(b * NHEADS + hh) * SEQLEN + t0) * HEADDIM + q * 8;
      Yt8[j] = *(const us8v*)(YdT + src);
      Xt8[j] = *(const us8v*)(xoT + src);
    }
    At[d] = acum_g[(size_t)(b * NHEADS + (d >> 4)) * SEQLEN + t0 + (d & 15)];
    if (d < TT * 16) Ct[d] = bf2f(Co[(size_t)r0 * D_STATE + d]);
  }

  float S[16];
  {
    const float* Sp = stpre + ((size_t)(b * NCHUNKS + cidx) * NHEADS + h) * 256 + p * 16;
#pragma unroll
    for (int q = 0; q < 4; ++q) {
      float4 v4 = *(const float4*)(Sp + 4 * q);
      S[4 * q + 0] = v4.x; S[4 * q + 1] = v4.y; S[4 * q + 2] = v4.z; S[4 * q + 3] = v4.w;
    }
  }
  const float Dh = Dvec[h];
  const float nw = norm_w[d];
  __syncthreads();

  float yg[TT];
#pragma unroll
  for (int tt = 0; tt < TT; ++tt) {
    float dot = 0.f;
#pragma unroll
    for (int n = 0; n < 16; ++n) dot += Ct[tt * 16 + n] * S[n];
    const float acl = At[h * TT + tt];
    float y = bf2f(Yt[h * 256 + tt * 16 + p]) + __expf(acl) * dot
            + Dh * bf2f(Xt[h * 256 + tt * 16 + p]);
    const float z = bf2f(zxbdt[(size_t)(r0 + tt) * D_IN_PROJ + d]);
    yg[tt] = y * silu_f(z);
    float s = yg[tt] * yg[tt];
#pragma unroll
    for (int off = 32; off > 0; off >>= 1) s += __shfl_down(s, off);
    if ((d & 63) == 0) red[tt][wv] = s;
  }
  __syncthreads();

#pragma unroll
  for (int tt = 0; tt < TT; ++tt) {
    const float tot = red[tt][0] + red[tt][1] + red[tt][2] + red[tt][3] + red[tt][4] + red[tt][5];
    const float scale = rsqrtf(tot * (1.0f / D_INNER) + EPS);
    yn[(size_t)(r0 + tt) * D_INNER + d] = f2bf(yg[tt] * scale * nw);
  }
}

// ---------------------------------------------------------------------------
extern "C" void kernel_launch(void* const* d_in, const int* in_sizes, int n_in,
                              void* d_out, int out_size, void* d_ws, size_t ws_size,
                              hipStream_t stream) {
  const float* u        = (const float*)d_in[0];
  const float* support  = (const float*)d_in[1];
  const float* W_in     = (const float*)d_in[2];
  const float* W_in_b   = (const float*)d_in[3];
  const float* conv_w   = (const float*)d_in[4];
  const float* conv_b   = (const float*)d_in[5];
  const float* conv_w_b = (const float*)d_in[6];
  const float* conv_b_b = (const float*)d_in[7];
  const float* dt_bias  = (const float*)d_in[8];
  const float* A_log    = (const float*)d_in[9];
  const float* Dvec     = (const float*)d_in[10];
  const float* norm_w   = (const float*)d_in[11];
  const float* W_out    = (const float*)d_in[12];
  float* out = (float*)d_out;
  char* wsb  = (char*)d_ws;

  unsigned short* Wi_b  = (unsigned short*)(wsb);
  unsigned short* Wo_b  = Wi_b + (size_t)D_IN_PROJ * D_MODEL;
  unsigned short* zxbdt = Wo_b + (size_t)D_MODEL * D_INNER;
  unsigned short* xoT   = zxbdt + (size_t)ROWS * D_IN_PROJ;      // [b][h][t][16]
  unsigned short* Bo    = xoT + (size_t)ROWS * D_INNER;          // [b][t][16]
  unsigned short* Co    = Bo + (size_t)ROWS * D_STATE;           // [b][t][16]
  unsigned short* YdT   = Co + (size_t)ROWS * D_STATE;           // [b][h][t][16]
  unsigned short* yn    = YdT + (size_t)ROWS * D_INNER;          // [row][384]
  float* cproj = (float*)(yn + (size_t)ROWS * D_INNER);
  float* dtoT  = cproj + (size_t)ROWS * D_STATE;                 // [b][h][t]
  float* acum  = dtoT  + (size_t)ROWS * NHEADS;                  // [b][h][t]
  float* csum  = acum  + (size_t)BATCH * NHEADS * SEQLEN;
  float* stloc = csum  + (size_t)BATCH * NHEADS * NCHUNKS;
  float* stpre = stloc + (size_t)BATCH * NCHUNKS * NHEADS * 256;

  // K0: convert W_in, W_out to bf16 (weights only)
  cvt2_kernel<<<224, 256, 0, stream>>>(W_in, Wi_b, (long)D_IN_PROJ * D_MODEL,
                                       W_out, Wo_b, (long)D_MODEL * D_INNER);
  // K1a: zxbdt = u @ W_in^T  (A fp32 converted in staging, bf16 out)
  gemm_bf16<true, true><<<dim3((D_IN_PROJ + 127) / 128, ROWS / 128), 256, 0, stream>>>(
      u, Wi_b, zxbdt, ROWS, D_IN_PROJ, D_MODEL);
  // K1b: cproj = support @ W_in_b^T (tiny, fp32 SIMT)
  gemm_nt<64, 16, 16, 4, 1><<<dim3(1, ROWS / 64), 256, 0, stream>>>(
      support, W_in_b, cproj, ROWS, D_STATE, D_MODEL);
  // K2
  conv_dt_row<<<ROWS, 448, 0, stream>>>(zxbdt, cproj, conv_w, conv_b, conv_w_b,
                                        conv_b_b, dt_bias, xoT, Bo, Co, dtoT);
  // K3
  ssd_mfma_kernel<<<dim3(NHEADS, NCHUNKS, BATCH), 256, 0, stream>>>(
      xoT, Bo, Co, dtoT, A_log, YdT, acum, csum, stloc);
  // K4
  chunk_scan_kernel<<<BATCH * NHEADS, 256, 0, stream>>>(stloc, csum, stpre);
  // K5
  yoff_norm_tiled<<<ROWS / TT, 384, 0, stream>>>(YdT, xoT, Co, acum, stpre, Dvec, zxbdt,
                                                 norm_w, yn);
  // K6: out = yn @ W_out^T  (bf16 A, fp32 out)
  gemm_bf16<false, false><<<dim3((D_MODEL + 127) / 128, ROWS / 128), 256, 0, stream>>>(
      yn, Wo_b, out, ROWS, D_MODEL, D_INNER);
}

// Round 11
// 143.345 us; speedup vs baseline: 1.1138x; 1.1138x over previous
//
#include <hip/hip_runtime.h>
#include <cmath>

#define ROWS      16384
#define SEQLEN    8192
#define BATCH     2
#define NHEADS    24
#define HEADDIM   16
#define D_STATE   16
#define D_INNER   384
#define D_MODEL   192
#define D_IN_PROJ 808
#define CONV_DIM  400
#define NCHUNKS   32
#define CHUNK     256
#define EPS       1e-5f
#define LOG2E     1.44269504088896f

typedef short bf16x8 __attribute__((ext_vector_type(8)));
typedef float f32x4  __attribute__((ext_vector_type(4)));
typedef unsigned short us4v __attribute__((ext_vector_type(4)));
typedef unsigned short us8v __attribute__((ext_vector_type(8)));

__device__ __forceinline__ float silu_f(float x) { return x / (1.0f + expf(-x)); }
__device__ __forceinline__ float softplus_f(float x) { return (x > 20.0f) ? x : log1pf(expf(x)); }
__device__ __forceinline__ unsigned short f2bf(float x) {
  unsigned u = __builtin_bit_cast(unsigned, x);
  u += 0x7fff + ((u >> 16) & 1);
  return (unsigned short)(u >> 16);
}
__device__ __forceinline__ float bf2f(unsigned short s) {
  unsigned u = (unsigned)s << 16;
  return __builtin_bit_cast(float, u);
}
// pack two f32 -> bf16x2 word (lo = a, hi = b), round-to-nearest (half-ulp)
__device__ __forceinline__ unsigned pk_bf(float a, float b) {
  unsigned ua = __builtin_bit_cast(unsigned, a) + 0x7fffu;
  unsigned ub = __builtin_bit_cast(unsigned, b) + 0x7fffu;
  return __builtin_amdgcn_perm(ub, ua, 0x07060302u);
}

// ---------------------------------------------------------------------------
// K0: fp32 -> bf16 conversion for W_in, W_out, W_in_b (weights only)
// ---------------------------------------------------------------------------
__global__ __launch_bounds__(256)
void cvt3_kernel(const float* __restrict__ a, unsigned short* __restrict__ ao, long na,
                 const float* __restrict__ b, unsigned short* __restrict__ bo, long nb,
                 const float* __restrict__ c, unsigned short* __restrict__ co, long nc) {
  const long t0 = na >> 2, t1 = t0 + (nb >> 2), t2 = t1 + (nc >> 2);
  const long stride = (long)gridDim.x * blockDim.x;
  for (long i = (long)blockIdx.x * blockDim.x + threadIdx.x; i < t2; i += stride) {
    const float4* s; us4v* d; long j;
    if (i < t0)      { s = (const float4*)a; d = (us4v*)ao; j = i; }
    else if (i < t1) { s = (const float4*)b; d = (us4v*)bo; j = i - t0; }
    else             { s = (const float4*)c; d = (us4v*)co; j = i - t1; }
    float4 v = s[j];
    us4v o = { f2bf(v.x), f2bf(v.y), f2bf(v.z), f2bf(v.w) };
    d[j] = o;
  }
}

// ---------------------------------------------------------------------------
// MFMA bf16 GEMM: C[M,N] = A[M,K] * W[N,K]^T. A fp32 (converted in staging)
// or bf16; out bf16 or fp32. Double-buffered LDS; operand-swapped MFMA for
// packed epilogue stores.
// ---------------------------------------------------------------------------
template<bool A_F32, bool OUT_BF16>
__launch_bounds__(256, 3)
__global__ void gemm_bf16(const void* __restrict__ Ap,
                          const unsigned short* __restrict__ W,
                          void* __restrict__ Cp, int M, int N, int K) {
  constexpr int BM = 128, BN = 128, BK = 32, LDK = 40;
  __shared__ unsigned short As[2][BM * LDK];
  __shared__ unsigned short Ws[2][BN * LDK];
  const int tid  = threadIdx.x;
  const int wid  = tid >> 6, lane = tid & 63;
  const int wr   = wid >> 1, wc = wid & 1;
  const int fr   = lane & 15, fq = lane >> 4;
  const long m0  = (long)blockIdx.y * BM;
  const int  n0  = blockIdx.x * BN;

  f32x4 acc[4][4] = {};

  auto stage = [&](int k0, int buf) {
    if (A_F32) {
      const float* A = (const float*)Ap;
#pragma unroll
      for (int p = 0; p < 2; ++p) {
        int flat = p * 2048 + tid * 8;
        int r = flat >> 5, c = flat & 31;
        const float4* src = (const float4*)(A + (m0 + r) * (long)K + k0 + c);
        float4 v0 = src[0], v1 = src[1];
        us8v o = { f2bf(v0.x), f2bf(v0.y), f2bf(v0.z), f2bf(v0.w),
                   f2bf(v1.x), f2bf(v1.y), f2bf(v1.z), f2bf(v1.w) };
        *(us8v*)&As[buf][r * LDK + c] = o;
      }
    } else {
      const unsigned short* A = (const unsigned short*)Ap;
#pragma unroll
      for (int p = 0; p < 2; ++p) {
        int flat = p * 2048 + tid * 8;
        int r = flat >> 5, c = flat & 31;
        us8v v = *(const us8v*)(A + (m0 + r) * (long)K + k0 + c);
        *(us8v*)&As[buf][r * LDK + c] = v;
      }
    }
#pragma unroll
    for (int p = 0; p < 2; ++p) {
      int flat = p * 2048 + tid * 8;
      int r = flat >> 5, c = flat & 31;
      int gn = n0 + r;
      us8v v = { 0, 0, 0, 0, 0, 0, 0, 0 };
      if (gn < N) v = *(const us8v*)(W + (long)gn * K + k0 + c);
      *(us8v*)&Ws[buf][r * LDK + c] = v;
    }
  };

  const int nk = K / BK;
  stage(0, 0);
  __syncthreads();
  for (int kt = 0; kt < nk; ++kt) {
    const int cur = kt & 1;
    if (kt + 1 < nk) stage((kt + 1) * BK, cur ^ 1);
    bf16x8 af[4], bfr[4];
#pragma unroll
    for (int m = 0; m < 4; ++m)
      af[m] = *(const bf16x8*)&As[cur][(wr * 64 + m * 16 + fr) * LDK + fq * 8];
#pragma unroll
    for (int n = 0; n < 4; ++n)
      bfr[n] = *(const bf16x8*)&Ws[cur][(wc * 64 + n * 16 + fr) * LDK + fq * 8];
#pragma unroll
    for (int m = 0; m < 4; ++m)
#pragma unroll
      for (int n = 0; n < 4; ++n)
        acc[m][n] = __builtin_amdgcn_mfma_f32_16x16x32_bf16(bfr[n], af[m], acc[m][n], 0, 0, 0);
    __syncthreads();
  }

#pragma unroll
  for (int m = 0; m < 4; ++m) {
    const long gm = m0 + wr * 64 + m * 16 + fr;
#pragma unroll
    for (int n = 0; n < 4; ++n) {
      const int gn = n0 + wc * 64 + n * 16 + fq * 4;
      if (gn < N) {
        if (OUT_BF16) {
          us4v o = { f2bf(acc[m][n][0]), f2bf(acc[m][n][1]),
                     f2bf(acc[m][n][2]), f2bf(acc[m][n][3]) };
          *(us4v*)((unsigned short*)Cp + gm * N + gn) = o;
        } else {
          float4 o = make_float4(acc[m][n][0], acc[m][n][1], acc[m][n][2], acc[m][n][3]);
          *(float4*)((float*)Cp + gm * N + gn) = o;
        }
      }
    }
  }
}

// ---------------------------------------------------------------------------
// K2: per-row depthwise causal conv + silu + dt softplus.
// XCD-aware row swizzle: each XCD walks a contiguous 2048-row stripe so the
// 4-row conv window stays L2-resident.
// ---------------------------------------------------------------------------
__global__ __launch_bounds__(448)
void conv_dt_row(const unsigned short* __restrict__ zxbdt, const float* __restrict__ cproj,
                 const float* __restrict__ conv_w, const float* __restrict__ conv_b,
                 const float* __restrict__ conv_w_b, const float* __restrict__ conv_b_b,
                 const float* __restrict__ dt_bias,
                 unsigned short* __restrict__ xoT, unsigned short* __restrict__ Bo,
                 unsigned short* __restrict__ Co, float* __restrict__ dtoT) {
  const int bid = blockIdx.x;
  const int row = ((bid & 7) * (ROWS / 8)) + (bid >> 3);
  const int b   = row / SEQLEN, t = row % SEQLEN;
  const int c   = threadIdx.x;

  if (c < CONV_DIM) {
    const float4 wv = *(const float4*)(conv_w + c * 4);
    const unsigned short* base = zxbdt + (size_t)row * D_IN_PROJ + D_INNER + c;
    const float x0 = (t >= 3) ? bf2f(base[-3 * D_IN_PROJ]) : 0.0f;
    const float x1 = (t >= 2) ? bf2f(base[-2 * D_IN_PROJ]) : 0.0f;
    const float x2 = (t >= 1) ? bf2f(base[-1 * D_IN_PROJ]) : 0.0f;
    const float x3 = bf2f(base[0]);
    float acc = conv_b[c] + wv.x * x0 + wv.y * x1 + wv.z * x2 + wv.w * x3;
    unsigned short y = f2bf(silu_f(acc));
    if (c < D_INNER) {
      const int h = c >> 4, i = c & 15;
      xoT[((size_t)(b * NHEADS + h) * SEQLEN + t) * HEADDIM + i] = y;
    } else {
      Bo[(size_t)row * D_STATE + (c - D_INNER)] = y;
    }
  } else if (c < CONV_DIM + D_STATE) {
    const int cc = c - CONV_DIM;
    const float4 wv = *(const float4*)(conv_w_b + cc * 4);
    const float* base = cproj + (size_t)row * D_STATE + cc;
    const float x0 = (t >= 3) ? base[-3 * D_STATE] : 0.0f;
    const float x1 = (t >= 2) ? base[-2 * D_STATE] : 0.0f;
    const float x2 = (t >= 1) ? base[-1 * D_STATE] : 0.0f;
    const float x3 = base[0];
    float acc = conv_b_b[cc] + wv.x * x0 + wv.y * x1 + wv.z * x2 + wv.w * x3;
    Co[(size_t)row * D_STATE + cc] = f2bf(silu_f(acc));
  } else if (c < CONV_DIM + D_STATE + NHEADS) {
    const int h = c - CONV_DIM - D_STATE;
    float v = bf2f(zxbdt[(size_t)row * D_IN_PROJ + (D_IN_PROJ - NHEADS) + h]) + dt_bias[h];
    dtoT[(size_t)(b * NHEADS + h) * SEQLEN + t] = softplus_f(v);
  }
}

// ---------------------------------------------------------------------------
// K3 (MFMA): per (h, chunk, b) block, 4 waves. Head-major in/out. ~37KB LDS.
// VALU diet: diagonal-only masking, exp2 with pre-scaled cumsum, perm-pack.
// ---------------------------------------------------------------------------
__global__ __launch_bounds__(256, 4)
void ssd_mfma_kernel(const unsigned short* __restrict__ xoT, const unsigned short* __restrict__ Bo,
                     const unsigned short* __restrict__ Co, const float* __restrict__ dtoT,
                     const float* __restrict__ A_log,
                     unsigned short* __restrict__ YdT, float* __restrict__ acum_g,
                     float* __restrict__ csum_g, float* __restrict__ stloc) {
  const int h    = blockIdx.x;
  const int cidx = blockIdx.y;
  const int b    = blockIdx.z;
  const int l    = threadIdx.x;
  const int t    = cidx * CHUNK + l;
  const size_t row  = (size_t)b * SEQLEN + t;
  const size_t hrow = (size_t)(b * NHEADS + h) * SEQLEN + t;
  const int wid = l >> 6, lane = l & 63;
  const int fr  = lane & 15, g = lane >> 4;

  __shared__ unsigned short Bs[256 * 24 + 32];
  __shared__ unsigned short xsT[16 * 264];
  __shared__ unsigned short BwT[16 * 264];
  __shared__ unsigned short Ps[4][16 * 40];
  __shared__ float sc[CHUNK];
  __shared__ float sc2[CHUNK];       // cumsum * log2(e) for exp2
  __shared__ float wsum[4];

  const float Ah  = -expf(A_log[h]);
  const float dtv = dtoT[hrow];

  float v = dtv * Ah;
#pragma unroll
  for (int off = 1; off < 64; off <<= 1) {
    float u = __shfl_up(v, off, 64);
    if (lane >= off) v += u;
  }
  if (lane == 63) wsum[wid] = v;

  us8v b0, b1;
  {
    const us8v z8 = { 0, 0, 0, 0, 0, 0, 0, 0 };
    const us8v* bp = (const us8v*)(Bo + row * D_STATE);
    b0 = bp[0]; b1 = bp[1];
    *(us8v*)&Bs[l * 24 + 0] = b0;
    *(us8v*)&Bs[l * 24 + 8] = b1;
    *(us8v*)&Bs[l * 24 + 16] = z8;
    if (l < 32) Bs[256 * 24 + l] = 0;
    const us8v* xp = (const us8v*)(xoT + hrow * HEADDIM);
    us8v x0 = xp[0], x1 = xp[1];
#pragma unroll
    for (int q = 0; q < 8; ++q) {
      xsT[q * 264 + l]       = f2bf(bf2f(x0[q]) * dtv);
      xsT[(q + 8) * 264 + l] = f2bf(bf2f(x1[q]) * dtv);
    }
  }
  __syncthreads();   // #1

  float pre = 0.f, ctot = 0.f;
#pragma unroll
  for (int w = 0; w < 4; ++w) {
    float s = wsum[w];
    if (w < wid) pre += s;
    ctot += s;
  }
  v += pre;
  sc[l]  = v;
  sc2[l] = v * LOG2E;
  acum_g[hrow] = v;
  if (l == CHUNK - 1) csum_g[(b * NHEADS + h) * NCHUNKS + cidx] = v;
  const float wdv = __expf(ctot - v);
#pragma unroll
  for (int q = 0; q < 8; ++q) {
    BwT[q * 264 + l]       = f2bf(bf2f(b0[q]) * wdv);
    BwT[(q + 8) * 264 + l] = f2bf(bf2f(b1[q]) * wdv);
  }
  __syncthreads();   // #2

  // chunk state: wave 0 computes all of K=256 (8 MFMAs), writes stloc direct
  if (wid == 0) {
    f32x4 accS = {};
#pragma unroll
    for (int k2 = 0; k2 < 8; ++k2) {
      bf16x8 af = *(const bf16x8*)&BwT[fr * 264 + 32 * k2 + 8 * g];
      bf16x8 bb = *(const bf16x8*)&xsT[fr * 264 + 32 * k2 + 8 * g];
      accS = __builtin_amdgcn_mfma_f32_16x16x32_bf16(af, bb, accS, 0, 0, 0);
    }
    *(f32x4*)&stloc[((size_t)(b * NCHUNKS + cidx) * NHEADS + h) * 256 + fr * 16 + 4 * g] = accS;
  }

  // Y_diag strips
  const int strips[4] = { wid, 7 - wid, 8 + wid, 15 - wid };
  const f32x4 zf = { 0.f, 0.f, 0.f, 0.f };
  const unsigned short* Cbase = Co + ((size_t)b * SEQLEN + (size_t)cidx * CHUNK) * D_STATE;
#pragma unroll
  for (int q = 0; q < 4; ++q) {
    const int lt = strips[q];
    f32x4 acc = zf;
    bf16x8 cf = { 0, 0, 0, 0, 0, 0, 0, 0 };
    if (g < 2) cf = *(const bf16x8*)(Cbase + (lt * 16 + fr) * D_STATE + 8 * g);
    const float acl2 = sc2[lt * 16 + fr];
    const int   lg   = lt * 16 + fr;
    const int npair = (lt + 2) >> 1;
    for (int sp = 0; sp < npair; ++sp) {
#pragma unroll
      for (int ti = 0; ti < 2; ++ti) {
        const int st = 2 * sp + ti;
        if (st < lt) {
          // strictly sub-diagonal: no masking needed (all s < all l)
          bf16x8 bfg = *(const bf16x8*)&Bs[(st * 16 + fr) * 24 + 8 * g];
          f32x4 G = __builtin_amdgcn_mfma_f32_16x16x32_bf16(bfg, cf, zf, 0, 0, 0);
          f32x4 se2 = *(const f32x4*)&sc2[st * 16 + 4 * g];
          float w0 = exp2f(acl2 - se2[0]);
          float w1 = exp2f(acl2 - se2[1]);
          float w2 = exp2f(acl2 - se2[2]);
          float w3 = exp2f(acl2 - se2[3]);
          uint2 pk;
          pk.x = pk_bf(G[0] * w0, G[1] * w1);
          pk.y = pk_bf(G[2] * w2, G[3] * w3);
          *(uint2*)&Ps[wid][fr * 40 + 16 * ti + 4 * g] = pk;
        } else if (st == lt) {
          // diagonal tile: mask s <= l
          bf16x8 bfg = *(const bf16x8*)&Bs[(st * 16 + fr) * 24 + 8 * g];
          f32x4 G = __builtin_amdgcn_mfma_f32_16x16x32_bf16(bfg, cf, zf, 0, 0, 0);
          f32x4 se2 = *(const f32x4*)&sc2[st * 16 + 4 * g];
          const int sbase = st * 16 + 4 * g;
          float w0 = (sbase + 0 <= lg) ? exp2f(acl2 - se2[0]) : 0.f;
          float w1 = (sbase + 1 <= lg) ? exp2f(acl2 - se2[1]) : 0.f;
          float w2 = (sbase + 2 <= lg) ? exp2f(acl2 - se2[2]) : 0.f;
          float w3 = (sbase + 3 <= lg) ? exp2f(acl2 - se2[3]) : 0.f;
          uint2 pk;
          pk.x = pk_bf(G[0] * w0, G[1] * w1);
          pk.y = pk_bf(G[2] * w2, G[3] * w3);
          *(uint2*)&Ps[wid][fr * 40 + 16 * ti + 4 * g] = pk;
        } else {
          uint2 zz; zz.x = 0u; zz.y = 0u;
          *(uint2*)&Ps[wid][fr * 40 + 16 * ti + 4 * g] = zz;
        }
      }
      const bf16x8 pf = *(const bf16x8*)&Ps[wid][fr * 40 + 8 * g];
      const bf16x8 xf = *(const bf16x8*)&xsT[fr * 264 + sp * 32 + 8 * g];
      acc = __builtin_amdgcn_mfma_f32_16x16x32_bf16(xf, pf, acc, 0, 0, 0);
    }
    us4v o = { f2bf(acc[0]), f2bf(acc[1]), f2bf(acc[2]), f2bf(acc[3]) };
    *(us4v*)(YdT + ((size_t)(b * NHEADS + h) * SEQLEN + (size_t)cidx * CHUNK + lt * 16 + fr) * HEADDIM
             + 4 * g) = o;
  }
}

// ---------------------------------------------------------------------------
// K4: sequential inter-chunk state recurrence ([p][n] layout)
// ---------------------------------------------------------------------------
__global__ __launch_bounds__(256)
void chunk_scan_kernel(const float* __restrict__ stloc, const float* __restrict__ csum_g,
                       float* __restrict__ stpre) {
  const int b  = blockIdx.x / NHEADS;
  const int h  = blockIdx.x % NHEADS;
  const int pn = threadIdx.x;
  float S = 0.0f;
  for (int c = 0; c < NCHUNKS; ++c) {
    const size_t idx = ((size_t)(b * NCHUNKS + c) * NHEADS + h) * 256 + pn;
    stpre[idx] = S;
    S = __expf(csum_g[(b * NHEADS + h) * NCHUNKS + c]) * S + stloc[idx];
  }
}

// ---------------------------------------------------------------------------
// K5 (tiled): Y_off + D*x, silu(z) gate, RMSNorm -> row-major bf16 yn.
// ---------------------------------------------------------------------------
#define TT 16
__global__ __launch_bounds__(384)
void yoff_norm_tiled(const unsigned short* __restrict__ YdT, const unsigned short* __restrict__ xoT,
                     const unsigned short* __restrict__ Co, const float* __restrict__ acum_g,
                     const float* __restrict__ stpre, const float* __restrict__ Dvec,
                     const unsigned short* __restrict__ zxbdt, const float* __restrict__ norm_w,
                     unsigned short* __restrict__ yn) {
  const int r0   = blockIdx.x * TT;
  const int b    = r0 / SEQLEN;
  const int t0   = r0 % SEQLEN;
  const int cidx = t0 / CHUNK;
  const int d    = threadIdx.x;
  const int h    = d >> 4, p = d & 15;
  const int wv   = d >> 6;

  __shared__ unsigned short Yt[NHEADS * TT * 16];
  __shared__ unsigned short Xt[NHEADS * TT * 16];
  __shared__ float At[NHEADS * TT];
  __shared__ float Ct[TT * 16];
  __shared__ float red[TT][6];

  {
    us8v* Yt8 = (us8v*)Yt;
    us8v* Xt8 = (us8v*)Xt;
#pragma unroll
    for (int rep = 0; rep < 2; ++rep) {
      int j = d + rep * 384;
      int hh = j >> 5, q = j & 31;
      const size_t src = ((size_t)(b * NHEADS + hh) * SEQLEN + t0) * HEADDIM + q * 8;
      Yt8[j] = *(const us8v*)(YdT + src);
      Xt8[j] = *(const us8v*)(xoT + src);
    }
    At[d] = acum_g[(size_t)(b * NHEADS + (d >> 4)) * SEQLEN + t0 + (d & 15)];
    if (d < TT * 16) Ct[d] = bf2f(Co[(size_t)r0 * D_STATE + d]);
  }

  float S[16];
  {
    const float* Sp = stpre + ((size_t)(b * NCHUNKS + cidx) * NHEADS + h) * 256 + p * 16;
#pragma unroll
    for (int q = 0; q < 4; ++q) {
      float4 v4 = *(const float4*)(Sp + 4 * q);
      S[4 * q + 0] = v4.x; S[4 * q + 1] = v4.y; S[4 * q + 2] = v4.z; S[4 * q + 3] = v4.w;
    }
  }
  const float Dh = Dvec[h];
  const float nw = norm_w[d];
  __syncthreads();

  float yg[TT];
#pragma unroll
  for (int tt = 0; tt < TT; ++tt) {
    float dot = 0.f;
#pragma unroll
    for (int n = 0; n < 16; ++n) dot += Ct[tt * 16 + n] * S[n];
    const float acl = At[h * TT + tt];
    float y = bf2f(Yt[h * 256 + tt * 16 + p]) + __expf(acl) * dot
            + Dh * bf2f(Xt[h * 256 + tt * 16 + p]);
    const float z = bf2f(zxbdt[(size_t)(r0 + tt) * D_IN_PROJ + d]);
    yg[tt] = y * silu_f(z);
    float s = yg[tt] * yg[tt];
#pragma unroll
    for (int off = 32; off > 0; off >>= 1) s += __shfl_down(s, off);
    if ((d & 63) == 0) red[tt][wv] = s;
  }
  __syncthreads();

#pragma unroll
  for (int tt = 0; tt < TT; ++tt) {
    const float tot = red[tt][0] + red[tt][1] + red[tt][2] + red[tt][3] + red[tt][4] + red[tt][5];
    const float scale = rsqrtf(tot * (1.0f / D_INNER) + EPS);
    yn[(size_t)(r0 + tt) * D_INNER + d] = f2bf(yg[tt] * scale * nw);
  }
}

// ---------------------------------------------------------------------------
extern "C" void kernel_launch(void* const* d_in, const int* in_sizes, int n_in,
                              void* d_out, int out_size, void* d_ws, size_t ws_size,
                              hipStream_t stream) {
  const float* u        = (const float*)d_in[0];
  const float* support  = (const float*)d_in[1];
  const float* W_in     = (const float*)d_in[2];
  const float* W_in_b   = (const float*)d_in[3];
  const float* conv_w   = (const float*)d_in[4];
  const float* conv_b   = (const float*)d_in[5];
  const float* conv_w_b = (const float*)d_in[6];
  const float* conv_b_b = (const float*)d_in[7];
  const float* dt_bias  = (const float*)d_in[8];
  const float* A_log    = (const float*)d_in[9];
  const float* Dvec     = (const float*)d_in[10];
  const float* norm_w   = (const float*)d_in[11];
  const float* W_out    = (const float*)d_in[12];
  float* out = (float*)d_out;
  char* wsb  = (char*)d_ws;

  unsigned short* Wi_b  = (unsigned short*)(wsb);
  unsigned short* Wo_b  = Wi_b + (size_t)D_IN_PROJ * D_MODEL;
  unsigned short* Wib_b = Wo_b + (size_t)D_MODEL * D_INNER;       // 16*192
  unsigned short* zxbdt = Wib_b + (size_t)D_STATE * D_MODEL;
  unsigned short* xoT   = zxbdt + (size_t)ROWS * D_IN_PROJ;       // [b][h][t][16]
  unsigned short* Bo    = xoT + (size_t)ROWS * D_INNER;           // [b][t][16]
  unsigned short* Co    = Bo + (size_t)ROWS * D_STATE;            // [b][t][16]
  unsigned short* YdT   = Co + (size_t)ROWS * D_STATE;            // [b][h][t][16]
  unsigned short* yn    = YdT + (size_t)ROWS * D_INNER;           // [row][384]
  float* cproj = (float*)(yn + (size_t)ROWS * D_INNER);
  float* dtoT  = cproj + (size_t)ROWS * D_STATE;                  // [b][h][t]
  float* acum  = dtoT  + (size_t)ROWS * NHEADS;                   // [b][h][t]
  float* csum  = acum  + (size_t)BATCH * NHEADS * SEQLEN;
  float* stloc = csum  + (size_t)BATCH * NHEADS * NCHUNKS;
  float* stpre = stloc + (size_t)BATCH * NCHUNKS * NHEADS * 256;

  // K0: convert W_in, W_out, W_in_b to bf16
  cvt3_kernel<<<224, 256, 0, stream>>>(W_in, Wi_b, (long)D_IN_PROJ * D_MODEL,
                                       W_out, Wo_b, (long)D_MODEL * D_INNER,
                                       W_in_b, Wib_b, (long)D_STATE * D_MODEL);
  // K1a: zxbdt = u @ W_in^T  (A fp32 converted in staging, bf16 out)
  gemm_bf16<true, true><<<dim3((D_IN_PROJ + 127) / 128, ROWS / 128), 256, 0, stream>>>(
      u, Wi_b, zxbdt, ROWS, D_IN_PROJ, D_MODEL);
  // K1b: cproj = support @ W_in_b^T  (MFMA, N=16, fp32 out)
  gemm_bf16<true, false><<<dim3(1, ROWS / 128), 256, 0, stream>>>(
      support, Wib_b, cproj, ROWS, D_STATE, D_MODEL);
  // K2
  conv_dt_row<<<ROWS, 448, 0, stream>>>(zxbdt, cproj, conv_w, conv_b, conv_w_b,
                                        conv_b_b, dt_bias, xoT, Bo, Co, dtoT);
  // K3
  ssd_mfma_kernel<<<dim3(NHEADS, NCHUNKS, BATCH), 256, 0, stream>>>(
      xoT, Bo, Co, dtoT, A_log, YdT, acum, csum, stloc);
  // K4
  chunk_scan_kernel<<<BATCH * NHEADS, 256, 0, stream>>>(stloc, csum, stpre);
  // K5
  yoff_norm_tiled<<<ROWS / TT, 384, 0, stream>>>(YdT, xoT, Co, acum, stpre, Dvec, zxbdt,
                                                 norm_w, yn);
  // K6: out = yn @ W_out^T  (bf16 A, fp32 out)
  gemm_bf16<false, false><<<dim3((D_MODEL + 127) / 128, ROWS / 128), 256, 0, stream>>>(
      yn, Wo_b, out, ROWS, D_MODEL, D_INNER);
}

// Round 12
// 133.419 us; speedup vs baseline: 1.1966x; 1.0744x over previous
//
#include <hip/hip_runtime.h>
#include <cmath>

#define ROWS      16384
#define SEQLEN    8192
#define BATCH     2
#define NHEADS    24
#define HEADDIM   16
#define D_STATE   16
#define D_INNER   384
#define D_MODEL   192
#define D_IN_PROJ 808
#define CONV_DIM  400
#define NCHUNKS   32
#define CHUNK     256
#define EPS       1e-5f
#define LOG2E     1.44269504088896f

typedef short bf16x8 __attribute__((ext_vector_type(8)));
typedef float f32x4  __attribute__((ext_vector_type(4)));
typedef unsigned short us4v __attribute__((ext_vector_type(4)));
typedef unsigned short us8v __attribute__((ext_vector_type(8)));

__device__ __forceinline__ float silu_f(float x) { return x / (1.0f + expf(-x)); }
__device__ __forceinline__ float softplus_f(float x) { return (x > 20.0f) ? x : log1pf(expf(x)); }
__device__ __forceinline__ unsigned short f2bf(float x) {
  unsigned u = __builtin_bit_cast(unsigned, x);
  u += 0x7fff + ((u >> 16) & 1);
  return (unsigned short)(u >> 16);
}
__device__ __forceinline__ float bf2f(unsigned short s) {
  unsigned u = (unsigned)s << 16;
  return __builtin_bit_cast(float, u);
}
__device__ __forceinline__ unsigned pk_bf(float a, float b) {
  unsigned ua = __builtin_bit_cast(unsigned, a) + 0x7fffu;
  unsigned ub = __builtin_bit_cast(unsigned, b) + 0x7fffu;
  return __builtin_amdgcn_perm(ub, ua, 0x07060302u);
}

// ---------------------------------------------------------------------------
// K0: fp32 -> bf16 conversion for W_in, W_out, W_in_b (weights only)
// ---------------------------------------------------------------------------
__global__ __launch_bounds__(256)
void cvt3_kernel(const float* __restrict__ a, unsigned short* __restrict__ ao, long na,
                 const float* __restrict__ b, unsigned short* __restrict__ bo, long nb,
                 const float* __restrict__ c, unsigned short* __restrict__ co, long nc) {
  const long t0 = na >> 2, t1 = t0 + (nb >> 2), t2 = t1 + (nc >> 2);
  const long stride = (long)gridDim.x * blockDim.x;
  for (long i = (long)blockIdx.x * blockDim.x + threadIdx.x; i < t2; i += stride) {
    const float4* s; us4v* d; long j;
    if (i < t0)      { s = (const float4*)a; d = (us4v*)ao; j = i; }
    else if (i < t1) { s = (const float4*)b; d = (us4v*)bo; j = i - t0; }
    else             { s = (const float4*)c; d = (us4v*)co; j = i - t1; }
    float4 v = s[j];
    us4v o = { f2bf(v.x), f2bf(v.y), f2bf(v.z), f2bf(v.w) };
    d[j] = o;
  }
}

// ---------------------------------------------------------------------------
// MFMA bf16 GEMM (unchanged from r11)
// ---------------------------------------------------------------------------
template<bool A_F32, bool OUT_BF16>
__launch_bounds__(256, 3)
__global__ void gemm_bf16(const void* __restrict__ Ap,
                          const unsigned short* __restrict__ W,
                          void* __restrict__ Cp, int M, int N, int K) {
  constexpr int BM = 128, BN = 128, BK = 32, LDK = 40;
  __shared__ unsigned short As[2][BM * LDK];
  __shared__ unsigned short Ws[2][BN * LDK];
  const int tid  = threadIdx.x;
  const int wid  = tid >> 6, lane = tid & 63;
  const int wr   = wid >> 1, wc = wid & 1;
  const int fr   = lane & 15, fq = lane >> 4;
  const long m0  = (long)blockIdx.y * BM;
  const int  n0  = blockIdx.x * BN;

  f32x4 acc[4][4] = {};

  auto stage = [&](int k0, int buf) {
    if (A_F32) {
      const float* A = (const float*)Ap;
#pragma unroll
      for (int p = 0; p < 2; ++p) {
        int flat = p * 2048 + tid * 8;
        int r = flat >> 5, c = flat & 31;
        const float4* src = (const float4*)(A + (m0 + r) * (long)K + k0 + c);
        float4 v0 = src[0], v1 = src[1];
        us8v o = { f2bf(v0.x), f2bf(v0.y), f2bf(v0.z), f2bf(v0.w),
                   f2bf(v1.x), f2bf(v1.y), f2bf(v1.z), f2bf(v1.w) };
        *(us8v*)&As[buf][r * LDK + c] = o;
      }
    } else {
      const unsigned short* A = (const unsigned short*)Ap;
#pragma unroll
      for (int p = 0; p < 2; ++p) {
        int flat = p * 2048 + tid * 8;
        int r = flat >> 5, c = flat & 31;
        us8v v = *(const us8v*)(A + (m0 + r) * (long)K + k0 + c);
        *(us8v*)&As[buf][r * LDK + c] = v;
      }
    }
#pragma unroll
    for (int p = 0; p < 2; ++p) {
      int flat = p * 2048 + tid * 8;
      int r = flat >> 5, c = flat & 31;
      int gn = n0 + r;
      us8v v = { 0, 0, 0, 0, 0, 0, 0, 0 };
      if (gn < N) v = *(const us8v*)(W + (long)gn * K + k0 + c);
      *(us8v*)&Ws[buf][r * LDK + c] = v;
    }
  };

  const int nk = K / BK;
  stage(0, 0);
  __syncthreads();
  for (int kt = 0; kt < nk; ++kt) {
    const int cur = kt & 1;
    if (kt + 1 < nk) stage((kt + 1) * BK, cur ^ 1);
    bf16x8 af[4], bfr[4];
#pragma unroll
    for (int m = 0; m < 4; ++m)
      af[m] = *(const bf16x8*)&As[cur][(wr * 64 + m * 16 + fr) * LDK + fq * 8];
#pragma unroll
    for (int n = 0; n < 4; ++n)
      bfr[n] = *(const bf16x8*)&Ws[cur][(wc * 64 + n * 16 + fr) * LDK + fq * 8];
#pragma unroll
    for (int m = 0; m < 4; ++m)
#pragma unroll
      for (int n = 0; n < 4; ++n)
        acc[m][n] = __builtin_amdgcn_mfma_f32_16x16x32_bf16(bfr[n], af[m], acc[m][n], 0, 0, 0);
    __syncthreads();
  }

#pragma unroll
  for (int m = 0; m < 4; ++m) {
    const long gm = m0 + wr * 64 + m * 16 + fr;
#pragma unroll
    for (int n = 0; n < 4; ++n) {
      const int gn = n0 + wc * 64 + n * 16 + fq * 4;
      if (gn < N) {
        if (OUT_BF16) {
          us4v o = { f2bf(acc[m][n][0]), f2bf(acc[m][n][1]),
                     f2bf(acc[m][n][2]), f2bf(acc[m][n][3]) };
          *(us4v*)((unsigned short*)Cp + gm * N + gn) = o;
        } else {
          float4 o = make_float4(acc[m][n][0], acc[m][n][1], acc[m][n][2], acc[m][n][3]);
          *(float4*)((float*)Cp + gm * N + gn) = o;
        }
      }
    }
  }
}

// ---------------------------------------------------------------------------
// K2 v3: vectorized role-segmented conv. One thread = one row x 8 channels.
// us8v (16B) loads/stores; bf16 register window (16 VGPR, no spill);
// 3520 role-pure blocks (x: 3072, B/C: 256, dt: 192).
// ---------------------------------------------------------------------------
#define CX_NB   (ROWS * 48 / 256)   // 3072
#define CBC_NB  (ROWS * 4 / 256)    // 256
#define CDT_NB  (ROWS * 3 / 256)    // 192

__global__ __launch_bounds__(256)
void conv_dt_v3(const unsigned short* __restrict__ zxbdt, const float* __restrict__ cproj,
                const float* __restrict__ conv_w, const float* __restrict__ conv_b,
                const float* __restrict__ conv_w_b, const float* __restrict__ conv_b_b,
                const float* __restrict__ dt_bias,
                unsigned short* __restrict__ xoT, unsigned short* __restrict__ Bo,
                unsigned short* __restrict__ Co, float* __restrict__ dtoT) {
  const int blk = blockIdx.x;
  const us8v z8 = { 0, 0, 0, 0, 0, 0, 0, 0 };

  if (blk < CX_NB) {
    // ---- x channels ----
    const int idx = blk * 256 + threadIdx.x;
    const int row = idx / 48, grp = idx % 48;
    const int b = row / SEQLEN, t = row % SEQLEN;
    const int c0 = grp * 8;
    const int h = grp >> 1, i0 = (grp & 1) * 8;
    const unsigned short* base = zxbdt + (size_t)row * D_IN_PROJ + D_INNER + c0;

    us8v x0 = (t >= 3) ? *(const us8v*)(base - 3 * D_IN_PROJ) : z8;
    us8v x1 = (t >= 2) ? *(const us8v*)(base - 2 * D_IN_PROJ) : z8;
    us8v x2 = (t >= 1) ? *(const us8v*)(base - 1 * D_IN_PROJ) : z8;
    us8v x3 = *(const us8v*)base;

    us8v o;
#pragma unroll
    for (int ch = 0; ch < 8; ++ch) {
      const float4 wv = *(const float4*)(conv_w + (c0 + ch) * 4);
      float acc = conv_b[c0 + ch] + wv.x * bf2f(x0[ch]) + wv.y * bf2f(x1[ch])
                + wv.z * bf2f(x2[ch]) + wv.w * bf2f(x3[ch]);
      o[ch] = f2bf(silu_f(acc));
    }
    *(us8v*)(xoT + ((size_t)(b * NHEADS + h) * SEQLEN + t) * HEADDIM + i0) = o;
  } else if (blk < CX_NB + CBC_NB) {
    // ---- B and C ----
    const int idx = (blk - CX_NB) * 256 + threadIdx.x;
    const int row = idx / 4, q = idx % 4;
    const int b = row / SEQLEN, t = row % SEQLEN;

    if (q < 2) {
      const int c0 = q * 8;
      const unsigned short* base = zxbdt + (size_t)row * D_IN_PROJ + D_INNER + 384 + c0;
      us8v x0 = (t >= 3) ? *(const us8v*)(base - 3 * D_IN_PROJ) : z8;
      us8v x1 = (t >= 2) ? *(const us8v*)(base - 2 * D_IN_PROJ) : z8;
      us8v x2 = (t >= 1) ? *(const us8v*)(base - 1 * D_IN_PROJ) : z8;
      us8v x3 = *(const us8v*)base;
      us8v o;
#pragma unroll
      for (int ch = 0; ch < 8; ++ch) {
        const float4 wv = *(const float4*)(conv_w + (384 + c0 + ch) * 4);
        float acc = conv_b[384 + c0 + ch] + wv.x * bf2f(x0[ch]) + wv.y * bf2f(x1[ch])
                  + wv.z * bf2f(x2[ch]) + wv.w * bf2f(x3[ch]);
        o[ch] = f2bf(silu_f(acc));
      }
      *(us8v*)(Bo + (size_t)row * D_STATE + c0) = o;
    } else {
      const int c0 = (q - 2) * 8;
      const float* base = cproj + (size_t)row * D_STATE + c0;
      float c0r[8], c1r[8], c2r[8], c3r[8];
#pragma unroll
      for (int half = 0; half < 2; ++half) {
        float4 v0 = (t >= 3) ? *(const float4*)(base - 3 * D_STATE + 4 * half) : make_float4(0,0,0,0);
        float4 v1 = (t >= 2) ? *(const float4*)(base - 2 * D_STATE + 4 * half) : make_float4(0,0,0,0);
        float4 v2 = (t >= 1) ? *(const float4*)(base - 1 * D_STATE + 4 * half) : make_float4(0,0,0,0);
        float4 v3 = *(const float4*)(base + 4 * half);
        c0r[4*half+0]=v0.x; c0r[4*half+1]=v0.y; c0r[4*half+2]=v0.z; c0r[4*half+3]=v0.w;
        c1r[4*half+0]=v1.x; c1r[4*half+1]=v1.y; c1r[4*half+2]=v1.z; c1r[4*half+3]=v1.w;
        c2r[4*half+0]=v2.x; c2r[4*half+1]=v2.y; c2r[4*half+2]=v2.z; c2r[4*half+3]=v2.w;
        c3r[4*half+0]=v3.x; c3r[4*half+1]=v3.y; c3r[4*half+2]=v3.z; c3r[4*half+3]=v3.w;
      }
      us8v o;
#pragma unroll
      for (int ch = 0; ch < 8; ++ch) {
        const float4 wv = *(const float4*)(conv_w_b + (c0 + ch) * 4);
        float acc = conv_b_b[c0 + ch] + wv.x * c0r[ch] + wv.y * c1r[ch]
                  + wv.z * c2r[ch] + wv.w * c3r[ch];
        o[ch] = f2bf(silu_f(acc));
      }
      *(us8v*)(Co + (size_t)row * D_STATE + c0) = o;
    }
  } else {
    // ---- dt: 8 heads per thread ----
    const int idx = (blk - CX_NB - CBC_NB) * 256 + threadIdx.x;
    const int row = idx / 3, q = idx % 3;
    const int b = row / SEQLEN, t = row % SEQLEN;
    const int h0 = q * 8;
    us8v dv = *(const us8v*)(zxbdt + (size_t)row * D_IN_PROJ + (D_IN_PROJ - NHEADS) + h0);
#pragma unroll
    for (int j = 0; j < 8; ++j) {
      float v = bf2f(dv[j]) + dt_bias[h0 + j];
      dtoT[(size_t)(b * NHEADS + h0 + j) * SEQLEN + t] = softplus_f(v);
    }
  }
}

// ---------------------------------------------------------------------------
// K3 (MFMA, 8 waves): per (h, chunk, b) block, 512 threads.
// Wave w owns strips {w, 15-w}: exactly 9 tile-pairs each (balanced);
// per-wave serial chain halved vs the 4-wave version.
// ---------------------------------------------------------------------------
__global__ __launch_bounds__(512, 4)
void ssd_mfma_kernel(const unsigned short* __restrict__ xoT, const unsigned short* __restrict__ Bo,
                     const unsigned short* __restrict__ Co, const float* __restrict__ dtoT,
                     const float* __restrict__ A_log,
                     unsigned short* __restrict__ YdT, float* __restrict__ acum_g,
                     float* __restrict__ csum_g, float* __restrict__ stloc) {
  const int h    = blockIdx.x;
  const int cidx = blockIdx.y;
  const int b    = blockIdx.z;
  const int tid  = threadIdx.x;
  const int wid  = tid >> 6, lane = tid & 63;
  const int fr   = lane & 15, g = lane >> 4;

  __shared__ unsigned short Bs[256 * 24 + 32];
  __shared__ unsigned short xsT[16 * 264];
  __shared__ unsigned short BwT[16 * 264];
  __shared__ unsigned short Ps[8][16 * 40];
  __shared__ float sc[CHUNK];
  __shared__ float sc2[CHUNK];
  __shared__ float sred[2][256];
  __shared__ float wsum[4];

  const float Ah = -expf(A_log[h]);

  // ---- cumsum over chunk: waves 0..3 (tid<256) ----
  float v = 0.f;
  if (tid < CHUNK) {
    v = dtoT[(size_t)(b * NHEADS + h) * SEQLEN + (size_t)cidx * CHUNK + tid] * Ah;
#pragma unroll
    for (int off = 1; off < 64; off <<= 1) {
      float u = __shfl_up(v, off, 64);
      if (lane >= off) v += u;
    }
    if (lane == 63) wsum[wid] = v;
  }

  // ---- stage Bs + xsT: 2 threads per row ----
  const int r  = tid >> 1;
  const int hf = tid & 1;
  const size_t rrow  = (size_t)b * SEQLEN + (size_t)cidx * CHUNK + r;
  const size_t rhrow = (size_t)(b * NHEADS + h) * SEQLEN + (size_t)cidx * CHUNK + r;
  const float rdtv = dtoT[rhrow];
  us8v bh = ((const us8v*)(Bo + rrow * D_STATE))[hf];
  *(us8v*)&Bs[r * 24 + 8 * hf] = bh;
  if (hf == 0) {
    const us8v z8 = { 0, 0, 0, 0, 0, 0, 0, 0 };
    *(us8v*)&Bs[r * 24 + 16] = z8;
  }
  if (tid < 32) Bs[256 * 24 + tid] = 0;
  {
    us8v xh = ((const us8v*)(xoT + rhrow * HEADDIM))[hf];
#pragma unroll
    for (int q = 0; q < 8; ++q)
      xsT[(q + 8 * hf) * 264 + r] = f2bf(bf2f(xh[q]) * rdtv);
  }
  __syncthreads();   // #1

  const float ctot = wsum[0] + wsum[1] + wsum[2] + wsum[3];
  if (tid < CHUNK) {
    float pre = 0.f;
#pragma unroll
    for (int w = 0; w < 4; ++w) if (w < wid) pre += wsum[w];
    v += pre;
    sc[tid]  = v;
    sc2[tid] = v * LOG2E;
    acum_g[(size_t)(b * NHEADS + h) * SEQLEN + (size_t)cidx * CHUNK + tid] = v;
    if (tid == CHUNK - 1) csum_g[(b * NHEADS + h) * NCHUNKS + cidx] = v;
  }
  __syncthreads();   // #2 (sc visible)

  // ---- BwT staging (all threads, 2/row; needs sc[r]) ----
  {
    const float wdv = __expf(ctot - sc[r]);
#pragma unroll
    for (int q = 0; q < 8; ++q)
      BwT[(q + 8 * hf) * 264 + r] = f2bf(bf2f(bh[q]) * wdv);
  }
  __syncthreads();   // #3

  // ---- chunk state: waves 0,1 each do K=128 ----
  if (wid < 2) {
    f32x4 accS = {};
#pragma unroll
    for (int k2 = 0; k2 < 4; ++k2) {
      bf16x8 af = *(const bf16x8*)&BwT[fr * 264 + wid * 128 + 32 * k2 + 8 * g];
      bf16x8 bb = *(const bf16x8*)&xsT[fr * 264 + wid * 128 + 32 * k2 + 8 * g];
      accS = __builtin_amdgcn_mfma_f32_16x16x32_bf16(af, bb, accS, 0, 0, 0);
    }
    *(f32x4*)&sred[wid][fr * 16 + 4 * g] = accS;
  }

  // ---- Y_diag strips: wave w -> {w, 15-w} (9 pairs each) ----
  const int strips[2] = { wid, 15 - wid };
  const f32x4 zf = { 0.f, 0.f, 0.f, 0.f };
  const unsigned short* Cbase = Co + ((size_t)b * SEQLEN + (size_t)cidx * CHUNK) * D_STATE;
#pragma unroll
  for (int q = 0; q < 2; ++q) {
    const int lt = strips[q];
    f32x4 acc = zf;
    bf16x8 cf = { 0, 0, 0, 0, 0, 0, 0, 0 };
    if (g < 2) cf = *(const bf16x8*)(Cbase + (lt * 16 + fr) * D_STATE + 8 * g);
    const float acl2 = sc2[lt * 16 + fr];
    const int   lg   = lt * 16 + fr;
    const int npair = (lt + 2) >> 1;
    for (int sp = 0; sp < npair; ++sp) {
#pragma unroll
      for (int ti = 0; ti < 2; ++ti) {
        const int st = 2 * sp + ti;
        if (st < lt) {
          bf16x8 bfg = *(const bf16x8*)&Bs[(st * 16 + fr) * 24 + 8 * g];
          f32x4 G = __builtin_amdgcn_mfma_f32_16x16x32_bf16(bfg, cf, zf, 0, 0, 0);
          f32x4 se2 = *(const f32x4*)&sc2[st * 16 + 4 * g];
          float w0 = exp2f(acl2 - se2[0]);
          float w1 = exp2f(acl2 - se2[1]);
          float w2 = exp2f(acl2 - se2[2]);
          float w3 = exp2f(acl2 - se2[3]);
          uint2 pk;
          pk.x = pk_bf(G[0] * w0, G[1] * w1);
          pk.y = pk_bf(G[2] * w2, G[3] * w3);
          *(uint2*)&Ps[wid][fr * 40 + 16 * ti + 4 * g] = pk;
        } else if (st == lt) {
          bf16x8 bfg = *(const bf16x8*)&Bs[(st * 16 + fr) * 24 + 8 * g];
          f32x4 G = __builtin_amdgcn_mfma_f32_16x16x32_bf16(bfg, cf, zf, 0, 0, 0);
          f32x4 se2 = *(const f32x4*)&sc2[st * 16 + 4 * g];
          const int sbase = st * 16 + 4 * g;
          float w0 = (sbase + 0 <= lg) ? exp2f(acl2 - se2[0]) : 0.f;
          float w1 = (sbase + 1 <= lg) ? exp2f(acl2 - se2[1]) : 0.f;
          float w2 = (sbase + 2 <= lg) ? exp2f(acl2 - se2[2]) : 0.f;
          float w3 = (sbase + 3 <= lg) ? exp2f(acl2 - se2[3]) : 0.f;
          uint2 pk;
          pk.x = pk_bf(G[0] * w0, G[1] * w1);
          pk.y = pk_bf(G[2] * w2, G[3] * w3);
          *(uint2*)&Ps[wid][fr * 40 + 16 * ti + 4 * g] = pk;
        } else {
          uint2 zz; zz.x = 0u; zz.y = 0u;
          *(uint2*)&Ps[wid][fr * 40 + 16 * ti + 4 * g] = zz;
        }
      }
      const bf16x8 pf = *(const bf16x8*)&Ps[wid][fr * 40 + 8 * g];
      const bf16x8 xf = *(const bf16x8*)&xsT[fr * 264 + sp * 32 + 8 * g];
      acc = __builtin_amdgcn_mfma_f32_16x16x32_bf16(xf, pf, acc, 0, 0, 0);
    }
    us4v o = { f2bf(acc[0]), f2bf(acc[1]), f2bf(acc[2]), f2bf(acc[3]) };
    *(us4v*)(YdT + ((size_t)(b * NHEADS + h) * SEQLEN + (size_t)cidx * CHUNK + lt * 16 + fr) * HEADDIM
             + 4 * g) = o;
  }

  __syncthreads();   // #4
  if (tid < 256) {
    stloc[((size_t)(b * NCHUNKS + cidx) * NHEADS + h) * 256 + tid] = sred[0][tid] + sred[1][tid];
  }
}

// ---------------------------------------------------------------------------
// K4: sequential inter-chunk state recurrence ([p][n] layout)
// ---------------------------------------------------------------------------
__global__ __launch_bounds__(256)
void chunk_scan_kernel(const float* __restrict__ stloc, const float* __restrict__ csum_g,
                       float* __restrict__ stpre) {
  const int b  = blockIdx.x / NHEADS;
  const int h  = blockIdx.x % NHEADS;
  const int pn = threadIdx.x;
  float S = 0.0f;
  for (int c = 0; c < NCHUNKS; ++c) {
    const size_t idx = ((size_t)(b * NCHUNKS + c) * NHEADS + h) * 256 + pn;
    stpre[idx] = S;
    S = __expf(csum_g[(b * NHEADS + h) * NCHUNKS + c]) * S + stloc[idx];
  }
}

// ---------------------------------------------------------------------------
// K5 (tiled): Y_off + D*x, silu(z) gate, RMSNorm -> row-major bf16 yn.
// ---------------------------------------------------------------------------
#define TT 16
__global__ __launch_bounds__(384)
void yoff_norm_tiled(const unsigned short* __restrict__ YdT, const unsigned short* __restrict__ xoT,
                     const unsigned short* __restrict__ Co, const float* __restrict__ acum_g,
                     const float* __restrict__ stpre, const float* __restrict__ Dvec,
                     const unsigned short* __restrict__ zxbdt, const float* __restrict__ norm_w,
                     unsigned short* __restrict__ yn) {
  const int r0   = blockIdx.x * TT;
  const int b    = r0 / SEQLEN;
  const int t0   = r0 % SEQLEN;
  const int cidx = t0 / CHUNK;
  const int d    = threadIdx.x;
  const int h    = d >> 4, p = d & 15;
  const int wv   = d >> 6;

  __shared__ unsigned short Yt[NHEADS * TT * 16];
  __shared__ unsigned short Xt[NHEADS * TT * 16];
  __shared__ float At[NHEADS * TT];
  __shared__ float Ct[TT * 16];
  __shared__ float red[TT][6];

  {
    us8v* Yt8 = (us8v*)Yt;
    us8v* Xt8 = (us8v*)Xt;
#pragma unroll
    for (int rep = 0; rep < 2; ++rep) {
      int j = d + rep * 384;
      int hh = j >> 5, q = j & 31;
      const size_t src = ((size_t)(b * NHEADS + hh) * SEQLEN + t0) * HEADDIM + q * 8;
      Yt8[j] = *(const us8v*)(YdT + src);
      Xt8[j] = *(const us8v*)(xoT + src);
    }
    At[d] = acum_g[(size_t)(b * NHEADS + (d >> 4)) * SEQLEN + t0 + (d & 15)];
    if (d < TT * 16) Ct[d] = bf2f(Co[(size_t)r0 * D_STATE + d]);
  }

  float S[16];
  {
    const float* Sp = stpre + ((size_t)(b * NCHUNKS + cidx) * NHEADS + h) * 256 + p * 16;
#pragma unroll
    for (int q = 0; q < 4; ++q) {
      float4 v4 = *(const float4*)(Sp + 4 * q);
      S[4 * q + 0] = v4.x; S[4 * q + 1] = v4.y; S[4 * q + 2] = v4.z; S[4 * q + 3] = v4.w;
    }
  }
  const float Dh = Dvec[h];
  const float nw = norm_w[d];
  __syncthreads();

  float yg[TT];
#pragma unroll
  for (int tt = 0; tt < TT; ++tt) {
    float dot = 0.f;
#pragma unroll
    for (int n = 0; n < 16; ++n) dot += Ct[tt * 16 + n] * S[n];
    const float acl = At[h * TT + tt];
    float y = bf2f(Yt[h * 256 + tt * 16 + p]) + __expf(acl) * dot
            + Dh * bf2f(Xt[h * 256 + tt * 16 + p]);
    const float z = bf2f(zxbdt[(size_t)(r0 + tt) * D_IN_PROJ + d]);
    yg[tt] = y * silu_f(z);
    float s = yg[tt] * yg[tt];
#pragma unroll
    for (int off = 32; off > 0; off >>= 1) s += __shfl_down(s, off);
    if ((d & 63) == 0) red[tt][wv] = s;
  }
  __syncthreads();

#pragma unroll
  for (int tt = 0; tt < TT; ++tt) {
    const float tot = red[tt][0] + red[tt][1] + red[tt][2] + red[tt][3] + red[tt][4] + red[tt][5];
    const float scale = rsqrtf(tot * (1.0f / D_INNER) + EPS);
    yn[(size_t)(r0 + tt) * D_INNER + d] = f2bf(yg[tt] * scale * nw);
  }
}

// ---------------------------------------------------------------------------
extern "C" void kernel_launch(void* const* d_in, const int* in_sizes, int n_in,
                              void* d_out, int out_size, void* d_ws, size_t ws_size,
                              hipStream_t stream) {
  const float* u        = (const float*)d_in[0];
  const float* support  = (const float*)d_in[1];
  const float* W_in     = (const float*)d_in[2];
  const float* W_in_b   = (const float*)d_in[3];
  const float* conv_w   = (const float*)d_in[4];
  const float* conv_b   = (const float*)d_in[5];
  const float* conv_w_b = (const float*)d_in[6];
  const float* conv_b_b = (const float*)d_in[7];
  const float* dt_bias  = (const float*)d_in[8];
  const float* A_log    = (const float*)d_in[9];
  const float* Dvec     = (const float*)d_in[10];
  const float* norm_w   = (const float*)d_in[11];
  const float* W_out    = (const float*)d_in[12];
  float* out = (float*)d_out;
  char* wsb  = (char*)d_ws;

  unsigned short* Wi_b  = (unsigned short*)(wsb);
  unsigned short* Wo_b  = Wi_b + (size_t)D_IN_PROJ * D_MODEL;
  unsigned short* Wib_b = Wo_b + (size_t)D_MODEL * D_INNER;
  unsigned short* zxbdt = Wib_b + (size_t)D_STATE * D_MODEL;
  unsigned short* xoT   = zxbdt + (size_t)ROWS * D_IN_PROJ;       // [b][h][t][16]
  unsigned short* Bo    = xoT + (size_t)ROWS * D_INNER;           // [b][t][16]
  unsigned short* Co    = Bo + (size_t)ROWS * D_STATE;            // [b][t][16]
  unsigned short* YdT   = Co + (size_t)ROWS * D_STATE;            // [b][h][t][16]
  unsigned short* yn    = YdT + (size_t)ROWS * D_INNER;           // [row][384]
  float* cproj = (float*)(yn + (size_t)ROWS * D_INNER);
  float* dtoT  = cproj + (size_t)ROWS * D_STATE;                  // [b][h][t]
  float* acum  = dtoT  + (size_t)ROWS * NHEADS;                   // [b][h][t]
  float* csum  = acum  + (size_t)BATCH * NHEADS * SEQLEN;
  float* stloc = csum  + (size_t)BATCH * NHEADS * NCHUNKS;
  float* stpre = stloc + (size_t)BATCH * NCHUNKS * NHEADS * 256;

  cvt3_kernel<<<224, 256, 0, stream>>>(W_in, Wi_b, (long)D_IN_PROJ * D_MODEL,
                                       W_out, Wo_b, (long)D_MODEL * D_INNER,
                                       W_in_b, Wib_b, (long)D_STATE * D_MODEL);
  gemm_bf16<true, true><<<dim3((D_IN_PROJ + 127) / 128, ROWS / 128), 256, 0, stream>>>(
      u, Wi_b, zxbdt, ROWS, D_IN_PROJ, D_MODEL);
  gemm_bf16<true, false><<<dim3(1, ROWS / 128), 256, 0, stream>>>(
      support, Wib_b, cproj, ROWS, D_STATE, D_MODEL);
  conv_dt_v3<<<CX_NB + CBC_NB + CDT_NB, 256, 0, stream>>>(
      zxbdt, cproj, conv_w, conv_b, conv_w_b, conv_b_b, dt_bias, xoT, Bo, Co, dtoT);
  ssd_mfma_kernel<<<dim3(NHEADS, NCHUNKS, BATCH), 512, 0, stream>>>(
      xoT, Bo, Co, dtoT, A_log, YdT, acum, csum, stloc);
  chunk_scan_kernel<<<BATCH * NHEADS, 256, 0, stream>>>(stloc, csum, stpre);
  yoff_norm_tiled<<<ROWS / TT, 384, 0, stream>>>(YdT, xoT, Co, acum, stpre, Dvec, zxbdt,
                                                 norm_w, yn);
  gemm_bf16<false, false><<<dim3((D_MODEL + 127) / 128, ROWS / 128), 256, 0, stream>>>(
      yn, Wo_b, out, ROWS, D_MODEL, D_INNER);
}

// Round 13
// 130.558 us; speedup vs baseline: 1.2228x; 1.0219x over previous
//
#include <hip/hip_runtime.h>
#include <cmath>

#define ROWS      16384
#define SEQLEN    8192
#define BATCH     2
#define NHEADS    24
#define HEADDIM   16
#define D_STATE   16
#define D_INNER   384
#define D_MODEL   192
#define D_IN_PROJ 808
#define CONV_DIM  400
#define NCHUNKS   32
#define CHUNK     256
#define EPS       1e-5f
#define LOG2E     1.44269504088896f

typedef short bf16x8 __attribute__((ext_vector_type(8)));
typedef float f32x4  __attribute__((ext_vector_type(4)));
typedef unsigned short us4v __attribute__((ext_vector_type(4)));
typedef unsigned short us8v __attribute__((ext_vector_type(8)));

__device__ __forceinline__ float silu_f(float x) { return x / (1.0f + expf(-x)); }
__device__ __forceinline__ float softplus_f(float x) { return (x > 20.0f) ? x : log1pf(expf(x)); }
__device__ __forceinline__ unsigned short f2bf(float x) {
  unsigned u = __builtin_bit_cast(unsigned, x);
  u += 0x7fff + ((u >> 16) & 1);
  return (unsigned short)(u >> 16);
}
__device__ __forceinline__ float bf2f(unsigned short s) {
  unsigned u = (unsigned)s << 16;
  return __builtin_bit_cast(float, u);
}
__device__ __forceinline__ unsigned pk_bf(float a, float b) {
  unsigned ua = __builtin_bit_cast(unsigned, a) + 0x7fffu;
  unsigned ub = __builtin_bit_cast(unsigned, b) + 0x7fffu;
  return __builtin_amdgcn_perm(ub, ua, 0x07060302u);
}

// ---------------------------------------------------------------------------
// K0: fp32 -> bf16 conversion for W_in, W_out, W_in_b (weights only)
// ---------------------------------------------------------------------------
__global__ __launch_bounds__(256)
void cvt3_kernel(const float* __restrict__ a, unsigned short* __restrict__ ao, long na,
                 const float* __restrict__ b, unsigned short* __restrict__ bo, long nb,
                 const float* __restrict__ c, unsigned short* __restrict__ co, long nc) {
  const long t0 = na >> 2, t1 = t0 + (nb >> 2), t2 = t1 + (nc >> 2);
  const long stride = (long)gridDim.x * blockDim.x;
  for (long i = (long)blockIdx.x * blockDim.x + threadIdx.x; i < t2; i += stride) {
    const float4* s; us4v* d; long j;
    if (i < t0)      { s = (const float4*)a; d = (us4v*)ao; j = i; }
    else if (i < t1) { s = (const float4*)b; d = (us4v*)bo; j = i - t0; }
    else             { s = (const float4*)c; d = (us4v*)co; j = i - t1; }
    float4 v = s[j];
    us4v o = { f2bf(v.x), f2bf(v.y), f2bf(v.z), f2bf(v.w) };
    d[j] = o;
  }
}

// ---------------------------------------------------------------------------
// MFMA bf16 GEMM (unchanged)
// ---------------------------------------------------------------------------
template<bool A_F32, bool OUT_BF16>
__launch_bounds__(256, 3)
__global__ void gemm_bf16(const void* __restrict__ Ap,
                          const unsigned short* __restrict__ W,
                          void* __restrict__ Cp, int M, int N, int K) {
  constexpr int BM = 128, BN = 128, BK = 32, LDK = 40;
  __shared__ unsigned short As[2][BM * LDK];
  __shared__ unsigned short Ws[2][BN * LDK];
  const int tid  = threadIdx.x;
  const int wid  = tid >> 6, lane = tid & 63;
  const int wr   = wid >> 1, wc = wid & 1;
  const int fr   = lane & 15, fq = lane >> 4;
  const long m0  = (long)blockIdx.y * BM;
  const int  n0  = blockIdx.x * BN;

  f32x4 acc[4][4] = {};

  auto stage = [&](int k0, int buf) {
    if (A_F32) {
      const float* A = (const float*)Ap;
#pragma unroll
      for (int p = 0; p < 2; ++p) {
        int flat = p * 2048 + tid * 8;
        int r = flat >> 5, c = flat & 31;
        const float4* src = (const float4*)(A + (m0 + r) * (long)K + k0 + c);
        float4 v0 = src[0], v1 = src[1];
        us8v o = { f2bf(v0.x), f2bf(v0.y), f2bf(v0.z), f2bf(v0.w),
                   f2bf(v1.x), f2bf(v1.y), f2bf(v1.z), f2bf(v1.w) };
        *(us8v*)&As[buf][r * LDK + c] = o;
      }
    } else {
      const unsigned short* A = (const unsigned short*)Ap;
#pragma unroll
      for (int p = 0; p < 2; ++p) {
        int flat = p * 2048 + tid * 8;
        int r = flat >> 5, c = flat & 31;
        us8v v = *(const us8v*)(A + (m0 + r) * (long)K + k0 + c);
        *(us8v*)&As[buf][r * LDK + c] = v;
      }
    }
#pragma unroll
    for (int p = 0; p < 2; ++p) {
      int flat = p * 2048 + tid * 8;
      int r = flat >> 5, c = flat & 31;
      int gn = n0 + r;
      us8v v = { 0, 0, 0, 0, 0, 0, 0, 0 };
      if (gn < N) v = *(const us8v*)(W + (long)gn * K + k0 + c);
      *(us8v*)&Ws[buf][r * LDK + c] = v;
    }
  };

  const int nk = K / BK;
  stage(0, 0);
  __syncthreads();
  for (int kt = 0; kt < nk; ++kt) {
    const int cur = kt & 1;
    if (kt + 1 < nk) stage((kt + 1) * BK, cur ^ 1);
    bf16x8 af[4], bfr[4];
#pragma unroll
    for (int m = 0; m < 4; ++m)
      af[m] = *(const bf16x8*)&As[cur][(wr * 64 + m * 16 + fr) * LDK + fq * 8];
#pragma unroll
    for (int n = 0; n < 4; ++n)
      bfr[n] = *(const bf16x8*)&Ws[cur][(wc * 64 + n * 16 + fr) * LDK + fq * 8];
#pragma unroll
    for (int m = 0; m < 4; ++m)
#pragma unroll
      for (int n = 0; n < 4; ++n)
        acc[m][n] = __builtin_amdgcn_mfma_f32_16x16x32_bf16(bfr[n], af[m], acc[m][n], 0, 0, 0);
    __syncthreads();
  }

#pragma unroll
  for (int m = 0; m < 4; ++m) {
    const long gm = m0 + wr * 64 + m * 16 + fr;
#pragma unroll
    for (int n = 0; n < 4; ++n) {
      const int gn = n0 + wc * 64 + n * 16 + fq * 4;
      if (gn < N) {
        if (OUT_BF16) {
          us4v o = { f2bf(acc[m][n][0]), f2bf(acc[m][n][1]),
                     f2bf(acc[m][n][2]), f2bf(acc[m][n][3]) };
          *(us4v*)((unsigned short*)Cp + gm * N + gn) = o;
        } else {
          float4 o = make_float4(acc[m][n][0], acc[m][n][1], acc[m][n][2], acc[m][n][3]);
          *(float4*)((float*)Cp + gm * N + gn) = o;
        }
      }
    }
  }
}

// ---------------------------------------------------------------------------
// K2: B/C/dt only (x-conv is fused into ssd). 448 role-pure blocks.
// ---------------------------------------------------------------------------
#define CBC_NB  (ROWS * 4 / 256)    // 256
#define CDT_NB  (ROWS * 3 / 256)    // 192

__global__ __launch_bounds__(256)
void conv_bcdt(const unsigned short* __restrict__ zxbdt, const float* __restrict__ cproj,
               const float* __restrict__ conv_w, const float* __restrict__ conv_b,
               const float* __restrict__ conv_w_b, const float* __restrict__ conv_b_b,
               const float* __restrict__ dt_bias,
               unsigned short* __restrict__ Bo, unsigned short* __restrict__ Co,
               float* __restrict__ dtoT) {
  const int blk = blockIdx.x;
  const us8v z8 = { 0, 0, 0, 0, 0, 0, 0, 0 };

  if (blk < CBC_NB) {
    const int idx = blk * 256 + threadIdx.x;
    const int row = idx / 4, q = idx % 4;
    const int b = row / SEQLEN, t = row % SEQLEN;

    if (q < 2) {
      const int c0 = q * 8;
      const unsigned short* base = zxbdt + (size_t)row * D_IN_PROJ + D_INNER + 384 + c0;
      us8v x0 = (t >= 3) ? *(const us8v*)(base - 3 * D_IN_PROJ) : z8;
      us8v x1 = (t >= 2) ? *(const us8v*)(base - 2 * D_IN_PROJ) : z8;
      us8v x2 = (t >= 1) ? *(const us8v*)(base - 1 * D_IN_PROJ) : z8;
      us8v x3 = *(const us8v*)base;
      us8v o;
#pragma unroll
      for (int ch = 0; ch < 8; ++ch) {
        const float4 wv = *(const float4*)(conv_w + (384 + c0 + ch) * 4);
        float acc = conv_b[384 + c0 + ch] + wv.x * bf2f(x0[ch]) + wv.y * bf2f(x1[ch])
                  + wv.z * bf2f(x2[ch]) + wv.w * bf2f(x3[ch]);
        o[ch] = f2bf(silu_f(acc));
      }
      *(us8v*)(Bo + (size_t)row * D_STATE + c0) = o;
    } else {
      const int c0 = (q - 2) * 8;
      const float* base = cproj + (size_t)row * D_STATE + c0;
      float c0r[8], c1r[8], c2r[8], c3r[8];
#pragma unroll
      for (int half = 0; half < 2; ++half) {
        float4 v0 = (t >= 3) ? *(const float4*)(base - 3 * D_STATE + 4 * half) : make_float4(0,0,0,0);
        float4 v1 = (t >= 2) ? *(const float4*)(base - 2 * D_STATE + 4 * half) : make_float4(0,0,0,0);
        float4 v2 = (t >= 1) ? *(const float4*)(base - 1 * D_STATE + 4 * half) : make_float4(0,0,0,0);
        float4 v3 = *(const float4*)(base + 4 * half);
        c0r[4*half+0]=v0.x; c0r[4*half+1]=v0.y; c0r[4*half+2]=v0.z; c0r[4*half+3]=v0.w;
        c1r[4*half+0]=v1.x; c1r[4*half+1]=v1.y; c1r[4*half+2]=v1.z; c1r[4*half+3]=v1.w;
        c2r[4*half+0]=v2.x; c2r[4*half+1]=v2.y; c2r[4*half+2]=v2.z; c2r[4*half+3]=v2.w;
        c3r[4*half+0]=v3.x; c3r[4*half+1]=v3.y; c3r[4*half+2]=v3.z; c3r[4*half+3]=v3.w;
      }
      us8v o;
#pragma unroll
      for (int ch = 0; ch < 8; ++ch) {
        const float4 wv = *(const float4*)(conv_w_b + (c0 + ch) * 4);
        float acc = conv_b_b[c0 + ch] + wv.x * c0r[ch] + wv.y * c1r[ch]
                  + wv.z * c2r[ch] + wv.w * c3r[ch];
        o[ch] = f2bf(silu_f(acc));
      }
      *(us8v*)(Co + (size_t)row * D_STATE + c0) = o;
    }
  } else {
    const int idx = (blk - CBC_NB) * 256 + threadIdx.x;
    const int row = idx / 3, q = idx % 3;
    const int b = row / SEQLEN, t = row % SEQLEN;
    const int h0 = q * 8;
    us8v dv = *(const us8v*)(zxbdt + (size_t)row * D_IN_PROJ + (D_IN_PROJ - NHEADS) + h0);
#pragma unroll
    for (int j = 0; j < 8; ++j) {
      float v = bf2f(dv[j]) + dt_bias[h0 + j];
      dtoT[(size_t)(b * NHEADS + h0 + j) * SEQLEN + t] = softplus_f(v);
    }
  }
}

// ---------------------------------------------------------------------------
// K3 (MFMA, 8 waves, fused x-conv): per (h, chunk, b) block, 512 threads.
// Stages raw x window (259 rows x 16ch, contiguous 32B/row in zxbdt), applies
// depthwise conv + silu in-register, folds D*x into the Y output.
// ---------------------------------------------------------------------------
__global__ __launch_bounds__(512, 4)
void ssd_mfma_kernel(const unsigned short* __restrict__ zxbdt, const unsigned short* __restrict__ Bo,
                     const unsigned short* __restrict__ Co, const float* __restrict__ dtoT,
                     const float* __restrict__ A_log, const float* __restrict__ conv_w,
                     const float* __restrict__ conv_b, const float* __restrict__ Dvec,
                     unsigned short* __restrict__ YdT, float* __restrict__ acum_g,
                     float* __restrict__ csum_g, float* __restrict__ stloc) {
  const int h    = blockIdx.x;
  const int cidx = blockIdx.y;
  const int b    = blockIdx.z;
  const int tid  = threadIdx.x;
  const int wid  = tid >> 6, lane = tid & 63;
  const int fr   = lane & 15, g = lane >> 4;

  __shared__ unsigned short Bs[256 * 24 + 32];
  __shared__ unsigned short xsT[16 * 264];
  __shared__ unsigned short BwT[16 * 264];
  __shared__ unsigned short Ps[8][16 * 40];
  __shared__ unsigned short xraw[259 * 16 + 8];  // raw x, then silu(conv) overlay at +3
  __shared__ float sc[CHUNK];
  __shared__ float sc2[CHUNK];
  __shared__ float sred[2][256];
  __shared__ float wsum[4];

  const float Ah = -expf(A_log[h]);
  const us8v z8 = { 0, 0, 0, 0, 0, 0, 0, 0 };

  // ---- phase 1: cumsum wave-scan + stage Bs + stage raw x window ----
  float v = 0.f;
  if (tid < CHUNK) {
    v = dtoT[(size_t)(b * NHEADS + h) * SEQLEN + (size_t)cidx * CHUNK + tid] * Ah;
#pragma unroll
    for (int off = 1; off < 64; off <<= 1) {
      float u = __shfl_up(v, off, 64);
      if (lane >= off) v += u;
    }
    if (lane == 63) wsum[wid] = v;
  }

  const int r  = tid >> 1;
  const int hf = tid & 1;
  const size_t rrow  = (size_t)b * SEQLEN + (size_t)cidx * CHUNK + r;
  const size_t rhrow = (size_t)(b * NHEADS + h) * SEQLEN + (size_t)cidx * CHUNK + r;
  const float rdtv = dtoT[rhrow];
  us8v bh = ((const us8v*)(Bo + rrow * D_STATE))[hf];
  *(us8v*)&Bs[r * 24 + 8 * hf] = bh;
  if (hf == 0) *(us8v*)&Bs[r * 24 + 16] = z8;
  if (tid < 32) Bs[256 * 24 + tid] = 0;
  {
    // xraw[rr] = raw x of chunk row rr-3, channels h*16 + 8*hf..+7
    const int tg = cidx * CHUNK + r - 3;
    us8v xv = z8;
    if (tg >= 0)
      xv = *(const us8v*)(zxbdt + ((size_t)b * SEQLEN + tg) * D_IN_PROJ + D_INNER + h * HEADDIM + 8 * hf);
    *(us8v*)&xraw[r * 16 + 8 * hf] = xv;
    if (tid < 6) {
      const int rr2 = 256 + (tid >> 1);
      const int hf2 = tid & 1;
      const int tg2 = cidx * CHUNK + rr2 - 3;
      us8v xv2 = *(const us8v*)(zxbdt + ((size_t)b * SEQLEN + tg2) * D_IN_PROJ + D_INNER + h * HEADDIM + 8 * hf2);
      *(us8v*)&xraw[rr2 * 16 + 8 * hf2] = xv2;
    }
  }
  __syncthreads();   // #1

  // ---- phase 2: conv taps -> regs; cross-wave cumsum combine ----
  us8v xsil, xdt8;
  {
    us8v tA = *(const us8v*)&xraw[(r + 0) * 16 + 8 * hf];
    us8v tB = *(const us8v*)&xraw[(r + 1) * 16 + 8 * hf];
    us8v tC = *(const us8v*)&xraw[(r + 2) * 16 + 8 * hf];
    us8v tD = *(const us8v*)&xraw[(r + 3) * 16 + 8 * hf];
    const int cbase = h * HEADDIM + 8 * hf;
#pragma unroll
    for (int ch = 0; ch < 8; ++ch) {
      const float4 wv = *(const float4*)(conv_w + (cbase + ch) * 4);
      float acc = conv_b[cbase + ch] + wv.x * bf2f(tA[ch]) + wv.y * bf2f(tB[ch])
                + wv.z * bf2f(tC[ch]) + wv.w * bf2f(tD[ch]);
      float sv = silu_f(acc);
      xsil[ch] = f2bf(sv);
      xdt8[ch] = f2bf(sv * rdtv);
    }
  }
  const float ctot = wsum[0] + wsum[1] + wsum[2] + wsum[3];
  if (tid < CHUNK) {
    float pre = 0.f;
#pragma unroll
    for (int w = 0; w < 4; ++w) if (w < wid) pre += wsum[w];
    v += pre;
    sc[tid]  = v;
    sc2[tid] = v * LOG2E;
    acum_g[(size_t)(b * NHEADS + h) * SEQLEN + (size_t)cidx * CHUNK + tid] = v;
    if (tid == CHUNK - 1) csum_g[(b * NHEADS + h) * NCHUNKS + cidx] = v;
  }
  __syncthreads();   // #2 (taps consumed; sc visible)

  // ---- phase 3: write xsil overlay, xsT, BwT ----
  *(us8v*)&xraw[(r + 3) * 16 + 8 * hf] = xsil;
#pragma unroll
  for (int q = 0; q < 8; ++q)
    xsT[(q + 8 * hf) * 264 + r] = xdt8[q];
  {
    const float wdv = __expf(ctot - sc[r]);
#pragma unroll
    for (int q = 0; q < 8; ++q)
      BwT[(q + 8 * hf) * 264 + r] = f2bf(bf2f(bh[q]) * wdv);
  }
  __syncthreads();   // #3

  // ---- chunk state: waves 0,1 each do K=128 ----
  if (wid < 2) {
    f32x4 accS = {};
#pragma unroll
    for (int k2 = 0; k2 < 4; ++k2) {
      bf16x8 af = *(const bf16x8*)&BwT[fr * 264 + wid * 128 + 32 * k2 + 8 * g];
      bf16x8 bb = *(const bf16x8*)&xsT[fr * 264 + wid * 128 + 32 * k2 + 8 * g];
      accS = __builtin_amdgcn_mfma_f32_16x16x32_bf16(af, bb, accS, 0, 0, 0);
    }
    *(f32x4*)&sred[wid][fr * 16 + 4 * g] = accS;
  }

  // ---- Y_diag strips: wave w -> {w, 15-w}; D*x folded at store ----
  const int strips[2] = { wid, 15 - wid };
  const f32x4 zf = { 0.f, 0.f, 0.f, 0.f };
  const unsigned short* Cbase = Co + ((size_t)b * SEQLEN + (size_t)cidx * CHUNK) * D_STATE;
  const float Dh = Dvec[h];
#pragma unroll
  for (int q = 0; q < 2; ++q) {
    const int lt = strips[q];
    f32x4 acc = zf;
    bf16x8 cf = { 0, 0, 0, 0, 0, 0, 0, 0 };
    if (g < 2) cf = *(const bf16x8*)(Cbase + (lt * 16 + fr) * D_STATE + 8 * g);
    const float acl2 = sc2[lt * 16 + fr];
    const int   lg   = lt * 16 + fr;
    const int npair = (lt + 2) >> 1;
    for (int sp = 0; sp < npair; ++sp) {
#pragma unroll
      for (int ti = 0; ti < 2; ++ti) {
        const int st = 2 * sp + ti;
        if (st < lt) {
          bf16x8 bfg = *(const bf16x8*)&Bs[(st * 16 + fr) * 24 + 8 * g];
          f32x4 G = __builtin_amdgcn_mfma_f32_16x16x32_bf16(bfg, cf, zf, 0, 0, 0);
          f32x4 se2 = *(const f32x4*)&sc2[st * 16 + 4 * g];
          float w0 = exp2f(acl2 - se2[0]);
          float w1 = exp2f(acl2 - se2[1]);
          float w2 = exp2f(acl2 - se2[2]);
          float w3 = exp2f(acl2 - se2[3]);
          uint2 pk;
          pk.x = pk_bf(G[0] * w0, G[1] * w1);
          pk.y = pk_bf(G[2] * w2, G[3] * w3);
          *(uint2*)&Ps[wid][fr * 40 + 16 * ti + 4 * g] = pk;
        } else if (st == lt) {
          bf16x8 bfg = *(const bf16x8*)&Bs[(st * 16 + fr) * 24 + 8 * g];
          f32x4 G = __builtin_amdgcn_mfma_f32_16x16x32_bf16(bfg, cf, zf, 0, 0, 0);
          f32x4 se2 = *(const f32x4*)&sc2[st * 16 + 4 * g];
          const int sbase = st * 16 + 4 * g;
          float w0 = (sbase + 0 <= lg) ? exp2f(acl2 - se2[0]) : 0.f;
          float w1 = (sbase + 1 <= lg) ? exp2f(acl2 - se2[1]) : 0.f;
          float w2 = (sbase + 2 <= lg) ? exp2f(acl2 - se2[2]) : 0.f;
          float w3 = (sbase + 3 <= lg) ? exp2f(acl2 - se2[3]) : 0.f;
          uint2 pk;
          pk.x = pk_bf(G[0] * w0, G[1] * w1);
          pk.y = pk_bf(G[2] * w2, G[3] * w3);
          *(uint2*)&Ps[wid][fr * 40 + 16 * ti + 4 * g] = pk;
        } else {
          uint2 zz; zz.x = 0u; zz.y = 0u;
          *(uint2*)&Ps[wid][fr * 40 + 16 * ti + 4 * g] = zz;
        }
      }
      const bf16x8 pf = *(const bf16x8*)&Ps[wid][fr * 40 + 8 * g];
      const bf16x8 xf = *(const bf16x8*)&xsT[fr * 264 + sp * 32 + 8 * g];
      acc = __builtin_amdgcn_mfma_f32_16x16x32_bf16(xf, pf, acc, 0, 0, 0);
    }
    // fold D*x (xsil overlay lives at xraw[row+3])
    us4v xs4 = *(const us4v*)&xraw[(lt * 16 + fr + 3) * 16 + 4 * g];
    us4v o = { f2bf(acc[0] + Dh * bf2f(xs4[0])),
               f2bf(acc[1] + Dh * bf2f(xs4[1])),
               f2bf(acc[2] + Dh * bf2f(xs4[2])),
               f2bf(acc[3] + Dh * bf2f(xs4[3])) };
    *(us4v*)(YdT + ((size_t)(b * NHEADS + h) * SEQLEN + (size_t)cidx * CHUNK + lt * 16 + fr) * HEADDIM
             + 4 * g) = o;
  }

  __syncthreads();   // #4
  if (tid < 256) {
    stloc[((size_t)(b * NCHUNKS + cidx) * NHEADS + h) * 256 + tid] = sred[0][tid] + sred[1][tid];
  }
}

// ---------------------------------------------------------------------------
// K4: sequential inter-chunk state recurrence ([p][n] layout)
// ---------------------------------------------------------------------------
__global__ __launch_bounds__(256)
void chunk_scan_kernel(const float* __restrict__ stloc, const float* __restrict__ csum_g,
                       float* __restrict__ stpre) {
  const int b  = blockIdx.x / NHEADS;
  const int h  = blockIdx.x % NHEADS;
  const int pn = threadIdx.x;
  float S = 0.0f;
  for (int c = 0; c < NCHUNKS; ++c) {
    const size_t idx = ((size_t)(b * NCHUNKS + c) * NHEADS + h) * 256 + pn;
    stpre[idx] = S;
    S = __expf(csum_g[(b * NHEADS + h) * NCHUNKS + c]) * S + stloc[idx];
  }
}

// ---------------------------------------------------------------------------
// K5 (tiled): Y_off add (D*x already folded), silu(z) gate, RMSNorm -> yn.
// ---------------------------------------------------------------------------
#define TT 16
__global__ __launch_bounds__(384)
void yoff_norm_tiled(const unsigned short* __restrict__ YdT,
                     const unsigned short* __restrict__ Co, const float* __restrict__ acum_g,
                     const float* __restrict__ stpre,
                     const unsigned short* __restrict__ zxbdt, const float* __restrict__ norm_w,
                     unsigned short* __restrict__ yn) {
  const int r0   = blockIdx.x * TT;
  const int b    = r0 / SEQLEN;
  const int t0   = r0 % SEQLEN;
  const int cidx = t0 / CHUNK;
  const int d    = threadIdx.x;
  const int h    = d >> 4, p = d & 15;
  const int wv   = d >> 6;

  __shared__ unsigned short Yt[NHEADS * TT * 16];
  __shared__ float At[NHEADS * TT];
  __shared__ float Ct[TT * 16];
  __shared__ float red[TT][6];

  {
    us8v* Yt8 = (us8v*)Yt;
#pragma unroll
    for (int rep = 0; rep < 2; ++rep) {
      int j = d + rep * 384;
      int hh = j >> 5, q = j & 31;
      const size_t src = ((size_t)(b * NHEADS + hh) * SEQLEN + t0) * HEADDIM + q * 8;
      Yt8[j] = *(const us8v*)(YdT + src);
    }
    At[d] = acum_g[(size_t)(b * NHEADS + (d >> 4)) * SEQLEN + t0 + (d & 15)];
    if (d < TT * 16) Ct[d] = bf2f(Co[(size_t)r0 * D_STATE + d]);
  }

  float S[16];
  {
    const float* Sp = stpre + ((size_t)(b * NCHUNKS + cidx) * NHEADS + h) * 256 + p * 16;
#pragma unroll
    for (int q = 0; q < 4; ++q) {
      float4 v4 = *(const float4*)(Sp + 4 * q);
      S[4 * q + 0] = v4.x; S[4 * q + 1] = v4.y; S[4 * q + 2] = v4.z; S[4 * q + 3] = v4.w;
    }
  }
  const float nw = norm_w[d];
  __syncthreads();

  float yg[TT];
#pragma unroll
  for (int tt = 0; tt < TT; ++tt) {
    float dot = 0.f;
#pragma unroll
    for (int n = 0; n < 16; ++n) dot += Ct[tt * 16 + n] * S[n];
    const float acl = At[h * TT + tt];
    float y = bf2f(Yt[h * 256 + tt * 16 + p]) + __expf(acl) * dot;
    const float z = bf2f(zxbdt[(size_t)(r0 + tt) * D_IN_PROJ + d]);
    yg[tt] = y * silu_f(z);
    float s = yg[tt] * yg[tt];
#pragma unroll
    for (int off = 32; off > 0; off >>= 1) s += __shfl_down(s, off);
    if ((d & 63) == 0) red[tt][wv] = s;
  }
  __syncthreads();

#pragma unroll
  for (int tt = 0; tt < TT; ++tt) {
    const float tot = red[tt][0] + red[tt][1] + red[tt][2] + red[tt][3] + red[tt][4] + red[tt][5];
    const float scale = rsqrtf(tot * (1.0f / D_INNER) + EPS);
    yn[(size_t)(r0 + tt) * D_INNER + d] = f2bf(yg[tt] * scale * nw);
  }
}

// ---------------------------------------------------------------------------
extern "C" void kernel_launch(void* const* d_in, const int* in_sizes, int n_in,
                              void* d_out, int out_size, void* d_ws, size_t ws_size,
                              hipStream_t stream) {
  const float* u        = (const float*)d_in[0];
  const float* support  = (const float*)d_in[1];
  const float* W_in     = (const float*)d_in[2];
  const float* W_in_b   = (const float*)d_in[3];
  const float* conv_w   = (const float*)d_in[4];
  const float* conv_b   = (const float*)d_in[5];
  const float* conv_w_b = (const float*)d_in[6];
  const float* conv_b_b = (const float*)d_in[7];
  const float* dt_bias  = (const float*)d_in[8];
  const float* A_log    = (const float*)d_in[9];
  const float* Dvec     = (const float*)d_in[10];
  const float* norm_w   = (const float*)d_in[11];
  const float* W_out    = (const float*)d_in[12];
  float* out = (float*)d_out;
  char* wsb  = (char*)d_ws;

  unsigned short* Wi_b  = (unsigned short*)(wsb);
  unsigned short* Wo_b  = Wi_b + (size_t)D_IN_PROJ * D_MODEL;
  unsigned short* Wib_b = Wo_b + (size_t)D_MODEL * D_INNER;
  unsigned short* zxbdt = Wib_b + (size_t)D_STATE * D_MODEL;
  unsigned short* Bo    = zxbdt + (size_t)ROWS * D_IN_PROJ;       // [b][t][16]
  unsigned short* Co    = Bo + (size_t)ROWS * D_STATE;            // [b][t][16]
  unsigned short* YdT   = Co + (size_t)ROWS * D_STATE;            // [b][h][t][16]
  unsigned short* yn    = YdT + (size_t)ROWS * D_INNER;           // [row][384]
  float* cproj = (float*)(yn + (size_t)ROWS * D_INNER);
  float* dtoT  = cproj + (size_t)ROWS * D_STATE;                  // [b][h][t]
  float* acum  = dtoT  + (size_t)ROWS * NHEADS;                   // [b][h][t]
  float* csum  = acum  + (size_t)BATCH * NHEADS * SEQLEN;
  float* stloc = csum  + (size_t)BATCH * NHEADS * NCHUNKS;
  float* stpre = stloc + (size_t)BATCH * NCHUNKS * NHEADS * 256;

  cvt3_kernel<<<224, 256, 0, stream>>>(W_in, Wi_b, (long)D_IN_PROJ * D_MODEL,
                                       W_out, Wo_b, (long)D_MODEL * D_INNER,
                                       W_in_b, Wib_b, (long)D_STATE * D_MODEL);
  gemm_bf16<true, true><<<dim3((D_IN_PROJ + 127) / 128, ROWS / 128), 256, 0, stream>>>(
      u, Wi_b, zxbdt, ROWS, D_IN_PROJ, D_MODEL);
  gemm_bf16<true, false><<<dim3(1, ROWS / 128), 256, 0, stream>>>(
      support, Wib_b, cproj, ROWS, D_STATE, D_MODEL);
  conv_bcdt<<<CBC_NB + CDT_NB, 256, 0, stream>>>(
      zxbdt, cproj, conv_w, conv_b, conv_w_b, conv_b_b, dt_bias, Bo, Co, dtoT);
  ssd_mfma_kernel<<<dim3(NHEADS, NCHUNKS, BATCH), 512, 0, stream>>>(
      zxbdt, Bo, Co, dtoT, A_log, conv_w, conv_b, Dvec, YdT, acum, csum, stloc);
  chunk_scan_kernel<<<BATCH * NHEADS, 256, 0, stream>>>(stloc, csum, stpre);
  yoff_norm_tiled<<<ROWS / TT, 384, 0, stream>>>(YdT, Co, acum, stpre, zxbdt, norm_w, yn);
  gemm_bf16<false, false><<<dim3((D_MODEL + 127) / 128, ROWS / 128), 256, 0, stream>>>(
      yn, Wo_b, out, ROWS, D_MODEL, D_INNER);
}

// Round 14
// 128.688 us; speedup vs baseline: 1.2406x; 1.0145x over previous
//
#include <hip/hip_runtime.h>
#include <cmath>

#define ROWS      16384
#define SEQLEN    8192
#define BATCH     2
#define NHEADS    24
#define HEADDIM   16
#define D_STATE   16
#define D_INNER   384
#define D_MODEL   192
#define D_IN_PROJ 808
#define CONV_DIM  400
#define NCHUNKS   32
#define CHUNK     256
#define EPS       1e-5f
#define LOG2E     1.44269504088896f

typedef short bf16x8 __attribute__((ext_vector_type(8)));
typedef float f32x4  __attribute__((ext_vector_type(4)));
typedef unsigned short us4v __attribute__((ext_vector_type(4)));
typedef unsigned short us8v __attribute__((ext_vector_type(8)));

__device__ __forceinline__ float silu_f(float x) { return x / (1.0f + expf(-x)); }
__device__ __forceinline__ float softplus_f(float x) { return (x > 20.0f) ? x : log1pf(expf(x)); }
__device__ __forceinline__ unsigned short f2bf(float x) {
  unsigned u = __builtin_bit_cast(unsigned, x);
  u += 0x7fff + ((u >> 16) & 1);
  return (unsigned short)(u >> 16);
}
__device__ __forceinline__ float bf2f(unsigned short s) {
  unsigned u = (unsigned)s << 16;
  return __builtin_bit_cast(float, u);
}
__device__ __forceinline__ unsigned pk_bf(float a, float b) {
  unsigned ua = __builtin_bit_cast(unsigned, a) + 0x7fffu;
  unsigned ub = __builtin_bit_cast(unsigned, b) + 0x7fffu;
  return __builtin_amdgcn_perm(ub, ua, 0x07060302u);
}

// ---------------------------------------------------------------------------
// K0: fp32 -> bf16 weights (W_in, W_out, W_in_b)
// ---------------------------------------------------------------------------
__global__ __launch_bounds__(256)
void cvt3_kernel(const float* __restrict__ a, unsigned short* __restrict__ ao, long na,
                 const float* __restrict__ b, unsigned short* __restrict__ bo, long nb,
                 const float* __restrict__ c, unsigned short* __restrict__ co, long nc) {
  const long t0 = na >> 2, t1 = t0 + (nb >> 2), t2 = t1 + (nc >> 2);
  const long stride = (long)gridDim.x * blockDim.x;
  for (long i = (long)blockIdx.x * blockDim.x + threadIdx.x; i < t2; i += stride) {
    const float4* s; us4v* d; long j;
    if (i < t0)      { s = (const float4*)a; d = (us4v*)ao; j = i; }
    else if (i < t1) { s = (const float4*)b; d = (us4v*)bo; j = i - t0; }
    else             { s = (const float4*)c; d = (us4v*)co; j = i - t1; }
    float4 v = s[j];
    us4v o = { f2bf(v.x), f2bf(v.y), f2bf(v.z), f2bf(v.w) };
    d[j] = o;
  }
}

// ---------------------------------------------------------------------------
// MFMA bf16 GEMM. ROUTE=true: in-proj output split into consumer-native dense
// buffers (z->zbuf, x->head-major xT, Braw, draw). N=808 for the routed call.
// ---------------------------------------------------------------------------
template<bool A_F32, bool OUT_BF16, bool ROUTE>
__launch_bounds__(256, 3)
__global__ void gemm_bf16(const void* __restrict__ Ap,
                          const unsigned short* __restrict__ W,
                          void* __restrict__ Cp, int M, int N, int K,
                          unsigned short* __restrict__ zbuf,
                          unsigned short* __restrict__ xT,
                          unsigned short* __restrict__ Braw,
                          unsigned short* __restrict__ draw) {
  constexpr int BM = 128, BN = 128, BK = 32, LDK = 40;
  __shared__ unsigned short As[2][BM * LDK];
  __shared__ unsigned short Ws[2][BN * LDK];
  const int tid  = threadIdx.x;
  const int wid  = tid >> 6, lane = tid & 63;
  const int wr   = wid >> 1, wc = wid & 1;
  const int fr   = lane & 15, fq = lane >> 4;
  const long m0  = (long)blockIdx.y * BM;
  const int  n0  = blockIdx.x * BN;

  f32x4 acc[4][4] = {};

  auto stage = [&](int k0, int buf) {
    if (A_F32) {
      const float* A = (const float*)Ap;
#pragma unroll
      for (int p = 0; p < 2; ++p) {
        int flat = p * 2048 + tid * 8;
        int r = flat >> 5, c = flat & 31;
        const float4* src = (const float4*)(A + (m0 + r) * (long)K + k0 + c);
        float4 v0 = src[0], v1 = src[1];
        us8v o = { f2bf(v0.x), f2bf(v0.y), f2bf(v0.z), f2bf(v0.w),
                   f2bf(v1.x), f2bf(v1.y), f2bf(v1.z), f2bf(v1.w) };
        *(us8v*)&As[buf][r * LDK + c] = o;
      }
    } else {
      const unsigned short* A = (const unsigned short*)Ap;
#pragma unroll
      for (int p = 0; p < 2; ++p) {
        int flat = p * 2048 + tid * 8;
        int r = flat >> 5, c = flat & 31;
        us8v v = *(const us8v*)(A + (m0 + r) * (long)K + k0 + c);
        *(us8v*)&As[buf][r * LDK + c] = v;
      }
    }
#pragma unroll
    for (int p = 0; p < 2; ++p) {
      int flat = p * 2048 + tid * 8;
      int r = flat >> 5, c = flat & 31;
      int gn = n0 + r;
      us8v v = { 0, 0, 0, 0, 0, 0, 0, 0 };
      if (gn < N) v = *(const us8v*)(W + (long)gn * K + k0 + c);
      *(us8v*)&Ws[buf][r * LDK + c] = v;
    }
  };

  const int nk = K / BK;
  stage(0, 0);
  __syncthreads();
  for (int kt = 0; kt < nk; ++kt) {
    const int cur = kt & 1;
    if (kt + 1 < nk) stage((kt + 1) * BK, cur ^ 1);
    bf16x8 af[4], bfr[4];
#pragma unroll
    for (int m = 0; m < 4; ++m)
      af[m] = *(const bf16x8*)&As[cur][(wr * 64 + m * 16 + fr) * LDK + fq * 8];
#pragma unroll
    for (int n = 0; n < 4; ++n)
      bfr[n] = *(const bf16x8*)&Ws[cur][(wc * 64 + n * 16 + fr) * LDK + fq * 8];
#pragma unroll
    for (int m = 0; m < 4; ++m)
#pragma unroll
      for (int n = 0; n < 4; ++n)
        acc[m][n] = __builtin_amdgcn_mfma_f32_16x16x32_bf16(bfr[n], af[m], acc[m][n], 0, 0, 0);
    __syncthreads();
  }

#pragma unroll
  for (int m = 0; m < 4; ++m) {
    const long gm = m0 + wr * 64 + m * 16 + fr;
#pragma unroll
    for (int n = 0; n < 4; ++n) {
      const int gn = n0 + wc * 64 + n * 16 + fq * 4;
      if (gn < N) {
        if (ROUTE) {
          us4v o = { f2bf(acc[m][n][0]), f2bf(acc[m][n][1]),
                     f2bf(acc[m][n][2]), f2bf(acc[m][n][3]) };
          const int bb = (int)(gm >> 13);
          const long t = gm & 8191;
          if (gn < 384) {
            *(us4v*)(zbuf + gm * 384 + gn) = o;
          } else if (gn < 768) {
            const int c = gn - 384, hh = c >> 4, ii = c & 15;
            *(us4v*)(xT + (((size_t)(bb * NHEADS + hh) * SEQLEN + t) << 4) + ii) = o;
          } else if (gn < 784) {
            *(us4v*)(Braw + gm * 16 + (gn - 768)) = o;
          } else {
            *(us4v*)(draw + gm * 24 + (gn - 784)) = o;
          }
        } else if (OUT_BF16) {
          us4v o = { f2bf(acc[m][n][0]), f2bf(acc[m][n][1]),
                     f2bf(acc[m][n][2]), f2bf(acc[m][n][3]) };
          *(us4v*)((unsigned short*)Cp + gm * N + gn) = o;
        } else {
          float4 o = make_float4(acc[m][n][0], acc[m][n][1], acc[m][n][2], acc[m][n][3]);
          *(float4*)((float*)Cp + gm * N + gn) = o;
        }
      }
    }
  }
}

// ---------------------------------------------------------------------------
// K2: B/C conv + dt softplus, dense raw buffers. 448 role-pure blocks.
// ---------------------------------------------------------------------------
#define CBC_NB  (ROWS * 4 / 256)    // 256
#define CDT_NB  (ROWS * 3 / 256)    // 192

__global__ __launch_bounds__(256)
void conv_bcdt(const unsigned short* __restrict__ Braw, const unsigned short* __restrict__ craw,
               const unsigned short* __restrict__ draw,
               const float* __restrict__ conv_w, const float* __restrict__ conv_b,
               const float* __restrict__ conv_w_b, const float* __restrict__ conv_b_b,
               const float* __restrict__ dt_bias,
               unsigned short* __restrict__ Bo, unsigned short* __restrict__ Co,
               float* __restrict__ dtoT) {
  const int blk = blockIdx.x;
  const us8v z8 = { 0, 0, 0, 0, 0, 0, 0, 0 };

  if (blk < CBC_NB) {
    const int idx = blk * 256 + threadIdx.x;
    const int row = idx / 4, q = idx % 4;
    const int b = row / SEQLEN, t = row % SEQLEN;

    const unsigned short* src = (q < 2) ? Braw : craw;
    const float* cw = (q < 2) ? conv_w + 384 * 4 : conv_w_b;
    const float* cb = (q < 2) ? conv_b + 384 : conv_b_b;
    const int c0 = (q & 1) * 8;
    const unsigned short* base = src + (size_t)row * D_STATE + c0;
    us8v x0 = (t >= 3) ? *(const us8v*)(base - 3 * D_STATE) : z8;
    us8v x1 = (t >= 2) ? *(const us8v*)(base - 2 * D_STATE) : z8;
    us8v x2 = (t >= 1) ? *(const us8v*)(base - 1 * D_STATE) : z8;
    us8v x3 = *(const us8v*)base;
    us8v o;
#pragma unroll
    for (int ch = 0; ch < 8; ++ch) {
      const float4 wv = *(const float4*)(cw + (c0 + ch) * 4);
      float acc = cb[c0 + ch] + wv.x * bf2f(x0[ch]) + wv.y * bf2f(x1[ch])
                + wv.z * bf2f(x2[ch]) + wv.w * bf2f(x3[ch]);
      o[ch] = f2bf(silu_f(acc));
    }
    if (q < 2) *(us8v*)(Bo + (size_t)row * D_STATE + c0) = o;
    else       *(us8v*)(Co + (size_t)row * D_STATE + c0) = o;
  } else {
    const int idx = (blk - CBC_NB) * 256 + threadIdx.x;
    const int row = idx / 3, q = idx % 3;
    const int b = row / SEQLEN, t = row % SEQLEN;
    const int h0 = q * 8;
    us8v dv = *(const us8v*)(draw + (size_t)row * 24 + h0);
#pragma unroll
    for (int j = 0; j < 8; ++j) {
      float v = bf2f(dv[j]) + dt_bias[h0 + j];
      dtoT[(size_t)(b * NHEADS + h0 + j) * SEQLEN + t] = softplus_f(v);
    }
  }
}

// ---------------------------------------------------------------------------
// K3 (MFMA, 8 waves, fused x-conv): contiguous head-major x window.
// ---------------------------------------------------------------------------
__global__ __launch_bounds__(512, 4)
void ssd_mfma_kernel(const unsigned short* __restrict__ xT, const unsigned short* __restrict__ Bo,
                     const unsigned short* __restrict__ Co, const float* __restrict__ dtoT,
                     const float* __restrict__ A_log, const float* __restrict__ conv_w,
                     const float* __restrict__ conv_b, const float* __restrict__ Dvec,
                     unsigned short* __restrict__ YdT, float* __restrict__ acum_g,
                     float* __restrict__ csum_g, float* __restrict__ stloc) {
  const int h    = blockIdx.x;
  const int cidx = blockIdx.y;
  const int b    = blockIdx.z;
  const int tid  = threadIdx.x;
  const int wid  = tid >> 6, lane = tid & 63;
  const int fr   = lane & 15, g = lane >> 4;

  __shared__ unsigned short Bs[256 * 24 + 32];
  __shared__ unsigned short xsT[16 * 264];
  __shared__ unsigned short BwT[16 * 264];
  __shared__ unsigned short Ps[8][16 * 40];
  __shared__ unsigned short xraw[259 * 16 + 8];
  __shared__ float sc[CHUNK];
  __shared__ float sc2[CHUNK];
  __shared__ float sred[2][256];
  __shared__ float wsum[4];

  const float Ah = -expf(A_log[h]);
  const us8v z8 = { 0, 0, 0, 0, 0, 0, 0, 0 };

  float v = 0.f;
  if (tid < CHUNK) {
    v = dtoT[(size_t)(b * NHEADS + h) * SEQLEN + (size_t)cidx * CHUNK + tid] * Ah;
#pragma unroll
    for (int off = 1; off < 64; off <<= 1) {
      float u = __shfl_up(v, off, 64);
      if (lane >= off) v += u;
    }
    if (lane == 63) wsum[wid] = v;
  }

  const int r  = tid >> 1;
  const int hf = tid & 1;
  const size_t rrow  = (size_t)b * SEQLEN + (size_t)cidx * CHUNK + r;
  const size_t rhrow = (size_t)(b * NHEADS + h) * SEQLEN + (size_t)cidx * CHUNK + r;
  const float rdtv = dtoT[rhrow];
  us8v bh = ((const us8v*)(Bo + rrow * D_STATE))[hf];
  *(us8v*)&Bs[r * 24 + 8 * hf] = bh;
  if (hf == 0) *(us8v*)&Bs[r * 24 + 16] = z8;
  if (tid < 32) Bs[256 * 24 + tid] = 0;
  {
    const int tg = cidx * CHUNK + r - 3;
    us8v xv = z8;
    if (tg >= 0)
      xv = *(const us8v*)(xT + (((size_t)(b * NHEADS + h) * SEQLEN + tg) << 4) + 8 * hf);
    *(us8v*)&xraw[r * 16 + 8 * hf] = xv;
    if (tid < 6) {
      const int rr2 = 256 + (tid >> 1);
      const int hf2 = tid & 1;
      const int tg2 = cidx * CHUNK + rr2 - 3;
      us8v xv2 = *(const us8v*)(xT + (((size_t)(b * NHEADS + h) * SEQLEN + tg2) << 4) + 8 * hf2);
      *(us8v*)&xraw[rr2 * 16 + 8 * hf2] = xv2;
    }
  }
  __syncthreads();   // #1

  us8v xsil, xdt8;
  {
    us8v tA = *(const us8v*)&xraw[(r + 0) * 16 + 8 * hf];
    us8v tB = *(const us8v*)&xraw[(r + 1) * 16 + 8 * hf];
    us8v tC = *(const us8v*)&xraw[(r + 2) * 16 + 8 * hf];
    us8v tD = *(const us8v*)&xraw[(r + 3) * 16 + 8 * hf];
    const int cbase = h * HEADDIM + 8 * hf;
#pragma unroll
    for (int ch = 0; ch < 8; ++ch) {
      const float4 wv = *(const float4*)(conv_w + (cbase + ch) * 4);
      float acc = conv_b[cbase + ch] + wv.x * bf2f(tA[ch]) + wv.y * bf2f(tB[ch])
                + wv.z * bf2f(tC[ch]) + wv.w * bf2f(tD[ch]);
      float sv = silu_f(acc);
      xsil[ch] = f2bf(sv);
      xdt8[ch] = f2bf(sv * rdtv);
    }
  }
  const float ctot = wsum[0] + wsum[1] + wsum[2] + wsum[3];
  if (tid < CHUNK) {
    float pre = 0.f;
#pragma unroll
    for (int w = 0; w < 4; ++w) if (w < wid) pre += wsum[w];
    v += pre;
    sc[tid]  = v;
    sc2[tid] = v * LOG2E;
    acum_g[(size_t)(b * NHEADS + h) * SEQLEN + (size_t)cidx * CHUNK + tid] = v;
    if (tid == CHUNK - 1) csum_g[(b * NHEADS + h) * NCHUNKS + cidx] = v;
  }
  __syncthreads();   // #2

  *(us8v*)&xraw[(r + 3) * 16 + 8 * hf] = xsil;
#pragma unroll
  for (int q = 0; q < 8; ++q)
    xsT[(q + 8 * hf) * 264 + r] = xdt8[q];
  {
    const float wdv = __expf(ctot - sc[r]);
#pragma unroll
    for (int q = 0; q < 8; ++q)
      BwT[(q + 8 * hf) * 264 + r] = f2bf(bf2f(bh[q]) * wdv);
  }
  __syncthreads();   // #3

  if (wid < 2) {
    f32x4 accS = {};
#pragma unroll
    for (int k2 = 0; k2 < 4; ++k2) {
      bf16x8 af = *(const bf16x8*)&BwT[fr * 264 + wid * 128 + 32 * k2 + 8 * g];
      bf16x8 bb = *(const bf16x8*)&xsT[fr * 264 + wid * 128 + 32 * k2 + 8 * g];
      accS = __builtin_amdgcn_mfma_f32_16x16x32_bf16(af, bb, accS, 0, 0, 0);
    }
    *(f32x4*)&sred[wid][fr * 16 + 4 * g] = accS;
  }

  const int strips[2] = { wid, 15 - wid };
  const f32x4 zf = { 0.f, 0.f, 0.f, 0.f };
  const unsigned short* Cbase = Co + ((size_t)b * SEQLEN + (size_t)cidx * CHUNK) * D_STATE;
  const float Dh = Dvec[h];
#pragma unroll
  for (int q = 0; q < 2; ++q) {
    const int lt = strips[q];
    f32x4 acc = zf;
    bf16x8 cf = { 0, 0, 0, 0, 0, 0, 0, 0 };
    if (g < 2) cf = *(const bf16x8*)(Cbase + (lt * 16 + fr) * D_STATE + 8 * g);
    const float acl2 = sc2[lt * 16 + fr];
    const int   lg   = lt * 16 + fr;
    const int npair = (lt + 2) >> 1;
    for (int sp = 0; sp < npair; ++sp) {
#pragma unroll
      for (int ti = 0; ti < 2; ++ti) {
        const int st = 2 * sp + ti;
        if (st < lt) {
          bf16x8 bfg = *(const bf16x8*)&Bs[(st * 16 + fr) * 24 + 8 * g];
          f32x4 G = __builtin_amdgcn_mfma_f32_16x16x32_bf16(bfg, cf, zf, 0, 0, 0);
          f32x4 se2 = *(const f32x4*)&sc2[st * 16 + 4 * g];
          float w0 = exp2f(acl2 - se2[0]);
          float w1 = exp2f(acl2 - se2[1]);
          float w2 = exp2f(acl2 - se2[2]);
          float w3 = exp2f(acl2 - se2[3]);
          uint2 pk;
          pk.x = pk_bf(G[0] * w0, G[1] * w1);
          pk.y = pk_bf(G[2] * w2, G[3] * w3);
          *(uint2*)&Ps[wid][fr * 40 + 16 * ti + 4 * g] = pk;
        } else if (st == lt) {
          bf16x8 bfg = *(const bf16x8*)&Bs[(st * 16 + fr) * 24 + 8 * g];
          f32x4 G = __builtin_amdgcn_mfma_f32_16x16x32_bf16(bfg, cf, zf, 0, 0, 0);
          f32x4 se2 = *(const f32x4*)&sc2[st * 16 + 4 * g];
          const int sbase = st * 16 + 4 * g;
          float w0 = (sbase + 0 <= lg) ? exp2f(acl2 - se2[0]) : 0.f;
          float w1 = (sbase + 1 <= lg) ? exp2f(acl2 - se2[1]) : 0.f;
          float w2 = (sbase + 2 <= lg) ? exp2f(acl2 - se2[2]) : 0.f;
          float w3 = (sbase + 3 <= lg) ? exp2f(acl2 - se2[3]) : 0.f;
          uint2 pk;
          pk.x = pk_bf(G[0] * w0, G[1] * w1);
          pk.y = pk_bf(G[2] * w2, G[3] * w3);
          *(uint2*)&Ps[wid][fr * 40 + 16 * ti + 4 * g] = pk;
        } else {
          uint2 zz; zz.x = 0u; zz.y = 0u;
          *(uint2*)&Ps[wid][fr * 40 + 16 * ti + 4 * g] = zz;
        }
      }
      const bf16x8 pf = *(const bf16x8*)&Ps[wid][fr * 40 + 8 * g];
      const bf16x8 xf = *(const bf16x8*)&xsT[fr * 264 + sp * 32 + 8 * g];
      acc = __builtin_amdgcn_mfma_f32_16x16x32_bf16(xf, pf, acc, 0, 0, 0);
    }
    us4v xs4 = *(const us4v*)&xraw[(lt * 16 + fr + 3) * 16 + 4 * g];
    us4v o = { f2bf(acc[0] + Dh * bf2f(xs4[0])),
               f2bf(acc[1] + Dh * bf2f(xs4[1])),
               f2bf(acc[2] + Dh * bf2f(xs4[2])),
               f2bf(acc[3] + Dh * bf2f(xs4[3])) };
    *(us4v*)(YdT + ((size_t)(b * NHEADS + h) * SEQLEN + (size_t)cidx * CHUNK + lt * 16 + fr) * HEADDIM
             + 4 * g) = o;
  }

  __syncthreads();   // #4
  if (tid < 256) {
    stloc[((size_t)(b * NCHUNKS + cidx) * NHEADS + h) * 256 + tid] = sred[0][tid] + sred[1][tid];
  }
}

// ---------------------------------------------------------------------------
// K4: sequential inter-chunk state recurrence
// ---------------------------------------------------------------------------
__global__ __launch_bounds__(256)
void chunk_scan_kernel(const float* __restrict__ stloc, const float* __restrict__ csum_g,
                       float* __restrict__ stpre) {
  const int b  = blockIdx.x / NHEADS;
  const int h  = blockIdx.x % NHEADS;
  const int pn = threadIdx.x;
  float S = 0.0f;
  for (int c = 0; c < NCHUNKS; ++c) {
    const size_t idx = ((size_t)(b * NCHUNKS + c) * NHEADS + h) * 256 + pn;
    stpre[idx] = S;
    S = __expf(csum_g[(b * NHEADS + h) * NCHUNKS + c]) * S + stloc[idx];
  }
}

// ---------------------------------------------------------------------------
// K5 (tiled): Y_off add, silu(z) gate, RMSNorm -> yn. Dense zbuf.
// ---------------------------------------------------------------------------
#define TT 16
__global__ __launch_bounds__(384)
void yoff_norm_tiled(const unsigned short* __restrict__ YdT,
                     const unsigned short* __restrict__ Co, const float* __restrict__ acum_g,
                     const float* __restrict__ stpre,
                     const unsigned short* __restrict__ zbuf, const float* __restrict__ norm_w,
                     unsigned short* __restrict__ yn) {
  const int r0   = blockIdx.x * TT;
  const int b    = r0 / SEQLEN;
  const int t0   = r0 % SEQLEN;
  const int cidx = t0 / CHUNK;
  const int d    = threadIdx.x;
  const int h    = d >> 4, p = d & 15;
  const int wv   = d >> 6;

  __shared__ unsigned short Yt[NHEADS * TT * 16];
  __shared__ float At[NHEADS * TT];
  __shared__ float Ct[TT * 16];
  __shared__ float red[TT][6];

  {
    us8v* Yt8 = (us8v*)Yt;
#pragma unroll
    for (int rep = 0; rep < 2; ++rep) {
      int j = d + rep * 384;
      int hh = j >> 5, q = j & 31;
      const size_t src = ((size_t)(b * NHEADS + hh) * SEQLEN + t0) * HEADDIM + q * 8;
      Yt8[j] = *(const us8v*)(YdT + src);
    }
    At[d] = acum_g[(size_t)(b * NHEADS + (d >> 4)) * SEQLEN + t0 + (d & 15)];
    if (d < TT * 16) Ct[d] = bf2f(Co[(size_t)r0 * D_STATE + d]);
  }

  float S[16];
  {
    const float* Sp = stpre + ((size_t)(b * NCHUNKS + cidx) * NHEADS + h) * 256 + p * 16;
#pragma unroll
    for (int q = 0; q < 4; ++q) {
      float4 v4 = *(const float4*)(Sp + 4 * q);
      S[4 * q + 0] = v4.x; S[4 * q + 1] = v4.y; S[4 * q + 2] = v4.z; S[4 * q + 3] = v4.w;
    }
  }
  const float nw = norm_w[d];
  __syncthreads();

  float yg[TT];
#pragma unroll
  for (int tt = 0; tt < TT; ++tt) {
    float dot = 0.f;
#pragma unroll
    for (int n = 0; n < 16; ++n) dot += Ct[tt * 16 + n] * S[n];
    const float acl = At[h * TT + tt];
    float y = bf2f(Yt[h * 256 + tt * 16 + p]) + __expf(acl) * dot;
    const float z = bf2f(zbuf[(size_t)(r0 + tt) * 384 + d]);
    yg[tt] = y * silu_f(z);
    float s = yg[tt] * yg[tt];
#pragma unroll
    for (int off = 32; off > 0; off >>= 1) s += __shfl_down(s, off);
    if ((d & 63) == 0) red[tt][wv] = s;
  }
  __syncthreads();

#pragma unroll
  for (int tt = 0; tt < TT; ++tt) {
    const float tot = red[tt][0] + red[tt][1] + red[tt][2] + red[tt][3] + red[tt][4] + red[tt][5];
    const float scale = rsqrtf(tot * (1.0f / D_INNER) + EPS);
    yn[(size_t)(r0 + tt) * D_INNER + d] = f2bf(yg[tt] * scale * nw);
  }
}

// ---------------------------------------------------------------------------
extern "C" void kernel_launch(void* const* d_in, const int* in_sizes, int n_in,
                              void* d_out, int out_size, void* d_ws, size_t ws_size,
                              hipStream_t stream) {
  const float* u        = (const float*)d_in[0];
  const float* support  = (const float*)d_in[1];
  const float* W_in     = (const float*)d_in[2];
  const float* W_in_b   = (const float*)d_in[3];
  const float* conv_w   = (const float*)d_in[4];
  const float* conv_b   = (const float*)d_in[5];
  const float* conv_w_b = (const float*)d_in[6];
  const float* conv_b_b = (const float*)d_in[7];
  const float* dt_bias  = (const float*)d_in[8];
  const float* A_log    = (const float*)d_in[9];
  const float* Dvec     = (const float*)d_in[10];
  const float* norm_w   = (const float*)d_in[11];
  const float* W_out    = (const float*)d_in[12];
  float* out = (float*)d_out;
  char* wsb  = (char*)d_ws;

  unsigned short* Wi_b  = (unsigned short*)(wsb);                 // [808][192]
  unsigned short* Wo_b  = Wi_b + (size_t)D_IN_PROJ * D_MODEL;     // [192][384]
  unsigned short* Wib_b = Wo_b + (size_t)D_MODEL * D_INNER;       // [16][192]
  unsigned short* zbuf  = Wib_b + (size_t)D_STATE * D_MODEL;      // [row][384]
  unsigned short* xT    = zbuf + (size_t)ROWS * D_INNER;          // [b][h][t][16] raw x
  unsigned short* Braw  = xT + (size_t)ROWS * D_INNER;            // [b][t][16]
  unsigned short* draw  = Braw + (size_t)ROWS * D_STATE;          // [b][t][24]
  unsigned short* craw  = draw + (size_t)ROWS * NHEADS;           // [b][t][16]
  unsigned short* Bo    = craw + (size_t)ROWS * D_STATE;          // [b][t][16]
  unsigned short* Co    = Bo + (size_t)ROWS * D_STATE;            // [b][t][16]
  unsigned short* YdT   = Co + (size_t)ROWS * D_STATE;            // [b][h][t][16]
  unsigned short* yn    = YdT + (size_t)ROWS * D_INNER;           // [row][384]
  float* dtoT  = (float*)(yn + (size_t)ROWS * D_INNER);           // [b][h][t]
  float* acum  = dtoT  + (size_t)ROWS * NHEADS;                   // [b][h][t]
  float* csum  = acum  + (size_t)BATCH * NHEADS * SEQLEN;
  float* stloc = csum  + (size_t)BATCH * NHEADS * NCHUNKS;
  float* stpre = stloc + (size_t)BATCH * NCHUNKS * NHEADS * 256;

  cvt3_kernel<<<224, 256, 0, stream>>>(W_in, Wi_b, (long)D_IN_PROJ * D_MODEL,
                                       W_out, Wo_b, (long)D_MODEL * D_INNER,
                                       W_in_b, Wib_b, (long)D_STATE * D_MODEL);
  // K1a: routed in-proj (z/x/B/dt into dense consumer layouts)
  gemm_bf16<true, true, true><<<dim3(7, ROWS / 128), 256, 0, stream>>>(
      u, Wi_b, nullptr, ROWS, D_IN_PROJ, D_MODEL, zbuf, xT, Braw, draw);
  // K1b: support @ W_in_b^T -> craw (bf16)
  gemm_bf16<true, true, false><<<dim3(1, ROWS / 128), 256, 0, stream>>>(
      support, Wib_b, craw, ROWS, D_STATE, D_MODEL, nullptr, nullptr, nullptr, nullptr);
  conv_bcdt<<<CBC_NB + CDT_NB, 256, 0, stream>>>(
      Braw, craw, draw, conv_w, conv_b, conv_w_b, conv_b_b, dt_bias, Bo, Co, dtoT);
  ssd_mfma_kernel<<<dim3(NHEADS, NCHUNKS, BATCH), 512, 0, stream>>>(
      xT, Bo, Co, dtoT, A_log, conv_w, conv_b, Dvec, YdT, acum, csum, stloc);
  chunk_scan_kernel<<<BATCH * NHEADS, 256, 0, stream>>>(stloc, csum, stpre);
  yoff_norm_tiled<<<ROWS / TT, 384, 0, stream>>>(YdT, Co, acum, stpre, zbuf, norm_w, yn);
  gemm_bf16<false, false, false><<<dim3((D_MODEL + 127) / 128, ROWS / 128), 256, 0, stream>>>(
      yn, Wo_b, out, ROWS, D_MODEL, D_INNER, nullptr, nullptr, nullptr, nullptr);
}

// Round 15
// 123.837 us; speedup vs baseline: 1.2892x; 1.0392x over previous
//
#include <hip/hip_runtime.h>
#include <cmath>

#define ROWS      16384
#define SEQLEN    8192
#define BATCH     2
#define NHEADS    24
#define HEADDIM   16
#define D_STATE   16
#define D_INNER   384
#define D_MODEL   192
#define D_IN_PROJ 808
#define CONV_DIM  400
#define NCHUNKS   32
#define CHUNK     256
#define EPS       1e-5f
#define LOG2E     1.44269504088896f

typedef short bf16x8 __attribute__((ext_vector_type(8)));
typedef float f32x4  __attribute__((ext_vector_type(4)));
typedef unsigned short us4v __attribute__((ext_vector_type(4)));
typedef unsigned short us8v __attribute__((ext_vector_type(8)));

__device__ __forceinline__ float silu_f(float x) { return x / (1.0f + expf(-x)); }
__device__ __forceinline__ float softplus_f(float x) { return (x > 20.0f) ? x : log1pf(expf(x)); }
__device__ __forceinline__ unsigned short f2bf(float x) {
  unsigned u = __builtin_bit_cast(unsigned, x);
  u += 0x7fff + ((u >> 16) & 1);
  return (unsigned short)(u >> 16);
}
__device__ __forceinline__ float bf2f(unsigned short s) {
  unsigned u = (unsigned)s << 16;
  return __builtin_bit_cast(float, u);
}
__device__ __forceinline__ unsigned pk_bf(float a, float b) {
  unsigned ua = __builtin_bit_cast(unsigned, a) + 0x7fffu;
  unsigned ub = __builtin_bit_cast(unsigned, b) + 0x7fffu;
  return __builtin_amdgcn_perm(ub, ua, 0x07060302u);
}

// ---------------------------------------------------------------------------
// K0: fp32 -> bf16 weights (W_in, W_out, W_in_b)
// ---------------------------------------------------------------------------
__global__ __launch_bounds__(256)
void cvt3_kernel(const float* __restrict__ a, unsigned short* __restrict__ ao, long na,
                 const float* __restrict__ b, unsigned short* __restrict__ bo, long nb,
                 const float* __restrict__ c, unsigned short* __restrict__ co, long nc) {
  const long t0 = na >> 2, t1 = t0 + (nb >> 2), t2 = t1 + (nc >> 2);
  const long stride = (long)gridDim.x * blockDim.x;
  for (long i = (long)blockIdx.x * blockDim.x + threadIdx.x; i < t2; i += stride) {
    const float4* s; us4v* d; long j;
    if (i < t0)      { s = (const float4*)a; d = (us4v*)ao; j = i; }
    else if (i < t1) { s = (const float4*)b; d = (us4v*)bo; j = i - t0; }
    else             { s = (const float4*)c; d = (us4v*)co; j = i - t1; }
    float4 v = s[j];
    us4v o = { f2bf(v.x), f2bf(v.y), f2bf(v.z), f2bf(v.w) };
    d[j] = o;
  }
}

// ---------------------------------------------------------------------------
// MFMA bf16 GEMM. ROUTE=true: in-proj output split into consumer-native dense
// buffers (z->zbuf, x->head-major xT, Braw, draw).
// ---------------------------------------------------------------------------
template<bool A_F32, bool OUT_BF16, bool ROUTE>
__launch_bounds__(256, 3)
__global__ void gemm_bf16(const void* __restrict__ Ap,
                          const unsigned short* __restrict__ W,
                          void* __restrict__ Cp, int M, int N, int K,
                          unsigned short* __restrict__ zbuf,
                          unsigned short* __restrict__ xT,
                          unsigned short* __restrict__ Braw,
                          unsigned short* __restrict__ draw) {
  constexpr int BM = 128, BN = 128, BK = 32, LDK = 40;
  __shared__ unsigned short As[2][BM * LDK];
  __shared__ unsigned short Ws[2][BN * LDK];
  const int tid  = threadIdx.x;
  const int wid  = tid >> 6, lane = tid & 63;
  const int wr   = wid >> 1, wc = wid & 1;
  const int fr   = lane & 15, fq = lane >> 4;
  const long m0  = (long)blockIdx.y * BM;
  const int  n0  = blockIdx.x * BN;

  f32x4 acc[4][4] = {};

  auto stage = [&](int k0, int buf) {
    if (A_F32) {
      const float* A = (const float*)Ap;
#pragma unroll
      for (int p = 0; p < 2; ++p) {
        int flat = p * 2048 + tid * 8;
        int r = flat >> 5, c = flat & 31;
        const float4* src = (const float4*)(A + (m0 + r) * (long)K + k0 + c);
        float4 v0 = src[0], v1 = src[1];
        us8v o = { f2bf(v0.x), f2bf(v0.y), f2bf(v0.z), f2bf(v0.w),
                   f2bf(v1.x), f2bf(v1.y), f2bf(v1.z), f2bf(v1.w) };
        *(us8v*)&As[buf][r * LDK + c] = o;
      }
    } else {
      const unsigned short* A = (const unsigned short*)Ap;
#pragma unroll
      for (int p = 0; p < 2; ++p) {
        int flat = p * 2048 + tid * 8;
        int r = flat >> 5, c = flat & 31;
        us8v v = *(const us8v*)(A + (m0 + r) * (long)K + k0 + c);
        *(us8v*)&As[buf][r * LDK + c] = v;
      }
    }
#pragma unroll
    for (int p = 0; p < 2; ++p) {
      int flat = p * 2048 + tid * 8;
      int r = flat >> 5, c = flat & 31;
      int gn = n0 + r;
      us8v v = { 0, 0, 0, 0, 0, 0, 0, 0 };
      if (gn < N) v = *(const us8v*)(W + (long)gn * K + k0 + c);
      *(us8v*)&Ws[buf][r * LDK + c] = v;
    }
  };

  const int nk = K / BK;
  stage(0, 0);
  __syncthreads();
  for (int kt = 0; kt < nk; ++kt) {
    const int cur = kt & 1;
    if (kt + 1 < nk) stage((kt + 1) * BK, cur ^ 1);
    bf16x8 af[4], bfr[4];
#pragma unroll
    for (int m = 0; m < 4; ++m)
      af[m] = *(const bf16x8*)&As[cur][(wr * 64 + m * 16 + fr) * LDK + fq * 8];
#pragma unroll
    for (int n = 0; n < 4; ++n)
      bfr[n] = *(const bf16x8*)&Ws[cur][(wc * 64 + n * 16 + fr) * LDK + fq * 8];
#pragma unroll
    for (int m = 0; m < 4; ++m)
#pragma unroll
      for (int n = 0; n < 4; ++n)
        acc[m][n] = __builtin_amdgcn_mfma_f32_16x16x32_bf16(bfr[n], af[m], acc[m][n], 0, 0, 0);
    __syncthreads();
  }

#pragma unroll
  for (int m = 0; m < 4; ++m) {
    const long gm = m0 + wr * 64 + m * 16 + fr;
#pragma unroll
    for (int n = 0; n < 4; ++n) {
      const int gn = n0 + wc * 64 + n * 16 + fq * 4;
      if (gn < N) {
        if (ROUTE) {
          us4v o = { f2bf(acc[m][n][0]), f2bf(acc[m][n][1]),
                     f2bf(acc[m][n][2]), f2bf(acc[m][n][3]) };
          const int bb = (int)(gm >> 13);
          const long t = gm & 8191;
          if (gn < 384) {
            *(us4v*)(zbuf + gm * 384 + gn) = o;
          } else if (gn < 768) {
            const int c = gn - 384, hh = c >> 4, ii = c & 15;
            *(us4v*)(xT + (((size_t)(bb * NHEADS + hh) * SEQLEN + t) << 4) + ii) = o;
          } else if (gn < 784) {
            *(us4v*)(Braw + gm * 16 + (gn - 768)) = o;
          } else {
            *(us4v*)(draw + gm * 24 + (gn - 784)) = o;
          }
        } else if (OUT_BF16) {
          us4v o = { f2bf(acc[m][n][0]), f2bf(acc[m][n][1]),
                     f2bf(acc[m][n][2]), f2bf(acc[m][n][3]) };
          *(us4v*)((unsigned short*)Cp + gm * N + gn) = o;
        } else {
          float4 o = make_float4(acc[m][n][0], acc[m][n][1], acc[m][n][2], acc[m][n][3]);
          *(float4*)((float*)Cp + gm * N + gn) = o;
        }
      }
    }
  }
}

// ---------------------------------------------------------------------------
// K2: B/C conv + dt softplus, dense raw buffers. 448 role-pure blocks.
// ---------------------------------------------------------------------------
#define CBC_NB  (ROWS * 4 / 256)    // 256
#define CDT_NB  (ROWS * 3 / 256)    // 192

__global__ __launch_bounds__(256)
void conv_bcdt(const unsigned short* __restrict__ Braw, const unsigned short* __restrict__ craw,
               const unsigned short* __restrict__ draw,
               const float* __restrict__ conv_w, const float* __restrict__ conv_b,
               const float* __restrict__ conv_w_b, const float* __restrict__ conv_b_b,
               const float* __restrict__ dt_bias,
               unsigned short* __restrict__ Bo, unsigned short* __restrict__ Co,
               float* __restrict__ dtoT) {
  const int blk = blockIdx.x;
  const us8v z8 = { 0, 0, 0, 0, 0, 0, 0, 0 };

  if (blk < CBC_NB) {
    const int idx = blk * 256 + threadIdx.x;
    const int row = idx / 4, q = idx % 4;
    const int b = row / SEQLEN, t = row % SEQLEN;

    const unsigned short* src = (q < 2) ? Braw : craw;
    const float* cw = (q < 2) ? conv_w + 384 * 4 : conv_w_b;
    const float* cb = (q < 2) ? conv_b + 384 : conv_b_b;
    const int c0 = (q & 1) * 8;
    const unsigned short* base = src + (size_t)row * D_STATE + c0;
    us8v x0 = (t >= 3) ? *(const us8v*)(base - 3 * D_STATE) : z8;
    us8v x1 = (t >= 2) ? *(const us8v*)(base - 2 * D_STATE) : z8;
    us8v x2 = (t >= 1) ? *(const us8v*)(base - 1 * D_STATE) : z8;
    us8v x3 = *(const us8v*)base;
    us8v o;
#pragma unroll
    for (int ch = 0; ch < 8; ++ch) {
      const float4 wv = *(const float4*)(cw + (c0 + ch) * 4);
      float acc = cb[c0 + ch] + wv.x * bf2f(x0[ch]) + wv.y * bf2f(x1[ch])
                + wv.z * bf2f(x2[ch]) + wv.w * bf2f(x3[ch]);
      o[ch] = f2bf(silu_f(acc));
    }
    if (q < 2) *(us8v*)(Bo + (size_t)row * D_STATE + c0) = o;
    else       *(us8v*)(Co + (size_t)row * D_STATE + c0) = o;
  } else {
    const int idx = (blk - CBC_NB) * 256 + threadIdx.x;
    const int row = idx / 3, q = idx % 3;
    const int b = row / SEQLEN, t = row % SEQLEN;
    const int h0 = q * 8;
    us8v dv = *(const us8v*)(draw + (size_t)row * 24 + h0);
#pragma unroll
    for (int j = 0; j < 8; ++j) {
      float v = bf2f(dv[j]) + dt_bias[h0 + j];
      dtoT[(size_t)(b * NHEADS + h0 + j) * SEQLEN + t] = softplus_f(v);
    }
  }
}

// ---------------------------------------------------------------------------
// K3 (MFMA, 8 waves, fused x-conv, factored decay):
//  Bs holds B rows pre-scaled by exp2(sc2[tile_end(s)] - sc2[s])  (<= 1).
//  Sub-diagonal tiles: P = G * exp2(acl2 - scE[st])  -> 1 exp/tile.
//  Diagonal tile: raw B re-fetched from L2-hot Bo; old 4-exp masked path
//  (factored form would overflow: exp(acl - ac_end) >= 1).
// ---------------------------------------------------------------------------
__global__ __launch_bounds__(512, 4)
void ssd_mfma_kernel(const unsigned short* __restrict__ xT, const unsigned short* __restrict__ Bo,
                     const unsigned short* __restrict__ Co, const float* __restrict__ dtoT,
                     const float* __restrict__ A_log, const float* __restrict__ conv_w,
                     const float* __restrict__ conv_b, const float* __restrict__ Dvec,
                     unsigned short* __restrict__ YdT, float* __restrict__ acum_g,
                     float* __restrict__ csum_g, float* __restrict__ stloc) {
  const int h    = blockIdx.x;
  const int cidx = blockIdx.y;
  const int b    = blockIdx.z;
  const int tid  = threadIdx.x;
  const int wid  = tid >> 6, lane = tid & 63;
  const int fr   = lane & 15, g = lane >> 4;

  __shared__ unsigned short Bs[256 * 24 + 32];
  __shared__ unsigned short xsT[16 * 264];
  __shared__ unsigned short BwT[16 * 264];
  __shared__ unsigned short Ps[8][16 * 40];
  __shared__ unsigned short xraw[259 * 16 + 8];
  __shared__ float sc[CHUNK];
  __shared__ float sc2[CHUNK];
  __shared__ float scE[16];
  __shared__ float sred[2][256];
  __shared__ float wsum[4];

  const float Ah = -expf(A_log[h]);
  const us8v z8 = { 0, 0, 0, 0, 0, 0, 0, 0 };

  // ---- phase 1: cumsum wave-scan + pad zeros + raw x window ----
  float v = 0.f;
  if (tid < CHUNK) {
    v = dtoT[(size_t)(b * NHEADS + h) * SEQLEN + (size_t)cidx * CHUNK + tid] * Ah;
#pragma unroll
    for (int off = 1; off < 64; off <<= 1) {
      float u = __shfl_up(v, off, 64);
      if (lane >= off) v += u;
    }
    if (lane == 63) wsum[wid] = v;
  }

  const int r  = tid >> 1;
  const int hf = tid & 1;
  const size_t rowbase = (size_t)b * SEQLEN + (size_t)cidx * CHUNK;
  const size_t rhrow = (size_t)(b * NHEADS + h) * SEQLEN + (size_t)cidx * CHUNK + r;
  const float rdtv = dtoT[rhrow];
  us8v bh = ((const us8v*)(Bo + (rowbase + r) * D_STATE))[hf];
  if (hf == 0) *(us8v*)&Bs[r * 24 + 16] = z8;
  if (tid < 32) Bs[256 * 24 + tid] = 0;
  {
    const int tg = cidx * CHUNK + r - 3;
    us8v xv = z8;
    if (tg >= 0)
      xv = *(const us8v*)(xT + (((size_t)(b * NHEADS + h) * SEQLEN + tg) << 4) + 8 * hf);
    *(us8v*)&xraw[r * 16 + 8 * hf] = xv;
    if (tid < 6) {
      const int rr2 = 256 + (tid >> 1);
      const int hf2 = tid & 1;
      const int tg2 = cidx * CHUNK + rr2 - 3;
      us8v xv2 = *(const us8v*)(xT + (((size_t)(b * NHEADS + h) * SEQLEN + tg2) << 4) + 8 * hf2);
      *(us8v*)&xraw[rr2 * 16 + 8 * hf2] = xv2;
    }
  }
  __syncthreads();   // #1

  // ---- phase 2: conv -> regs; cumsum combine ----
  us8v xsil, xdt8;
  {
    us8v tA = *(const us8v*)&xraw[(r + 0) * 16 + 8 * hf];
    us8v tB = *(const us8v*)&xraw[(r + 1) * 16 + 8 * hf];
    us8v tC = *(const us8v*)&xraw[(r + 2) * 16 + 8 * hf];
    us8v tD = *(const us8v*)&xraw[(r + 3) * 16 + 8 * hf];
    const int cbase = h * HEADDIM + 8 * hf;
#pragma unroll
    for (int ch = 0; ch < 8; ++ch) {
      const float4 wv = *(const float4*)(conv_w + (cbase + ch) * 4);
      float acc = conv_b[cbase + ch] + wv.x * bf2f(tA[ch]) + wv.y * bf2f(tB[ch])
                + wv.z * bf2f(tC[ch]) + wv.w * bf2f(tD[ch]);
      float sv = silu_f(acc);
      xsil[ch] = f2bf(sv);
      xdt8[ch] = f2bf(sv * rdtv);
    }
  }
  const float ctot = wsum[0] + wsum[1] + wsum[2] + wsum[3];
  if (tid < CHUNK) {
    float pre = 0.f;
#pragma unroll
    for (int w = 0; w < 4; ++w) if (w < wid) pre += wsum[w];
    v += pre;
    sc[tid]  = v;
    sc2[tid] = v * LOG2E;
    acum_g[(size_t)(b * NHEADS + h) * SEQLEN + (size_t)cidx * CHUNK + tid] = v;
    if (tid == CHUNK - 1) csum_g[(b * NHEADS + h) * NCHUNKS + cidx] = v;
  }
  __syncthreads();   // #2 (sc/sc2 visible)

  // ---- phase 3: xsil overlay, xsT, BwT, scaled Bs, scE ----
  *(us8v*)&xraw[(r + 3) * 16 + 8 * hf] = xsil;
#pragma unroll
  for (int q = 0; q < 8; ++q)
    xsT[(q + 8 * hf) * 264 + r] = xdt8[q];
  {
    const float wdv = __expf(ctot - sc[r]);
    const float ed  = exp2f(sc2[r | 15] - sc2[r]);   // <= 1
    us8v bscaled;
#pragma unroll
    for (int q = 0; q < 8; ++q) {
      BwT[(q + 8 * hf) * 264 + r] = f2bf(bf2f(bh[q]) * wdv);
      bscaled[q] = f2bf(bf2f(bh[q]) * ed);
    }
    *(us8v*)&Bs[r * 24 + 8 * hf] = bscaled;
  }
  if (tid < 16) scE[tid] = sc2[tid * 16 + 15];
  __syncthreads();   // #3

  // ---- chunk state: waves 0,1 each do K=128 ----
  if (wid < 2) {
    f32x4 accS = {};
#pragma unroll
    for (int k2 = 0; k2 < 4; ++k2) {
      bf16x8 af = *(const bf16x8*)&BwT[fr * 264 + wid * 128 + 32 * k2 + 8 * g];
      bf16x8 bb = *(const bf16x8*)&xsT[fr * 264 + wid * 128 + 32 * k2 + 8 * g];
      accS = __builtin_amdgcn_mfma_f32_16x16x32_bf16(af, bb, accS, 0, 0, 0);
    }
    *(f32x4*)&sred[wid][fr * 16 + 4 * g] = accS;
  }

  // ---- Y_diag strips: wave w -> {w, 15-w}; factored decay ----
  const int strips[2] = { wid, 15 - wid };
  const f32x4 zf = { 0.f, 0.f, 0.f, 0.f };
  const unsigned short* Cbase = Co + rowbase * D_STATE;
  const float Dh = Dvec[h];

  // preload raw B fragments for the two diagonal tiles (L2-hot)
  bf16x8 brawq[2];
#pragma unroll
  for (int q = 0; q < 2; ++q) {
    us8v bv = z8;
    if (g < 2)
      bv = *(const us8v*)(Bo + (rowbase + strips[q] * 16 + fr) * D_STATE + 8 * g);
    brawq[q] = __builtin_bit_cast(bf16x8, bv);
  }

#pragma unroll
  for (int q = 0; q < 2; ++q) {
    const int lt = strips[q];
    f32x4 acc = zf;
    bf16x8 cf = { 0, 0, 0, 0, 0, 0, 0, 0 };
    if (g < 2) cf = *(const bf16x8*)(Cbase + (lt * 16 + fr) * D_STATE + 8 * g);
    const float acl2 = sc2[lt * 16 + fr];
    const int   lg   = lt * 16 + fr;
    const int npair = (lt + 2) >> 1;
    for (int sp = 0; sp < npair; ++sp) {
#pragma unroll
      for (int ti = 0; ti < 2; ++ti) {
        const int st = 2 * sp + ti;
        if (st < lt) {
          // sub-diagonal: scaled B, single exp per tile
          bf16x8 bfg = *(const bf16x8*)&Bs[(st * 16 + fr) * 24 + 8 * g];
          f32x4 G = __builtin_amdgcn_mfma_f32_16x16x32_bf16(bfg, cf, zf, 0, 0, 0);
          const float wl = exp2f(acl2 - scE[st]);
          uint2 pk;
          pk.x = pk_bf(G[0] * wl, G[1] * wl);
          pk.y = pk_bf(G[2] * wl, G[3] * wl);
          *(uint2*)&Ps[wid][fr * 40 + 16 * ti + 4 * g] = pk;
        } else if (st == lt) {
          // diagonal: raw B, per-element exp + mask
          f32x4 G = __builtin_amdgcn_mfma_f32_16x16x32_bf16(brawq[q], cf, zf, 0, 0, 0);
          f32x4 se2 = *(const f32x4*)&sc2[st * 16 + 4 * g];
          const int sbase = st * 16 + 4 * g;
          float w0 = (sbase + 0 <= lg) ? exp2f(acl2 - se2[0]) : 0.f;
          float w1 = (sbase + 1 <= lg) ? exp2f(acl2 - se2[1]) : 0.f;
          float w2 = (sbase + 2 <= lg) ? exp2f(acl2 - se2[2]) : 0.f;
          float w3 = (sbase + 3 <= lg) ? exp2f(acl2 - se2[3]) : 0.f;
          uint2 pk;
          pk.x = pk_bf(G[0] * w0, G[1] * w1);
          pk.y = pk_bf(G[2] * w2, G[3] * w3);
          *(uint2*)&Ps[wid][fr * 40 + 16 * ti + 4 * g] = pk;
        } else {
          uint2 zz; zz.x = 0u; zz.y = 0u;
          *(uint2*)&Ps[wid][fr * 40 + 16 * ti + 4 * g] = zz;
        }
      }
      const bf16x8 pf = *(const bf16x8*)&Ps[wid][fr * 40 + 8 * g];
      const bf16x8 xf = *(const bf16x8*)&xsT[fr * 264 + sp * 32 + 8 * g];
      acc = __builtin_amdgcn_mfma_f32_16x16x32_bf16(xf, pf, acc, 0, 0, 0);
    }
    us4v xs4 = *(const us4v*)&xraw[(lt * 16 + fr + 3) * 16 + 4 * g];
    us4v o = { f2bf(acc[0] + Dh * bf2f(xs4[0])),
               f2bf(acc[1] + Dh * bf2f(xs4[1])),
               f2bf(acc[2] + Dh * bf2f(xs4[2])),
               f2bf(acc[3] + Dh * bf2f(xs4[3])) };
    *(us4v*)(YdT + (rhrow - r + (size_t)lt * 16 + fr) * HEADDIM + 4 * g) = o;
  }

  __syncthreads();   // #4
  if (tid < 256) {
    stloc[((size_t)(b * NCHUNKS + cidx) * NHEADS + h) * 256 + tid] = sred[0][tid] + sred[1][tid];
  }
}

// ---------------------------------------------------------------------------
// K4: sequential inter-chunk state recurrence
// ---------------------------------------------------------------------------
__global__ __launch_bounds__(256)
void chunk_scan_kernel(const float* __restrict__ stloc, const float* __restrict__ csum_g,
                       float* __restrict__ stpre) {
  const int b  = blockIdx.x / NHEADS;
  const int h  = blockIdx.x % NHEADS;
  const int pn = threadIdx.x;
  float S = 0.0f;
  for (int c = 0; c < NCHUNKS; ++c) {
    const size_t idx = ((size_t)(b * NCHUNKS + c) * NHEADS + h) * 256 + pn;
    stpre[idx] = S;
    S = __expf(csum_g[(b * NHEADS + h) * NCHUNKS + c]) * S + stloc[idx];
  }
}

// ---------------------------------------------------------------------------
// K5 (tiled): Y_off add, silu(z) gate, RMSNorm -> yn. Dense zbuf.
// ---------------------------------------------------------------------------
#define TT 16
__global__ __launch_bounds__(384)
void yoff_norm_tiled(const unsigned short* __restrict__ YdT,
                     const unsigned short* __restrict__ Co, const float* __restrict__ acum_g,
                     const float* __restrict__ stpre,
                     const unsigned short* __restrict__ zbuf, const float* __restrict__ norm_w,
                     unsigned short* __restrict__ yn) {
  const int r0   = blockIdx.x * TT;
  const int b    = r0 / SEQLEN;
  const int t0   = r0 % SEQLEN;
  const int cidx = t0 / CHUNK;
  const int d    = threadIdx.x;
  const int h    = d >> 4, p = d & 15;
  const int wv   = d >> 6;

  __shared__ unsigned short Yt[NHEADS * TT * 16];
  __shared__ float At[NHEADS * TT];
  __shared__ float Ct[TT * 16];
  __shared__ float red[TT][6];

  {
    us8v* Yt8 = (us8v*)Yt;
#pragma unroll
    for (int rep = 0; rep < 2; ++rep) {
      int j = d + rep * 384;
      int hh = j >> 5, q = j & 31;
      const size_t src = ((size_t)(b * NHEADS + hh) * SEQLEN + t0) * HEADDIM + q * 8;
      Yt8[j] = *(const us8v*)(YdT + src);
    }
    At[d] = acum_g[(size_t)(b * NHEADS + (d >> 4)) * SEQLEN + t0 + (d & 15)];
    if (d < TT * 16) Ct[d] = bf2f(Co[(size_t)r0 * D_STATE + d]);
  }

  float S[16];
  {
    const float* Sp = stpre + ((size_t)(b * NCHUNKS + cidx) * NHEADS + h) * 256 + p * 16;
#pragma unroll
    for (int q = 0; q < 4; ++q) {
      float4 v4 = *(const float4*)(Sp + 4 * q);
      S[4 * q + 0] = v4.x; S[4 * q + 1] = v4.y; S[4 * q + 2] = v4.z; S[4 * q + 3] = v4.w;
    }
  }
  const float nw = norm_w[d];
  __syncthreads();

  float yg[TT];
#pragma unroll
  for (int tt = 0; tt < TT; ++tt) {
    float dot = 0.f;
#pragma unroll
    for (int n = 0; n < 16; ++n) dot += Ct[tt * 16 + n] * S[n];
    const float acl = At[h * TT + tt];
    float y = bf2f(Yt[h * 256 + tt * 16 + p]) + __expf(acl) * dot;
    const float z = bf2f(zbuf[(size_t)(r0 + tt) * 384 + d]);
    yg[tt] = y * silu_f(z);
    float s = yg[tt] * yg[tt];
#pragma unroll
    for (int off = 32; off > 0; off >>= 1) s += __shfl_down(s, off);
    if ((d & 63) == 0) red[tt][wv] = s;
  }
  __syncthreads();

#pragma unroll
  for (int tt = 0; tt < TT; ++tt) {
    const float tot = red[tt][0] + red[tt][1] + red[tt][2] + red[tt][3] + red[tt][4] + red[tt][5];
    const float scale = rsqrtf(tot * (1.0f / D_INNER) + EPS);
    yn[(size_t)(r0 + tt) * D_INNER + d] = f2bf(yg[tt] * scale * nw);
  }
}

// ---------------------------------------------------------------------------
extern "C" void kernel_launch(void* const* d_in, const int* in_sizes, int n_in,
                              void* d_out, int out_size, void* d_ws, size_t ws_size,
                              hipStream_t stream) {
  const float* u        = (const float*)d_in[0];
  const float* support  = (const float*)d_in[1];
  const float* W_in     = (const float*)d_in[2];
  const float* W_in_b   = (const float*)d_in[3];
  const float* conv_w   = (const float*)d_in[4];
  const float* conv_b   = (const float*)d_in[5];
  const float* conv_w_b = (const float*)d_in[6];
  const float* conv_b_b = (const float*)d_in[7];
  const float* dt_bias  = (const float*)d_in[8];
  const float* A_log    = (const float*)d_in[9];
  const float* Dvec     = (const float*)d_in[10];
  const float* norm_w   = (const float*)d_in[11];
  const float* W_out    = (const float*)d_in[12];
  float* out = (float*)d_out;
  char* wsb  = (char*)d_ws;

  unsigned short* Wi_b  = (unsigned short*)(wsb);
  unsigned short* Wo_b  = Wi_b + (size_t)D_IN_PROJ * D_MODEL;
  unsigned short* Wib_b = Wo_b + (size_t)D_MODEL * D_INNER;
  unsigned short* zbuf  = Wib_b + (size_t)D_STATE * D_MODEL;
  unsigned short* xT    = zbuf + (size_t)ROWS * D_INNER;
  unsigned short* Braw  = xT + (size_t)ROWS * D_INNER;
  unsigned short* draw  = Braw + (size_t)ROWS * D_STATE;
  unsigned short* craw  = draw + (size_t)ROWS * NHEADS;
  unsigned short* Bo    = craw + (size_t)ROWS * D_STATE;
  unsigned short* Co    = Bo + (size_t)ROWS * D_STATE;
  unsigned short* YdT   = Co + (size_t)ROWS * D_STATE;
  unsigned short* yn    = YdT + (size_t)ROWS * D_INNER;
  float* dtoT  = (float*)(yn + (size_t)ROWS * D_INNER);
  float* acum  = dtoT  + (size_t)ROWS * NHEADS;
  float* csum  = acum  + (size_t)BATCH * NHEADS * SEQLEN;
  float* stloc = csum  + (size_t)BATCH * NHEADS * NCHUNKS;
  float* stpre = stloc + (size_t)BATCH * NCHUNKS * NHEADS * 256;

  cvt3_kernel<<<224, 256, 0, stream>>>(W_in, Wi_b, (long)D_IN_PROJ * D_MODEL,
                                       W_out, Wo_b, (long)D_MODEL * D_INNER,
                                       W_in_b, Wib_b, (long)D_STATE * D_MODEL);
  gemm_bf16<true, true, true><<<dim3(7, ROWS / 128), 256, 0, stream>>>(
      u, Wi_b, nullptr, ROWS, D_IN_PROJ, D_MODEL, zbuf, xT, Braw, draw);
  gemm_bf16<true, true, false><<<dim3(1, ROWS / 128), 256, 0, stream>>>(
      support, Wib_b, craw, ROWS, D_STATE, D_MODEL, nullptr, nullptr, nullptr, nullptr);
  conv_bcdt<<<CBC_NB + CDT_NB, 256, 0, stream>>>(
      Braw, craw, draw, conv_w, conv_b, conv_w_b, conv_b_b, dt_bias, Bo, Co, dtoT);
  ssd_mfma_kernel<<<dim3(NHEADS, NCHUNKS, BATCH), 512, 0, stream>>>(
      xT, Bo, Co, dtoT, A_log, conv_w, conv_b, Dvec, YdT, acum, csum, stloc);
  chunk_scan_kernel<<<BATCH * NHEADS, 256, 0, stream>>>(stloc, csum, stpre);
  yoff_norm_tiled<<<ROWS / TT, 384, 0, stream>>>(YdT, Co, acum, stpre, zbuf, norm_w, yn);
  gemm_bf16<false, false, false><<<dim3((D_MODEL + 127) / 128, ROWS / 128), 256, 0, stream>>>(
      yn, Wo_b, out, ROWS, D_MODEL, D_INNER, nullptr, nullptr, nullptr, nullptr);
}

// Round 16
// 123.755 us; speedup vs baseline: 1.2901x; 1.0007x over previous
//
#include <hip/hip_runtime.h>
#include <cmath>

#define ROWS      16384
#define SEQLEN    8192
#define BATCH     2
#define NHEADS    24
#define HEADDIM   16
#define D_STATE   16
#define D_INNER   384
#define D_MODEL   192
#define D_IN_PROJ 808
#define CONV_DIM  400
#define NCHUNKS   32
#define CHUNK     256
#define EPS       1e-5f
#define LOG2E     1.44269504088896f

typedef short bf16x8 __attribute__((ext_vector_type(8)));
typedef float f32x4  __attribute__((ext_vector_type(4)));
typedef unsigned short us4v __attribute__((ext_vector_type(4)));
typedef unsigned short us8v __attribute__((ext_vector_type(8)));

__device__ __forceinline__ float silu_f(float x) { return x / (1.0f + expf(-x)); }
__device__ __forceinline__ float softplus_f(float x) { return (x > 20.0f) ? x : log1pf(expf(x)); }
__device__ __forceinline__ unsigned short f2bf(float x) {
  unsigned u = __builtin_bit_cast(unsigned, x);
  u += 0x7fff + ((u >> 16) & 1);
  return (unsigned short)(u >> 16);
}
__device__ __forceinline__ float bf2f(unsigned short s) {
  unsigned u = (unsigned)s << 16;
  return __builtin_bit_cast(float, u);
}
__device__ __forceinline__ unsigned pk_bf(float a, float b) {
  unsigned ua = __builtin_bit_cast(unsigned, a) + 0x7fffu;
  unsigned ub = __builtin_bit_cast(unsigned, b) + 0x7fffu;
  return __builtin_amdgcn_perm(ub, ua, 0x07060302u);
}

// ---------------------------------------------------------------------------
// K0: fp32 -> bf16 weights (W_in, W_out, W_in_b)
// ---------------------------------------------------------------------------
__global__ __launch_bounds__(256)
void cvt3_kernel(const float* __restrict__ a, unsigned short* __restrict__ ao, long na,
                 const float* __restrict__ b, unsigned short* __restrict__ bo, long nb,
                 const float* __restrict__ c, unsigned short* __restrict__ co, long nc) {
  const long t0 = na >> 2, t1 = t0 + (nb >> 2), t2 = t1 + (nc >> 2);
  const long stride = (long)gridDim.x * blockDim.x;
  for (long i = (long)blockIdx.x * blockDim.x + threadIdx.x; i < t2; i += stride) {
    const float4* s; us4v* d; long j;
    if (i < t0)      { s = (const float4*)a; d = (us4v*)ao; j = i; }
    else if (i < t1) { s = (const float4*)b; d = (us4v*)bo; j = i - t0; }
    else             { s = (const float4*)c; d = (us4v*)co; j = i - t1; }
    float4 v = s[j];
    us4v o = { f2bf(v.x), f2bf(v.y), f2bf(v.z), f2bf(v.w) };
    d[j] = o;
  }
}

// ---------------------------------------------------------------------------
// MFMA bf16 GEMM. ROUTE=true: in-proj output split into consumer-native dense
// buffers (z->zbuf, x->head-major xT, Braw, draw).
// ---------------------------------------------------------------------------
template<bool A_F32, bool OUT_BF16, bool ROUTE>
__launch_bounds__(256, 3)
__global__ void gemm_bf16(const void* __restrict__ Ap,
                          const unsigned short* __restrict__ W,
                          void* __restrict__ Cp, int M, int N, int K,
                          unsigned short* __restrict__ zbuf,
                          unsigned short* __restrict__ xT,
                          unsigned short* __restrict__ Braw,
                          unsigned short* __restrict__ draw) {
  constexpr int BM = 128, BN = 128, BK = 32, LDK = 40;
  __shared__ unsigned short As[2][BM * LDK];
  __shared__ unsigned short Ws[2][BN * LDK];
  const int tid  = threadIdx.x;
  const int wid  = tid >> 6, lane = tid & 63;
  const int wr   = wid >> 1, wc = wid & 1;
  const int fr   = lane & 15, fq = lane >> 4;
  const long m0  = (long)blockIdx.y * BM;
  const int  n0  = blockIdx.x * BN;

  f32x4 acc[4][4] = {};

  auto stage = [&](int k0, int buf) {
    if (A_F32) {
      const float* A = (const float*)Ap;
#pragma unroll
      for (int p = 0; p < 2; ++p) {
        int flat = p * 2048 + tid * 8;
        int r = flat >> 5, c = flat & 31;
        const float4* src = (const float4*)(A + (m0 + r) * (long)K + k0 + c);
        float4 v0 = src[0], v1 = src[1];
        us8v o = { f2bf(v0.x), f2bf(v0.y), f2bf(v0.z), f2bf(v0.w),
                   f2bf(v1.x), f2bf(v1.y), f2bf(v1.z), f2bf(v1.w) };
        *(us8v*)&As[buf][r * LDK + c] = o;
      }
    } else {
      const unsigned short* A = (const unsigned short*)Ap;
#pragma unroll
      for (int p = 0; p < 2; ++p) {
        int flat = p * 2048 + tid * 8;
        int r = flat >> 5, c = flat & 31;
        us8v v = *(const us8v*)(A + (m0 + r) * (long)K + k0 + c);
        *(us8v*)&As[buf][r * LDK + c] = v;
      }
    }
#pragma unroll
    for (int p = 0; p < 2; ++p) {
      int flat = p * 2048 + tid * 8;
      int r = flat >> 5, c = flat & 31;
      int gn = n0 + r;
      us8v v = { 0, 0, 0, 0, 0, 0, 0, 0 };
      if (gn < N) v = *(const us8v*)(W + (long)gn * K + k0 + c);
      *(us8v*)&Ws[buf][r * LDK + c] = v;
    }
  };

  const int nk = K / BK;
  stage(0, 0);
  __syncthreads();
  for (int kt = 0; kt < nk; ++kt) {
    const int cur = kt & 1;
    if (kt + 1 < nk) stage((kt + 1) * BK, cur ^ 1);
    bf16x8 af[4], bfr[4];
#pragma unroll
    for (int m = 0; m < 4; ++m)
      af[m] = *(const bf16x8*)&As[cur][(wr * 64 + m * 16 + fr) * LDK + fq * 8];
#pragma unroll
    for (int n = 0; n < 4; ++n)
      bfr[n] = *(const bf16x8*)&Ws[cur][(wc * 64 + n * 16 + fr) * LDK + fq * 8];
#pragma unroll
    for (int m = 0; m < 4; ++m)
#pragma unroll
      for (int n = 0; n < 4; ++n)
        acc[m][n] = __builtin_amdgcn_mfma_f32_16x16x32_bf16(bfr[n], af[m], acc[m][n], 0, 0, 0);
    __syncthreads();
  }

#pragma unroll
  for (int m = 0; m < 4; ++m) {
    const long gm = m0 + wr * 64 + m * 16 + fr;
#pragma unroll
    for (int n = 0; n < 4; ++n) {
      const int gn = n0 + wc * 64 + n * 16 + fq * 4;
      if (gn < N) {
        if (ROUTE) {
          us4v o = { f2bf(acc[m][n][0]), f2bf(acc[m][n][1]),
                     f2bf(acc[m][n][2]), f2bf(acc[m][n][3]) };
          const int bb = (int)(gm >> 13);
          const long t = gm & 8191;
          if (gn < 384) {
            *(us4v*)(zbuf + gm * 384 + gn) = o;
          } else if (gn < 768) {
            const int c = gn - 384, hh = c >> 4, ii = c & 15;
            *(us4v*)(xT + (((size_t)(bb * NHEADS + hh) * SEQLEN + t) << 4) + ii) = o;
          } else if (gn < 784) {
            *(us4v*)(Braw + gm * 16 + (gn - 768)) = o;
          } else {
            *(us4v*)(draw + gm * 24 + (gn - 784)) = o;
          }
        } else if (OUT_BF16) {
          us4v o = { f2bf(acc[m][n][0]), f2bf(acc[m][n][1]),
                     f2bf(acc[m][n][2]), f2bf(acc[m][n][3]) };
          *(us4v*)((unsigned short*)Cp + gm * N + gn) = o;
        } else {
          float4 o = make_float4(acc[m][n][0], acc[m][n][1], acc[m][n][2], acc[m][n][3]);
          *(float4*)((float*)Cp + gm * N + gn) = o;
        }
      }
    }
  }
}

// ---------------------------------------------------------------------------
// K2: B/C conv + dt softplus, dense raw buffers. 448 role-pure blocks.
// ---------------------------------------------------------------------------
#define CBC_NB  (ROWS * 4 / 256)    // 256
#define CDT_NB  (ROWS * 3 / 256)    // 192

__global__ __launch_bounds__(256)
void conv_bcdt(const unsigned short* __restrict__ Braw, const unsigned short* __restrict__ craw,
               const unsigned short* __restrict__ draw,
               const float* __restrict__ conv_w, const float* __restrict__ conv_b,
               const float* __restrict__ conv_w_b, const float* __restrict__ conv_b_b,
               const float* __restrict__ dt_bias,
               unsigned short* __restrict__ Bo, unsigned short* __restrict__ Co,
               float* __restrict__ dtoT) {
  const int blk = blockIdx.x;
  const us8v z8 = { 0, 0, 0, 0, 0, 0, 0, 0 };

  if (blk < CBC_NB) {
    const int idx = blk * 256 + threadIdx.x;
    const int row = idx / 4, q = idx % 4;
    const int b = row / SEQLEN, t = row % SEQLEN;

    const unsigned short* src = (q < 2) ? Braw : craw;
    const float* cw = (q < 2) ? conv_w + 384 * 4 : conv_w_b;
    const float* cb = (q < 2) ? conv_b + 384 : conv_b_b;
    const int c0 = (q & 1) * 8;
    const unsigned short* base = src + (size_t)row * D_STATE + c0;
    us8v x0 = (t >= 3) ? *(const us8v*)(base - 3 * D_STATE) : z8;
    us8v x1 = (t >= 2) ? *(const us8v*)(base - 2 * D_STATE) : z8;
    us8v x2 = (t >= 1) ? *(const us8v*)(base - 1 * D_STATE) : z8;
    us8v x3 = *(const us8v*)base;
    us8v o;
#pragma unroll
    for (int ch = 0; ch < 8; ++ch) {
      const float4 wv = *(const float4*)(cw + (c0 + ch) * 4);
      float acc = cb[c0 + ch] + wv.x * bf2f(x0[ch]) + wv.y * bf2f(x1[ch])
                + wv.z * bf2f(x2[ch]) + wv.w * bf2f(x3[ch]);
      o[ch] = f2bf(silu_f(acc));
    }
    if (q < 2) *(us8v*)(Bo + (size_t)row * D_STATE + c0) = o;
    else       *(us8v*)(Co + (size_t)row * D_STATE + c0) = o;
  } else {
    const int idx = (blk - CBC_NB) * 256 + threadIdx.x;
    const int row = idx / 3, q = idx % 3;
    const int b = row / SEQLEN, t = row % SEQLEN;
    const int h0 = q * 8;
    us8v dv = *(const us8v*)(draw + (size_t)row * 24 + h0);
#pragma unroll
    for (int j = 0; j < 8; ++j) {
      float v = bf2f(dv[j]) + dt_bias[h0 + j];
      dtoT[(size_t)(b * NHEADS + h0 + j) * SEQLEN + t] = softplus_f(v);
    }
  }
}

// ---------------------------------------------------------------------------
// K3 (MFMA, 8 waves, fused x-conv, factored decay, dual-chain Y_diag):
// Each wave runs its two strips {wid, 15-wid} in LOCKSTEP - both strips'
// G-MFMAs + exp/pack are independent and overlap the serial Ps round-trips.
// Single per-wave Ps buffer reused (per-wave LDS ops are in issue order).
// ---------------------------------------------------------------------------
__global__ __launch_bounds__(512, 4)
void ssd_mfma_kernel(const unsigned short* __restrict__ xT, const unsigned short* __restrict__ Bo,
                     const unsigned short* __restrict__ Co, const float* __restrict__ dtoT,
                     const float* __restrict__ A_log, const float* __restrict__ conv_w,
                     const float* __restrict__ conv_b, const float* __restrict__ Dvec,
                     unsigned short* __restrict__ YdT, float* __restrict__ acum_g,
                     float* __restrict__ csum_g, float* __restrict__ stloc) {
  const int h    = blockIdx.x;
  const int cidx = blockIdx.y;
  const int b    = blockIdx.z;
  const int tid  = threadIdx.x;
  const int wid  = tid >> 6, lane = tid & 63;
  const int fr   = lane & 15, g = lane >> 4;

  __shared__ unsigned short Bs[256 * 24 + 32];
  __shared__ unsigned short xsT[16 * 264];
  __shared__ unsigned short BwT[16 * 264];
  __shared__ unsigned short Ps[8][16 * 40];
  __shared__ unsigned short xraw[259 * 16 + 8];
  __shared__ float sc[CHUNK];
  __shared__ float sc2[CHUNK];
  __shared__ float scE[16];
  __shared__ float sred[2][256];
  __shared__ float wsum[4];

  const float Ah = -expf(A_log[h]);
  const us8v z8 = { 0, 0, 0, 0, 0, 0, 0, 0 };

  // ---- phase 1: cumsum wave-scan + pad zeros + raw x window ----
  float v = 0.f;
  if (tid < CHUNK) {
    v = dtoT[(size_t)(b * NHEADS + h) * SEQLEN + (size_t)cidx * CHUNK + tid] * Ah;
#pragma unroll
    for (int off = 1; off < 64; off <<= 1) {
      float u = __shfl_up(v, off, 64);
      if (lane >= off) v += u;
    }
    if (lane == 63) wsum[wid] = v;
  }

  const int r  = tid >> 1;
  const int hf = tid & 1;
  const size_t rowbase = (size_t)b * SEQLEN + (size_t)cidx * CHUNK;
  const size_t rhrow = (size_t)(b * NHEADS + h) * SEQLEN + (size_t)cidx * CHUNK + r;
  const float rdtv = dtoT[rhrow];
  us8v bh = ((const us8v*)(Bo + (rowbase + r) * D_STATE))[hf];
  if (hf == 0) *(us8v*)&Bs[r * 24 + 16] = z8;
  if (tid < 32) Bs[256 * 24 + tid] = 0;
  {
    const int tg = cidx * CHUNK + r - 3;
    us8v xv = z8;
    if (tg >= 0)
      xv = *(const us8v*)(xT + (((size_t)(b * NHEADS + h) * SEQLEN + tg) << 4) + 8 * hf);
    *(us8v*)&xraw[r * 16 + 8 * hf] = xv;
    if (tid < 6) {
      const int rr2 = 256 + (tid >> 1);
      const int hf2 = tid & 1;
      const int tg2 = cidx * CHUNK + rr2 - 3;
      us8v xv2 = *(const us8v*)(xT + (((size_t)(b * NHEADS + h) * SEQLEN + tg2) << 4) + 8 * hf2);
      *(us8v*)&xraw[rr2 * 16 + 8 * hf2] = xv2;
    }
  }
  __syncthreads();   // #1

  // ---- phase 2: conv -> regs; cumsum combine ----
  us8v xsil, xdt8;
  {
    us8v tA = *(const us8v*)&xraw[(r + 0) * 16 + 8 * hf];
    us8v tB = *(const us8v*)&xraw[(r + 1) * 16 + 8 * hf];
    us8v tC = *(const us8v*)&xraw[(r + 2) * 16 + 8 * hf];
    us8v tD = *(const us8v*)&xraw[(r + 3) * 16 + 8 * hf];
    const int cbase = h * HEADDIM + 8 * hf;
#pragma unroll
    for (int ch = 0; ch < 8; ++ch) {
      const float4 wv = *(const float4*)(conv_w + (cbase + ch) * 4);
      float acc = conv_b[cbase + ch] + wv.x * bf2f(tA[ch]) + wv.y * bf2f(tB[ch])
                + wv.z * bf2f(tC[ch]) + wv.w * bf2f(tD[ch]);
      float sv = silu_f(acc);
      xsil[ch] = f2bf(sv);
      xdt8[ch] = f2bf(sv * rdtv);
    }
  }
  const float ctot = wsum[0] + wsum[1] + wsum[2] + wsum[3];
  if (tid < CHUNK) {
    float pre = 0.f;
#pragma unroll
    for (int w = 0; w < 4; ++w) if (w < wid) pre += wsum[w];
    v += pre;
    sc[tid]  = v;
    sc2[tid] = v * LOG2E;
    acum_g[(size_t)(b * NHEADS + h) * SEQLEN + (size_t)cidx * CHUNK + tid] = v;
    if (tid == CHUNK - 1) csum_g[(b * NHEADS + h) * NCHUNKS + cidx] = v;
  }
  __syncthreads();   // #2 (sc/sc2 visible)

  // ---- phase 3: xsil overlay, xsT, BwT, scaled Bs, scE ----
  *(us8v*)&xraw[(r + 3) * 16 + 8 * hf] = xsil;
#pragma unroll
  for (int q = 0; q < 8; ++q)
    xsT[(q + 8 * hf) * 264 + r] = xdt8[q];
  {
    const float wdv = __expf(ctot - sc[r]);
    const float ed  = exp2f(sc2[r | 15] - sc2[r]);   // <= 1
    us8v bscaled;
#pragma unroll
    for (int q = 0; q < 8; ++q) {
      BwT[(q + 8 * hf) * 264 + r] = f2bf(bf2f(bh[q]) * wdv);
      bscaled[q] = f2bf(bf2f(bh[q]) * ed);
    }
    *(us8v*)&Bs[r * 24 + 8 * hf] = bscaled;
  }
  if (tid < 16) scE[tid] = sc2[tid * 16 + 15];
  __syncthreads();   // #3

  // ---- chunk state: waves 0,1 each do K=128 ----
  if (wid < 2) {
    f32x4 accS = {};
#pragma unroll
    for (int k2 = 0; k2 < 4; ++k2) {
      bf16x8 af = *(const bf16x8*)&BwT[fr * 264 + wid * 128 + 32 * k2 + 8 * g];
      bf16x8 bb = *(const bf16x8*)&xsT[fr * 264 + wid * 128 + 32 * k2 + 8 * g];
      accS = __builtin_amdgcn_mfma_f32_16x16x32_bf16(af, bb, accS, 0, 0, 0);
    }
    *(f32x4*)&sred[wid][fr * 16 + 4 * g] = accS;
  }

  // ---- Y_diag: dual-chain lockstep over strips lt0=wid (short), lt1=15-wid ----
  const f32x4 zf = { 0.f, 0.f, 0.f, 0.f };
  const unsigned short* Cbase = Co + rowbase * D_STATE;
  const float Dh = Dvec[h];

  const int lt0 = wid, lt1 = 15 - wid;
  const int lg0 = lt0 * 16 + fr, lg1 = lt1 * 16 + fr;
  const int npair0 = (lt0 + 2) >> 1, npair1 = (lt1 + 2) >> 1;

  bf16x8 cf0 = { 0,0,0,0,0,0,0,0 }, cf1 = { 0,0,0,0,0,0,0,0 };
  if (g < 2) {
    cf0 = *(const bf16x8*)(Cbase + (size_t)lg0 * D_STATE + 8 * g);
    cf1 = *(const bf16x8*)(Cbase + (size_t)lg1 * D_STATE + 8 * g);
  }
  const float acl20 = sc2[lg0], acl21 = sc2[lg1];

  // raw B fragments for the diagonal tiles (L2-hot)
  bf16x8 braw0 = { 0,0,0,0,0,0,0,0 }, braw1 = { 0,0,0,0,0,0,0,0 };
  if (g < 2) {
    braw0 = __builtin_bit_cast(bf16x8, *(const us8v*)(Bo + (rowbase + lg0) * D_STATE + 8 * g));
    braw1 = __builtin_bit_cast(bf16x8, *(const us8v*)(Bo + (rowbase + lg1) * D_STATE + 8 * g));
  }

  auto g_tile = [&](int st, int lt, int lg, float acl2, bf16x8 cf, bf16x8 braw) -> uint2 {
    uint2 pk;
    if (st < lt) {
      bf16x8 bfg = *(const bf16x8*)&Bs[(st * 16 + fr) * 24 + 8 * g];
      f32x4 G = __builtin_amdgcn_mfma_f32_16x16x32_bf16(bfg, cf, zf, 0, 0, 0);
      const float wl = exp2f(acl2 - scE[st]);
      pk.x = pk_bf(G[0] * wl, G[1] * wl);
      pk.y = pk_bf(G[2] * wl, G[3] * wl);
    } else if (st == lt) {
      f32x4 G = __builtin_amdgcn_mfma_f32_16x16x32_bf16(braw, cf, zf, 0, 0, 0);
      f32x4 se2 = *(const f32x4*)&sc2[st * 16 + 4 * g];
      const int sbase = st * 16 + 4 * g;
      float w0 = (sbase + 0 <= lg) ? exp2f(acl2 - se2[0]) : 0.f;
      float w1 = (sbase + 1 <= lg) ? exp2f(acl2 - se2[1]) : 0.f;
      float w2 = (sbase + 2 <= lg) ? exp2f(acl2 - se2[2]) : 0.f;
      float w3 = (sbase + 3 <= lg) ? exp2f(acl2 - se2[3]) : 0.f;
      pk.x = pk_bf(G[0] * w0, G[1] * w1);
      pk.y = pk_bf(G[2] * w2, G[3] * w3);
    } else {
      pk.x = 0u; pk.y = 0u;
    }
    return pk;
  };

  f32x4 acc0 = zf, acc1 = zf;
  for (int sp = 0; sp < npair1; ++sp) {
    const bf16x8 xf = *(const bf16x8*)&xsT[fr * 264 + sp * 32 + 8 * g];
    const bool a0 = (sp < npair0);
    // both chains' G-MFMAs + exp/pack issued before any Ps round-trip
    uint2 p1a = g_tile(2 * sp,     lt1, lg1, acl21, cf1, braw1);
    uint2 p1b = g_tile(2 * sp + 1, lt1, lg1, acl21, cf1, braw1);
    uint2 p0a, p0b;
    if (a0) {
      p0a = g_tile(2 * sp,     lt0, lg0, acl20, cf0, braw0);
      p0b = g_tile(2 * sp + 1, lt0, lg0, acl20, cf0, braw0);
    }
    // chain 1 Ps round-trip + PV
    *(uint2*)&Ps[wid][fr * 40 +  0 + 4 * g] = p1a;
    *(uint2*)&Ps[wid][fr * 40 + 16 + 4 * g] = p1b;
    bf16x8 pf1 = *(const bf16x8*)&Ps[wid][fr * 40 + 8 * g];
    acc1 = __builtin_amdgcn_mfma_f32_16x16x32_bf16(xf, pf1, acc1, 0, 0, 0);
    // chain 0 Ps round-trip + PV (write-after-read safe: per-wave in-order LDS)
    if (a0) {
      *(uint2*)&Ps[wid][fr * 40 +  0 + 4 * g] = p0a;
      *(uint2*)&Ps[wid][fr * 40 + 16 + 4 * g] = p0b;
      bf16x8 pf0 = *(const bf16x8*)&Ps[wid][fr * 40 + 8 * g];
      acc0 = __builtin_amdgcn_mfma_f32_16x16x32_bf16(xf, pf0, acc0, 0, 0, 0);
    }
  }

  // ---- store both strips' Y with D*x fold ----
#pragma unroll
  for (int q = 0; q < 2; ++q) {
    const int lt = q ? lt1 : lt0;
    const f32x4 acc = q ? acc1 : acc0;
    us4v xs4 = *(const us4v*)&xraw[(lt * 16 + fr + 3) * 16 + 4 * g];
    us4v o = { f2bf(acc[0] + Dh * bf2f(xs4[0])),
               f2bf(acc[1] + Dh * bf2f(xs4[1])),
               f2bf(acc[2] + Dh * bf2f(xs4[2])),
               f2bf(acc[3] + Dh * bf2f(xs4[3])) };
    *(us4v*)(YdT + (rhrow - r + (size_t)lt * 16 + fr) * HEADDIM + 4 * g) = o;
  }

  __syncthreads();   // #4
  if (tid < 256) {
    stloc[((size_t)(b * NCHUNKS + cidx) * NHEADS + h) * 256 + tid] = sred[0][tid] + sred[1][tid];
  }
}

// ---------------------------------------------------------------------------
// K4: sequential inter-chunk state recurrence
// ---------------------------------------------------------------------------
__global__ __launch_bounds__(256)
void chunk_scan_kernel(const float* __restrict__ stloc, const float* __restrict__ csum_g,
                       float* __restrict__ stpre) {
  const int b  = blockIdx.x / NHEADS;
  const int h  = blockIdx.x % NHEADS;
  const int pn = threadIdx.x;
  float S = 0.0f;
  for (int c = 0; c < NCHUNKS; ++c) {
    const size_t idx = ((size_t)(b * NCHUNKS + c) * NHEADS + h) * 256 + pn;
    stpre[idx] = S;
    S = __expf(csum_g[(b * NHEADS + h) * NCHUNKS + c]) * S + stloc[idx];
  }
}

// ---------------------------------------------------------------------------
// K5 (tiled): Y_off add, silu(z) gate, RMSNorm -> yn. Dense zbuf.
// ---------------------------------------------------------------------------
#define TT 16
__global__ __launch_bounds__(384)
void yoff_norm_tiled(const unsigned short* __restrict__ YdT,
                     const unsigned short* __restrict__ Co, const float* __restrict__ acum_g,
                     const float* __restrict__ stpre,
                     const unsigned short* __restrict__ zbuf, const float* __restrict__ norm_w,
                     unsigned short* __restrict__ yn) {
  const int r0   = blockIdx.x * TT;
  const int b    = r0 / SEQLEN;
  const int t0   = r0 % SEQLEN;
  const int cidx = t0 / CHUNK;
  const int d    = threadIdx.x;
  const int h    = d >> 4, p = d & 15;
  const int wv   = d >> 6;

  __shared__ unsigned short Yt[NHEADS * TT * 16];
  __shared__ float At[NHEADS * TT];
  __shared__ float Ct[TT * 16];
  __shared__ float red[TT][6];

  {
    us8v* Yt8 = (us8v*)Yt;
#pragma unroll
    for (int rep = 0; rep < 2; ++rep) {
      int j = d + rep * 384;
      int hh = j >> 5, q = j & 31;
      const size_t src = ((size_t)(b * NHEADS + hh) * SEQLEN + t0) * HEADDIM + q * 8;
      Yt8[j] = *(const us8v*)(YdT + src);
    }
    At[d] = acum_g[(size_t)(b * NHEADS + (d >> 4)) * SEQLEN + t0 + (d & 15)];
    if (d < TT * 16) Ct[d] = bf2f(Co[(size_t)r0 * D_STATE + d]);
  }

  float S[16];
  {
    const float* Sp = stpre + ((size_t)(b * NCHUNKS + cidx) * NHEADS + h) * 256 + p * 16;
#pragma unroll
    for (int q = 0; q < 4; ++q) {
      float4 v4 = *(const float4*)(Sp + 4 * q);
      S[4 * q + 0] = v4.x; S[4 * q + 1] = v4.y; S[4 * q + 2] = v4.z; S[4 * q + 3] = v4.w;
    }
  }
  const float nw = norm_w[d];
  __syncthreads();

  float yg[TT];
#pragma unroll
  for (int tt = 0; tt < TT; ++tt) {
    float dot = 0.f;
#pragma unroll
    for (int n = 0; n < 16; ++n) dot += Ct[tt * 16 + n] * S[n];
    const float acl = At[h * TT + tt];
    float y = bf2f(Yt[h * 256 + tt * 16 + p]) + __expf(acl) * dot;
    const float z = bf2f(zbuf[(size_t)(r0 + tt) * 384 + d]);
    yg[tt] = y * silu_f(z);
    float s = yg[tt] * yg[tt];
#pragma unroll
    for (int off = 32; off > 0; off >>= 1) s += __shfl_down(s, off);
    if ((d & 63) == 0) red[tt][wv] = s;
  }
  __syncthreads();

#pragma unroll
  for (int tt = 0; tt < TT; ++tt) {
    const float tot = red[tt][0] + red[tt][1] + red[tt][2] + red[tt][3] + red[tt][4] + red[tt][5];
    const float scale = rsqrtf(tot * (1.0f / D_INNER) + EPS);
    yn[(size_t)(r0 + tt) * D_INNER + d] = f2bf(yg[tt] * scale * nw);
  }
}

// ---------------------------------------------------------------------------
extern "C" void kernel_launch(void* const* d_in, const int* in_sizes, int n_in,
                              void* d_out, int out_size, void* d_ws, size_t ws_size,
                              hipStream_t stream) {
  const float* u        = (const float*)d_in[0];
  const float* support  = (const float*)d_in[1];
  const float* W_in     = (const float*)d_in[2];
  const float* W_in_b   = (const float*)d_in[3];
  const float* conv_w   = (const float*)d_in[4];
  const float* conv_b   = (const float*)d_in[5];
  const float* conv_w_b = (const float*)d_in[6];
  const float* conv_b_b = (const float*)d_in[7];
  const float* dt_bias  = (const float*)d_in[8];
  const float* A_log    = (const float*)d_in[9];
  const float* Dvec     = (const float*)d_in[10];
  const float* norm_w   = (const float*)d_in[11];
  const float* W_out    = (const float*)d_in[12];
  float* out = (float*)d_out;
  char* wsb  = (char*)d_ws;

  unsigned short* Wi_b  = (unsigned short*)(wsb);
  unsigned short* Wo_b  = Wi_b + (size_t)D_IN_PROJ * D_MODEL;
  unsigned short* Wib_b = Wo_b + (size_t)D_MODEL * D_INNER;
  unsigned short* zbuf  = Wib_b + (size_t)D_STATE * D_MODEL;
  unsigned short* xT    = zbuf + (size_t)ROWS * D_INNER;
  unsigned short* Braw  = xT + (size_t)ROWS * D_INNER;
  unsigned short* draw  = Braw + (size_t)ROWS * D_STATE;
  unsigned short* craw  = draw + (size_t)ROWS * NHEADS;
  unsigned short* Bo    = craw + (size_t)ROWS * D_STATE;
  unsigned short* Co    = Bo + (size_t)ROWS * D_STATE;
  unsigned short* YdT   = Co + (size_t)ROWS * D_STATE;
  unsigned short* yn    = YdT + (size_t)ROWS * D_INNER;
  float* dtoT  = (float*)(yn + (size_t)ROWS * D_INNER);
  float* acum  = dtoT  + (size_t)ROWS * NHEADS;
  float* csum  = acum  + (size_t)BATCH * NHEADS * SEQLEN;
  float* stloc = csum  + (size_t)BATCH * NHEADS * NCHUNKS;
  float* stpre = stloc + (size_t)BATCH * NCHUNKS * NHEADS * 256;

  cvt3_kernel<<<224, 256, 0, stream>>>(W_in, Wi_b, (long)D_IN_PROJ * D_MODEL,
                                       W_out, Wo_b, (long)D_MODEL * D_INNER,
                                       W_in_b, Wib_b, (long)D_STATE * D_MODEL);
  gemm_bf16<true, true, true><<<dim3(7, ROWS / 128), 256, 0, stream>>>(
      u, Wi_b, nullptr, ROWS, D_IN_PROJ, D_MODEL, zbuf, xT, Braw, draw);
  gemm_bf16<true, true, false><<<dim3(1, ROWS / 128), 256, 0, stream>>>(
      support, Wib_b, craw, ROWS, D_STATE, D_MODEL, nullptr, nullptr, nullptr, nullptr);
  conv_bcdt<<<CBC_NB + CDT_NB, 256, 0, stream>>>(
      Braw, craw, draw, conv_w, conv_b, conv_w_b, conv_b_b, dt_bias, Bo, Co, dtoT);
  ssd_mfma_kernel<<<dim3(NHEADS, NCHUNKS, BATCH), 512, 0, stream>>>(
      xT, Bo, Co, dtoT, A_log, conv_w, conv_b, Dvec, YdT, acum, csum, stloc);
  chunk_scan_kernel<<<BATCH * NHEADS, 256, 0, stream>>>(stloc, csum, stpre);
  yoff_norm_tiled<<<ROWS / TT, 384, 0, stream>>>(YdT, Co, acum, stpre, zbuf, norm_w, yn);
  gemm_bf16<false, false, false><<<dim3((D_MODEL + 127) / 128, ROWS / 128), 256, 0, stream>>>(
      yn, Wo_b, out, ROWS, D_MODEL, D_INNER, nullptr, nullptr, nullptr, nullptr);
}